// Round 2
// baseline (26275.436 us; speedup 1.0000x reference)
//
#include <hip/hip_runtime.h>
#include <cstddef>
#include <cstdint>

#define N_NODES 100000
#define N_EDGES 800000
#define EL_TOT  900000      // edges + self loops
#define HID 128
#define H2  192
#define G4  768             // 4*H2

typedef unsigned short bf16;

// ---------------------------------------------------------------- dtype helpers

__device__ __forceinline__ float b2f(bf16 u) {
    return __uint_as_float(((unsigned)u) << 16);
}
__device__ __forceinline__ bf16 f2b(float f) {   // round-nearest-even
    unsigned u = __float_as_uint(f);
    u += 0x7FFFu + ((u >> 16) & 1u);
    return (bf16)(u >> 16);
}
__device__ __forceinline__ float ldE(const float* p, size_t i) { return p[i]; }
__device__ __forceinline__ float ldE(const bf16* p, size_t i) { return b2f(p[i]); }
__device__ __forceinline__ void stE(float* p, size_t i, float v) { p[i] = v; }
__device__ __forceinline__ void stE(bf16* p, size_t i, float v) { p[i] = f2b(v); }
__device__ __forceinline__ float4 ld4(const float* p) { return *(const float4*)p; }
__device__ __forceinline__ float4 ld4(const bf16* p) {
    ushort4 u = *(const ushort4*)p;
    return make_float4(b2f(u.x), b2f(u.y), b2f(u.z), b2f(u.w));
}

// ---------------------------------------------------------------- utilities

__global__ void sentinel_kernel(float* out, int n, float val) {
    int t = blockIdx.x * blockDim.x + threadIdx.x;
    if (t < n) out[t] = val;
}

template<typename TX0>
__global__ void init_x0_kernel(const int* __restrict__ x_idx,
                               const float* __restrict__ x_flt,
                               const float* __restrict__ emb_aa,
                               const float* __restrict__ emb_ss,
                               TX0* __restrict__ x0l, TX0* __restrict__ x0r) {
    int tid = blockIdx.x * blockDim.x + threadIdx.x;
    if (tid >= N_NODES * HID) return;
    int n = tid >> 7, cc = tid & 127;
    int ia = x_idx[2 * n], is_ = x_idx[2 * n + 1];
    float vl, vr;
    if (cc < 123) {
        vl = emb_aa[(0 * 26 + ia) * 123 + cc] + emb_ss[(0 * 3 + is_) * 123 + cc];
        vr = emb_aa[(1 * 26 + ia) * 123 + cc] + emb_ss[(1 * 3 + is_) * 123 + cc];
    } else {
        float f = x_flt[n * 5 + (cc - 123)];
        vl = f; vr = f;
    }
    stE(x0l, (size_t)tid, vl);
    stE(x0r, (size_t)tid, vr);
}

__global__ void bsum_kernel(const float* __restrict__ bih,
                            const float* __restrict__ bhh,
                            float* __restrict__ bsum) {
    int t = blockIdx.x * blockDim.x + threadIdx.x;
    if (t < 4 * G4) bsum[t] = bih[t] + bhh[t];
}

// ---------------------------------------------------------------- CSR build

__global__ void deg_kernel(const int* __restrict__ dst, int* __restrict__ deg) {
    int t = blockIdx.x * blockDim.x + threadIdx.x;
    if (t >= EL_TOT) return;
    int d = (t < N_EDGES) ? dst[t] : (t - N_EDGES);
    atomicAdd(&deg[d], 1);
}

__global__ void scan_kernel(const int* __restrict__ deg, int* __restrict__ offs, int n) {
    __shared__ int sdata[1024];
    __shared__ int carry;
    if (threadIdx.x == 0) carry = 0;
    __syncthreads();
    for (int base = 0; base < n; base += 1024) {
        int i = base + (int)threadIdx.x;
        int v = (i < n) ? deg[i] : 0;
        sdata[threadIdx.x] = v;
        __syncthreads();
        for (int off = 1; off < 1024; off <<= 1) {
            int t = (threadIdx.x >= (unsigned)off) ? sdata[threadIdx.x - off] : 0;
            __syncthreads();
            sdata[threadIdx.x] += t;
            __syncthreads();
        }
        if (i < n) offs[i + 1] = carry + sdata[threadIdx.x];
        __syncthreads();
        if (threadIdx.x == 1023) carry += sdata[1023];
        __syncthreads();
    }
    if (threadIdx.x == 0) offs[0] = 0;
}

__global__ void copy_int_kernel(const int* __restrict__ a, int* __restrict__ b, int n) {
    int t = blockIdx.x * blockDim.x + threadIdx.x;
    if (t < n) b[t] = a[t];
}

__global__ void fill_kernel(const int* __restrict__ dst, int* __restrict__ pos,
                            int* __restrict__ eid) {
    int t = blockIdx.x * blockDim.x + threadIdx.x;
    if (t >= EL_TOT) return;
    int d = (t < N_EDGES) ? dst[t] : (t - N_EDGES);
    int p = atomicAdd(&pos[d], 1);
    eid[p] = t;
}

// ---------------------------------------------------------------- generic GEMM
// C(RxM) = A(RxK) @ B + (beta ? C : bias)
// transB==0: B is (K,M) row-major; transB==1: B is (M,K) row-major
template<typename TA, typename TC>
__global__ __launch_bounds__(256) void gemm_kernel(
    const TA* __restrict__ A, const float* __restrict__ B,
    TC* __restrict__ C, const float* __restrict__ bias,
    int R, int K, int M, int transB, int beta) {
    __shared__ float As[16][128];
    __shared__ float Bs[16][128];
    const int tid = threadIdx.x;
    const int bm0 = blockIdx.y * 128;
    const int bn0 = blockIdx.x * 128;
    const int tx = tid & 15, ty = tid >> 4;
    float acc[8][8];
#pragma unroll
    for (int i = 0; i < 8; ++i)
#pragma unroll
        for (int j = 0; j < 8; ++j) acc[i][j] = 0.f;

    for (int k0 = 0; k0 < K; k0 += 16) {
        {   // A tile -> As[k][m]
            const int kk0 = (tid & 3) << 2;
            const int rowb = tid >> 2;
#pragma unroll
            for (int r = 0; r < 2; ++r) {
                const int row = rowb + (r << 6);
                const int grow = bm0 + row;
                float4 v = make_float4(0.f, 0.f, 0.f, 0.f);
                if (grow < R) v = ld4(A + (size_t)grow * K + k0 + kk0);
                As[kk0 + 0][row] = v.x; As[kk0 + 1][row] = v.y;
                As[kk0 + 2][row] = v.z; As[kk0 + 3][row] = v.w;
            }
        }
        if (!transB) {
            const int colb = (tid & 31) << 2;
            const int kkb = tid >> 5;
#pragma unroll
            for (int r = 0; r < 2; ++r) {
                const int kk = kkb + (r << 3);
                *(float4*)&Bs[kk][colb] =
                    *(const float4*)(B + (size_t)(k0 + kk) * M + bn0 + colb);
            }
        } else {
            const int kk0 = (tid & 3) << 2;
            const int colb = tid >> 2;
#pragma unroll
            for (int r = 0; r < 2; ++r) {
                const int col = colb + (r << 6);
                float4 v = *(const float4*)(B + (size_t)(bn0 + col) * K + k0 + kk0);
                Bs[kk0 + 0][col] = v.x; Bs[kk0 + 1][col] = v.y;
                Bs[kk0 + 2][col] = v.z; Bs[kk0 + 3][col] = v.w;
            }
        }
        __syncthreads();
#pragma unroll
        for (int kk = 0; kk < 16; ++kk) {
            float a[8], bb[8];
            *(float4*)&a[0]  = *(const float4*)&As[kk][(ty << 3)];
            *(float4*)&a[4]  = *(const float4*)&As[kk][(ty << 3) + 4];
            *(float4*)&bb[0] = *(const float4*)&Bs[kk][(tx << 3)];
            *(float4*)&bb[4] = *(const float4*)&Bs[kk][(tx << 3) + 4];
#pragma unroll
            for (int i = 0; i < 8; ++i)
#pragma unroll
                for (int j = 0; j < 8; ++j) acc[i][j] = fmaf(a[i], bb[j], acc[i][j]);
        }
        __syncthreads();
    }
#pragma unroll
    for (int i = 0; i < 8; ++i) {
        const int grow = bm0 + (ty << 3) + i;
        if (grow >= R) continue;
#pragma unroll
        for (int j = 0; j < 8; ++j) {
            const int gcol = bn0 + (tx << 3) + j;
            size_t idx = (size_t)grow * M + gcol;
            float v = acc[i][j];
            if (beta) v += ldE(C, idx);
            else if (bias) v += bias[gcol];
            stE(C, idx, v);
        }
    }
}

template<typename TA, typename TC>
static void launch_gemm(const TA* A, const float* B, TC* C, const float* bias,
                        int R, int K, int M, int transB, int beta, hipStream_t s) {
    dim3 g(M / 128, (R + 127) / 128);
    gemm_kernel<TA, TC><<<g, 256, 0, s>>>(A, B, C, bias, R, K, M, transB, beta);
}

// ---------------------------------------------------------------- GAT pieces

template<typename TXH>
__global__ __launch_bounds__(256) void att_kernel(
    const TXH* __restrict__ xh, const float* __restrict__ as_,
    const float* __restrict__ ad_, float* __restrict__ asrc, float* __restrict__ adst) {
    int w = (blockIdx.x * blockDim.x + threadIdx.x) >> 6;
    int lane = threadIdx.x & 63;
    if (w >= N_NODES) return;
    const TXH* row = xh + (size_t)w * 256;
    float x0 = ldE(row, (size_t)lane), x1 = ldE(row, (size_t)(64 + lane));
    float x2 = ldE(row, (size_t)(128 + lane)), x3 = ldE(row, (size_t)(192 + lane));
    float s0 = x0 * as_[lane] + x1 * as_[64 + lane];
    float s1 = x2 * as_[128 + lane] + x3 * as_[192 + lane];
    float d0 = x0 * ad_[lane] + x1 * ad_[64 + lane];
    float d1 = x2 * ad_[128 + lane] + x3 * ad_[192 + lane];
    for (int o = 1; o < 64; o <<= 1) {
        s0 += __shfl_xor(s0, o); s1 += __shfl_xor(s1, o);
        d0 += __shfl_xor(d0, o); d1 += __shfl_xor(d1, o);
    }
    if (lane == 0) {
        asrc[2 * w] = s0; asrc[2 * w + 1] = s1;
        adst[2 * w] = d0; adst[2 * w + 1] = d1;
    }
}

__device__ __forceinline__ float lrelu02(float x) { return x > 0.f ? x : 0.2f * x; }

template<typename TXH, typename TP, typename TO>
__global__ __launch_bounds__(256) void agg_kernel(
    const TXH* __restrict__ xh, const float* __restrict__ asrc,
    const float* __restrict__ adst, const int* __restrict__ offs,
    const int* __restrict__ eid, const int* __restrict__ srcarr,
    const TP* __restrict__ xprev_l, const TP* __restrict__ xprev_r,
    const float* __restrict__ bias, TO* __restrict__ outx) {
    int n = (blockIdx.x * blockDim.x + threadIdx.x) >> 6;
    int lane = threadIdx.x & 63;
    if (n >= N_NODES) return;
    int start = offs[n], end = offs[n + 1];
    float ad0 = adst[2 * n], ad1 = adst[2 * n + 1];

    float m0 = -1e30f, m1 = -1e30f;
    for (int j = start + lane; j < end; j += 64) {
        int id = eid[j];
        int s = (id < N_EDGES) ? srcarr[id] : (id - N_EDGES);
        m0 = fmaxf(m0, lrelu02(asrc[2 * s] + ad0));
        m1 = fmaxf(m1, lrelu02(asrc[2 * s + 1] + ad1));
    }
    for (int o = 1; o < 64; o <<= 1) {
        m0 = fmaxf(m0, __shfl_xor(m0, o));
        m1 = fmaxf(m1, __shfl_xor(m1, o));
    }
    float d0 = 0.f, d1 = 0.f;
    for (int j = start + lane; j < end; j += 64) {
        int id = eid[j];
        int s = (id < N_EDGES) ? srcarr[id] : (id - N_EDGES);
        d0 += __expf(lrelu02(asrc[2 * s] + ad0) - m0);
        d1 += __expf(lrelu02(asrc[2 * s + 1] + ad1) - m1);
    }
    for (int o = 1; o < 64; o <<= 1) {
        d0 += __shfl_xor(d0, o);
        d1 += __shfl_xor(d1, o);
    }
    float inv0 = 1.f / (d0 + 1e-16f), inv1 = 1.f / (d1 + 1e-16f);

    float ac[4] = {0.f, 0.f, 0.f, 0.f};
    bool hd1 = lane >= 32;
    for (int j = start; j < end; ++j) {
        int id = eid[j];
        int s = (id < N_EDGES) ? srcarr[id] : (id - N_EDGES);
        float al;
        if (hd1) al = __expf(lrelu02(asrc[2 * s + 1] + ad1) - m1) * inv1;
        else     al = __expf(lrelu02(asrc[2 * s] + ad0) - m0) * inv0;
        float4 v = ld4(xh + (size_t)s * 256 + lane * 4);
        ac[0] += v.x * al; ac[1] += v.y * al; ac[2] += v.z * al; ac[3] += v.w * al;
    }
    float ot[4];
#pragma unroll
    for (int t = 0; t < 4; ++t) ot[t] = __shfl_xor(ac[t], 32);
    if (lane < 32) {
        int c0 = lane * 4;
        size_t base = (size_t)n * HID + c0;
#pragma unroll
        for (int t = 0; t < 4; ++t) {
            float xl = ldE(xprev_l, base + t);
            float xr = ldE(xprev_r, base + t);
            float r = 0.5f * (xl + xr) +
                      fmaxf(0.f, 0.5f * (ac[t] + ot[t]) + bias[c0 + t]);
            stE(outx, base + t, r);
        }
    }
}

// ---------------------------------------------------------------- LSTM / JK

__global__ __launch_bounds__(256) void gate_kernel(
    const float* __restrict__ G, float* __restrict__ h, float* __restrict__ c,
    const float* __restrict__ attw, float* __restrict__ score, int accum, int ch) {
    int w = (blockIdx.x * blockDim.x + threadIdx.x) >> 6;
    int lane = threadIdx.x & 63;
    if (w >= ch) return;
    const float* g = G + (size_t)w * G4;
    float dot = 0.f;
#pragma unroll
    for (int j = 0; j < 3; ++j) {
        int u = lane + j * 64;
        float ig = g[u], fg = g[192 + u], gg = g[384 + u], og = g[576 + u];
        float co = c[(size_t)w * H2 + u];
        float si = 1.f / (1.f + __expf(-ig));
        float sf = 1.f / (1.f + __expf(-fg));
        float so = 1.f / (1.f + __expf(-og));
        float cn = sf * co + si * tanhf(gg);
        float hn = so * tanhf(cn);
        c[(size_t)w * H2 + u] = cn;
        h[(size_t)w * H2 + u] = hn;
        dot += hn * attw[u];
    }
    for (int o = 1; o < 64; o <<= 1) dot += __shfl_xor(dot, o);
    if (lane == 0) {
        if (accum) score[w] += dot; else score[w] = dot;
    }
}

template<typename TH, typename TJ>
__global__ __launch_bounds__(256) void jkfin_kernel(
    const float* __restrict__ scores, const TH* __restrict__ xs0,
    const TH* __restrict__ xs1, const TH* __restrict__ xs2,
    TJ* __restrict__ jk, int c0, int ch) {
    int w = (blockIdx.x * blockDim.x + threadIdx.x) >> 6;
    int lane = threadIdx.x & 63;
    if (w >= ch) return;
    float s0 = scores[w], s1 = scores[ch + w], s2 = scores[2 * ch + w];
    float m = fmaxf(s0, fmaxf(s1, s2));
    float a0 = __expf(s0 - m), a1 = __expf(s1 - m), a2 = __expf(s2 - m);
    float inv = 1.f / (a0 + a1 + a2);
    a0 *= inv; a1 *= inv; a2 *= inv;
    size_t gn = (size_t)(c0 + w) * HID + lane * 2;
#pragma unroll
    for (int t = 0; t < 2; ++t) {
        float v0 = ldE(xs0, gn + t);
        float v1 = ldE(xs1, gn + t);
        float v2 = ldE(xs2, gn + t);
        stE(jk, gn + t, v0 * a0 + v1 * a1 + v2 * a2);
    }
}

// ---------------------------------------------------------------- final combine

__global__ __launch_bounds__(256) void final_kernel(
    const float* __restrict__ o0, const float* __restrict__ o1,
    const float* __restrict__ o2, const float* __restrict__ o3,
    const float* __restrict__ lw, float* __restrict__ out, int nloc, long long c3off) {
    int w = (blockIdx.x * blockDim.x + threadIdx.x) >> 6;
    int lane = threadIdx.x & 63;
    if (w >= nloc) return;
    size_t base = (size_t)w * HID;
    float w0 = lw[lane], w1 = lw[64 + lane];
    const float* op[4] = {o0, o1, o2, o3};
    float v[4][2];
    float s[4];
#pragma unroll
    for (int i = 0; i < 4; ++i) {
        v[i][0] = op[i][base + lane];
        v[i][1] = op[i][base + 64 + lane];
        float t = v[i][0] * w0 + v[i][1] * w1;
        for (int o = 1; o < 64; o <<= 1) t += __shfl_xor(t, o);
        s[i] = t;
    }
    float m = fmaxf(fmaxf(s[0], s[1]), fmaxf(s[2], s[3]));
    float e0 = __expf(s[0] - m), e1 = __expf(s[1] - m);
    float e2 = __expf(s[2] - m), e3 = __expf(s[3] - m);
    float inv = 1.f / (e0 + e1 + e2 + e3);
    float r0 = (v[0][0] * e0 + v[1][0] * e1 + v[2][0] * e2 + v[3][0] * e3) * inv;
    float r1 = (v[0][1] * e0 + v[1][1] * e1 + v[2][1] * e2 + v[3][1] * e3) * inv;
    size_t obase = (size_t)(c3off + w) * HID;
    out[obase + lane] = r0;
    out[obase + 64 + lane] = r1;
}

// ---------------------------------------------------------------- plan sizing

static long long align1k(long long x) { return (x + 1023) & ~1023LL; }

static long long plan_bytes(int szTH, int szTX0, int szTXH, int szTJ, int CH) {
    const long long S = (long long)N_NODES * HID;
    long long t = 0;
    t += align1k(6 * S * szTH);
    long long rB = 2 * S * szTX0;
    long long sc = ((long long)CH * G4 + 2LL * CH * H2) * 4;
    t += align1k(rB > sc ? rB : sc);
    long long rC = (long long)N_NODES * 256 * szTXH;
    long long j2 = 2 * S * szTJ;
    t += align1k(rC > j2 ? rC : j2);
    t += align1k(2LL * N_NODES * 4);    // asrc
    t += align1k(2LL * N_NODES * 4);    // adst
    t += align1k(3LL * 25000 * 4);      // scores
    t += align1k(4LL * G4 * 4);         // bsum
    t += align1k(2LL * (N_NODES + (N_NODES + 1) + N_NODES + EL_TOT) * 4); // CSR ints
    return t;
}

// ---------------------------------------------------------------- main runner

template<typename TH, typename TX0, typename TXH, typename TJ>
static void run_net(void* const* d_in, float* out, char* ws, int CH, int CH3,
                    hipStream_t stream) {
    const int*   x_idx   = (const int*)  d_in[0];
    const float* x_flt   = (const float*)d_in[1];
    const int*   ei_l    = (const int*)  d_in[2];
    const int*   ei_r    = (const int*)  d_in[3];
    const float* emb_aa  = (const float*)d_in[4];
    const float* emb_ss  = (const float*)d_in[5];
    const float* conv_W  = (const float*)d_in[6];
    const float* att_s   = (const float*)d_in[7];
    const float* att_d   = (const float*)d_in[8];
    const float* conv_b  = (const float*)d_in[9];
    const float* Wih     = (const float*)d_in[10];
    const float* Whh     = (const float*)d_in[11];
    const float* bih     = (const float*)d_in[12];
    const float* bhh     = (const float*)d_in[13];
    const float* jkw     = (const float*)d_in[14];
    const float* dummy_W = (const float*)d_in[16];
    const float* dummy_b = (const float*)d_in[17];
    const float* fin_W   = (const float*)d_in[18];
    const float* fin_b   = (const float*)d_in[19];
    const float* last_W  = (const float*)d_in[20];

    const long long S = (long long)N_NODES * HID;
    long long off = 0;
    TH* hist = (TH*)(ws + off); off += align1k(6 * S * (long long)sizeof(TH));
    char* regB = ws + off;
    {
        long long rB = 2 * S * (long long)sizeof(TX0);
        long long sc = ((long long)CH * G4 + 2LL * CH * H2) * 4;
        off += align1k(rB > sc ? rB : sc);
    }
    char* regC = ws + off;
    {
        long long rC = (long long)N_NODES * 256 * (long long)sizeof(TXH);
        long long j2 = 2 * S * (long long)sizeof(TJ);
        off += align1k(rC > j2 ? rC : j2);
    }
    float* asrc   = (float*)(ws + off); off += align1k(2LL * N_NODES * 4);
    float* adst   = (float*)(ws + off); off += align1k(2LL * N_NODES * 4);
    float* scores = (float*)(ws + off); off += align1k(3LL * 25000 * 4);
    float* bsum   = (float*)(ws + off); off += align1k(4LL * G4 * 4);
    int* ibase = (int*)(ws + off);
    int *deg[2], *offs[2], *pos[2], *eid[2];
    {
        long long io = 0;
        for (int b = 0; b < 2; ++b) {
            deg[b]  = ibase + io; io += N_NODES;
            offs[b] = ibase + io; io += N_NODES + 1;
            pos[b]  = ibase + io; io += N_NODES;
            eid[b]  = ibase + io; io += EL_TOT;
        }
    }
    TX0* x0l = (TX0*)regB; TX0* x0r = x0l + S;
    float* Gbuf = (float*)regB;
    float* hbuf = Gbuf + (long long)CH * G4;
    float* cbuf = hbuf + (long long)CH * H2;
    TXH* xh = (TXH*)regC;
    TJ* jkb = (TJ*)regC;               // jk_l = jkb, jk_r = jkb + S

    // ---- stage 0
    init_x0_kernel<TX0><<<(N_NODES * HID + 255) / 256, 256, 0, stream>>>(
        x_idx, x_flt, emb_aa, emb_ss, x0l, x0r);
    bsum_kernel<<<12, 256, 0, stream>>>(bih, bhh, bsum);
    for (int b = 0; b < 2; ++b) {
        const int* ei = b ? ei_r : ei_l;
        hipMemsetAsync(deg[b], 0, N_NODES * sizeof(int), stream);
        deg_kernel<<<(EL_TOT + 255) / 256, 256, 0, stream>>>(ei + N_EDGES, deg[b]);
        scan_kernel<<<1, 1024, 0, stream>>>(deg[b], offs[b], N_NODES);
        copy_int_kernel<<<(N_NODES + 255) / 256, 256, 0, stream>>>(offs[b], pos[b], N_NODES);
        fill_kernel<<<(EL_TOT + 255) / 256, 256, 0, stream>>>(ei + N_EDGES, pos[b], eid[b]);
    }

    // ---- stage 1: 3 GAT layers x 2 branches
    for (int i = 0; i < 3; ++i) {
        for (int b = 0; b < 2; ++b) {
            const int* ei = b ? ei_r : ei_l;
            const float* W = conv_W + (size_t)(b * 3 + i) * HID * 256;
            if (i == 0)
                launch_gemm<TX0, TXH>(b ? x0r : x0l, W, xh, nullptr,
                                      N_NODES, HID, 256, 0, 0, stream);
            else
                launch_gemm<TH, TXH>(hist + (size_t)(b * 3 + i - 1) * S, W, xh, nullptr,
                                     N_NODES, HID, 256, 0, 0, stream);
            att_kernel<TXH><<<25000, 256, 0, stream>>>(
                xh, att_s + (size_t)(b * 3 + i) * 2 * HID,
                att_d + (size_t)(b * 3 + i) * 2 * HID, asrc, adst);
            TH* xout = hist + (size_t)(b * 3 + i) * S;
            const float* cb = conv_b + (size_t)(b * 3 + i) * HID;
            if (i == 0)
                agg_kernel<TXH, TX0, TH><<<25000, 256, 0, stream>>>(
                    xh, asrc, adst, offs[b], eid[b], ei, x0l, x0r, cb, xout);
            else
                agg_kernel<TXH, TH, TH><<<25000, 256, 0, stream>>>(
                    xh, asrc, adst, offs[b], eid[b], ei,
                    hist + (size_t)(i - 1) * S, hist + (size_t)(3 + i - 1) * S, cb, xout);
        }
    }

    // ---- stage 2: bi-LSTM JK, chunked over nodes
    for (int b = 0; b < 2; ++b) {
        for (int c0 = 0; c0 < N_NODES; c0 += CH) {
            for (int dir = 0; dir < 2; ++dir) {
                hipMemsetAsync(hbuf, 0, (size_t)2 * CH * H2 * sizeof(float), stream);
                const float* Wi = Wih + (size_t)(b * 2 + dir) * G4 * HID;
                const float* Wh = Whh + (size_t)(b * 2 + dir) * G4 * H2;
                const float* bs = bsum + (size_t)(b * 2 + dir) * G4;
                const float* aw = jkw + (size_t)b * 2 * H2 + (size_t)dir * H2;
                for (int st = 0; st < 3; ++st) {
                    int l = dir ? (2 - st) : st;
                    const TH* A = hist + (size_t)(b * 3 + l) * S + (size_t)c0 * HID;
                    launch_gemm<TH, float>(A, Wi, Gbuf, bs, CH, HID, G4, 1, 0, stream);
                    launch_gemm<float, float>(hbuf, Wh, Gbuf, nullptr, CH, H2, G4, 1, 1, stream);
                    gate_kernel<<<(CH + 3) / 4, 256, 0, stream>>>(
                        Gbuf, hbuf, cbuf, aw, scores + (size_t)l * CH, dir, CH);
                }
            }
            jkfin_kernel<TH, TJ><<<(CH + 3) / 4, 256, 0, stream>>>(
                scores, hist + (size_t)b * 3 * S, hist + (size_t)(b * 3 + 1) * S,
                hist + (size_t)(b * 3 + 2) * S, jkb + (size_t)b * S, c0, CH);
        }
    }

    // ---- stage 3: sq, outs, final combine (chunked; scratch = freed hist region)
    float* f3 = (float*)hist;
    TJ* jkl = jkb; TJ* jkr = jkb + S;
    for (long long c3 = 0; c3 < N_NODES; c3 += CH3) {
        int Rr = (int)((N_NODES - c3) < CH3 ? (N_NODES - c3) : CH3);
        float* o0 = f3;
        float* o1 = f3 + (long long)CH3 * HID;
        float* o2 = f3 + 2LL * CH3 * HID;
        float* o3 = f3 + 3LL * CH3 * HID;
        float* sql = f3 + 4LL * CH3 * HID;
        float* sqr = f3 + 5LL * CH3 * HID;
        launch_gemm<TJ, float>(jkl + c3 * HID, dummy_W, sql, dummy_b,
                               Rr, 128, 128, 0, 0, stream);
        launch_gemm<TJ, float>(jkr + c3 * HID, dummy_W + 16384, sqr, dummy_b + 128,
                               Rr, 128, 128, 0, 0, stream);
        launch_gemm<TJ, float>(jkl + c3 * HID, fin_W, o0, fin_b,
                               Rr, 128, 128, 0, 0, stream);
        launch_gemm<float, float>(sql, fin_W + 16384, o1, fin_b + 128,
                                  Rr, 128, 128, 0, 0, stream);
        launch_gemm<TJ, float>(jkr + c3 * HID, fin_W + 2 * 16384, o2, fin_b + 256,
                               Rr, 128, 128, 0, 0, stream);
        launch_gemm<float, float>(sqr, fin_W + 3 * 16384, o3, fin_b + 384,
                                  Rr, 128, 128, 0, 0, stream);
        final_kernel<<<(Rr + 3) / 4, 256, 0, stream>>>(
            o0, o1, o2, o3, last_W, out, Rr, c3);
    }
}

// ---------------------------------------------------------------- entry

extern "C" void kernel_launch(void* const* d_in, const int* in_sizes, int n_in,
                              void* d_out, int out_size, void* d_ws, size_t ws_size,
                              hipStream_t stream) {
    (void)in_sizes; (void)n_in; (void)out_size;
    float* out = (float*)d_out;
    long long needA = plan_bytes(4, 4, 4, 4, 12500);   // ~524 MB, all fp32
    long long needB = plan_bytes(2, 4, 4, 4, 12500);   // ~370 MB, bf16 hist
    long long needC = plan_bytes(2, 2, 2, 2, 6250);    // ~268 MB, bf16 big arrays
    if ((long long)ws_size >= needA) {
        run_net<float, float, float, float>(d_in, out, (char*)d_ws, 12500, 100000, stream);
    } else if ((long long)ws_size >= needB) {
        run_net<bf16, float, float, float>(d_in, out, (char*)d_ws, 12500, 50000, stream);
    } else if ((long long)ws_size >= needC) {
        run_net<bf16, bf16, bf16, bf16>(d_in, out, (char*)d_ws, 6250, 50000, stream);
    } else {
        // report ws_size (MB) through the output for diagnosis
        float val = 100000.0f + (float)(ws_size >> 20);
        sentinel_kernel<<<(N_NODES * HID + 255) / 256, 256, 0, stream>>>(
            out, N_NODES * HID, val);
    }
}

// Round 4
// 6734.261 us; speedup vs baseline: 3.9018x; 3.9018x over previous
//
#include <hip/hip_runtime.h>
#include <cstddef>
#include <cstdint>

#define N_NODES 100000
#define N_EDGES 800000
#define EL_TOT  900000      // edges + self loops
#define HID 128
#define H2  192
#define G4  768             // 4*H2
#define CH  12500           // LSTM node chunk (divides N_NODES)
#define CH3 25000           // stage-3 chunk
#define BK  32
#define LDST 40             // LDS row stride in bf16 elems

typedef unsigned short bf16;
typedef __attribute__((ext_vector_type(8))) short bf16x8v;
typedef __attribute__((ext_vector_type(4))) float f32x4v;

// ---------------------------------------------------------------- dtype helpers

__device__ __forceinline__ float b2f(bf16 u) {
    return __uint_as_float(((unsigned)u) << 16);
}
__device__ __forceinline__ bf16 f2b(float f) {   // round-nearest-even
    unsigned u = __float_as_uint(f);
    u += 0x7FFFu + ((u >> 16) & 1u);
    return (bf16)(u >> 16);
}
__device__ __forceinline__ void stE(float* p, size_t i, float v) { p[i] = v; }
__device__ __forceinline__ void stE(bf16* p, size_t i, float v) { p[i] = f2b(v); }
__device__ __forceinline__ float4 ld4(const bf16* p) {
    ushort4 u = *(const ushort4*)p;
    return make_float4(b2f(u.x), b2f(u.y), b2f(u.z), b2f(u.w));
}

// x0 recompute: column c of node n for one branch
__device__ __forceinline__ float x0_val(int c, int ia, int is_, int n,
                                        const float* __restrict__ embA,
                                        const float* __restrict__ embS,
                                        const float* __restrict__ xflt) {
    return (c < 123) ? (embA[ia * 123 + c] + embS[is_ * 123 + c])
                     : xflt[n * 5 + (c - 123)];
}

// ---------------------------------------------------------------- utilities

__global__ void sentinel_kernel(float* out, int n, float val) {
    int t = blockIdx.x * blockDim.x + threadIdx.x;
    if (t < n) out[t] = val;
}

__global__ void bsum_kernel(const float* __restrict__ bih,
                            const float* __restrict__ bhh,
                            float* __restrict__ bsum) {
    int t = blockIdx.x * blockDim.x + threadIdx.x;
    if (t < 4 * G4) bsum[t] = bih[t] + bhh[t];
}

__global__ void cvt_kernel(const float* __restrict__ in, bf16* __restrict__ out,
                           long long n) {
    long long t = (long long)blockIdx.x * blockDim.x + threadIdx.x;
    if (t < n) out[t] = f2b(in[t]);
}

// out[bt][m][k] = in[bt][k][m]  ((K,M) -> (M,K) bf16)
__global__ void trans_kernel(const float* __restrict__ in, bf16* __restrict__ out,
                             int batch, int K, int M) {
    long long t = (long long)blockIdx.x * blockDim.x + threadIdx.x;
    long long tot = (long long)batch * K * M;
    if (t >= tot) return;
    int per = K * M;
    int bt = (int)(t / per);
    int rem = (int)(t % per);
    int m = rem / K, k = rem % K;
    out[t] = f2b(in[(size_t)bt * per + (size_t)k * M + m]);
}

// ---------------------------------------------------------------- CSR build

__global__ void deg_kernel(const int* __restrict__ dst, int* __restrict__ deg) {
    int t = blockIdx.x * blockDim.x + threadIdx.x;
    if (t >= EL_TOT) return;
    int d = (t < N_EDGES) ? dst[t] : (t - N_EDGES);
    atomicAdd(&deg[d], 1);
}

__global__ void scan_kernel(const int* __restrict__ deg, int* __restrict__ offs, int n) {
    __shared__ int sdata[1024];
    __shared__ int carry;
    if (threadIdx.x == 0) carry = 0;
    __syncthreads();
    for (int base = 0; base < n; base += 1024) {
        int i = base + (int)threadIdx.x;
        int v = (i < n) ? deg[i] : 0;
        sdata[threadIdx.x] = v;
        __syncthreads();
        for (int off = 1; off < 1024; off <<= 1) {
            int t = (threadIdx.x >= (unsigned)off) ? sdata[threadIdx.x - off] : 0;
            __syncthreads();
            sdata[threadIdx.x] += t;
            __syncthreads();
        }
        if (i < n) offs[i + 1] = carry + sdata[threadIdx.x];
        __syncthreads();
        if (threadIdx.x == 1023) carry += sdata[1023];
        __syncthreads();
    }
    if (threadIdx.x == 0) offs[0] = 0;
}

__global__ void copy_int_kernel(const int* __restrict__ a, int* __restrict__ b, int n) {
    int t = blockIdx.x * blockDim.x + threadIdx.x;
    if (t < n) b[t] = a[t];
}

__global__ void fill_kernel(const int* __restrict__ dst, int* __restrict__ pos,
                            int* __restrict__ eid) {
    int t = blockIdx.x * blockDim.x + threadIdx.x;
    if (t >= EL_TOT) return;
    int d = (t < N_EDGES) ? dst[t] : (t - N_EDGES);
    int p = atomicAdd(&pos[d], 1);
    eid[p] = t;
}

// ---------------------------------------------------------------- MFMA GEMM
// C(RxM) = A1(RxK1) @ B1t(MxK1)^T [+ A2(RxK2) @ B2t(MxK2)^T] + bias[col]
template<typename TC>
__global__ __launch_bounds__(256) void mfma_gemm_kernel(
    const bf16* __restrict__ A1, const bf16* __restrict__ B1, int K1,
    const bf16* __restrict__ A2, const bf16* __restrict__ B2, int K2,
    TC* __restrict__ C, const float* __restrict__ bias, int R, int M) {
    __shared__ bf16 As[128 * LDST];
    __shared__ bf16 Bs[128 * LDST];
    const int tid = threadIdx.x;
    const int lane = tid & 63;
    const int wave = tid >> 6;
    const int wm = (wave & 1) * 64, wn = (wave >> 1) * 64;
    const int bm0 = blockIdx.y * 128, bn0 = blockIdx.x * 128;
    const int l15 = lane & 15;
    const int q8 = (lane >> 4) * 8;
    const int srow = tid >> 2;
    const int scol = (tid & 3) * 8;

    f32x4v acc[4][4];
#pragma unroll
    for (int i = 0; i < 4; ++i)
#pragma unroll
        for (int j = 0; j < 4; ++j) acc[i][j] = (f32x4v)(0.0f);

    auto panel = [&](const bf16* Ap, const bf16* Bp, int K) {
        for (int k0 = 0; k0 < K; k0 += BK) {
#pragma unroll
            for (int rnd = 0; rnd < 2; ++rnd) {
                int row = srow + rnd * 64;
                int ga = bm0 + row; ga = (ga < R) ? ga : (R - 1);
                int4 va = *(const int4*)(Ap + (size_t)ga * K + k0 + scol);
                *(int4*)&As[row * LDST + scol] = va;
                int4 vb = *(const int4*)(Bp + (size_t)(bn0 + row) * K + k0 + scol);
                *(int4*)&Bs[row * LDST + scol] = vb;
            }
            __syncthreads();
            bf16x8v af[4], bfv[4];
#pragma unroll
            for (int i = 0; i < 4; ++i) {
                af[i]  = *(const bf16x8v*)&As[(wm + i * 16 + l15) * LDST + q8];
                bfv[i] = *(const bf16x8v*)&Bs[(wn + i * 16 + l15) * LDST + q8];
            }
#pragma unroll
            for (int i = 0; i < 4; ++i)
#pragma unroll
                for (int j = 0; j < 4; ++j)
                    acc[i][j] = __builtin_amdgcn_mfma_f32_16x16x32_bf16(
                        af[i], bfv[j], acc[i][j], 0, 0, 0);
            __syncthreads();
        }
    };
    panel(A1, B1, K1);
    if (A2) panel(A2, B2, K2);

#pragma unroll
    for (int i = 0; i < 4; ++i) {
        const int row0 = bm0 + wm + i * 16 + (lane >> 4) * 4;
#pragma unroll
        for (int j = 0; j < 4; ++j) {
            const int col = bn0 + wn + j * 16 + l15;
            const float bv = bias ? bias[col] : 0.f;
#pragma unroll
            for (int r = 0; r < 4; ++r) {
                const int gr = row0 + r;
                if (gr < R) stE(C, (size_t)gr * M + col, acc[i][j][r] + bv);
            }
        }
    }
}

template<typename TC>
static void mfma_gemm(const bf16* A1, const bf16* B1, int K1,
                      const bf16* A2, const bf16* B2, int K2,
                      TC* C, const float* bias, int R, int M, hipStream_t s) {
    dim3 g(M / 128, (R + 127) / 128);
    mfma_gemm_kernel<TC><<<g, 256, 0, s>>>(A1, B1, K1, A2, B2, K2, C, bias, R, M);
}

// Layer-0 conv GEMM: A built on the fly from embeddings (K=128 fixed)
__global__ __launch_bounds__(256) void mfma_gemm_x0_kernel(
    const int* __restrict__ xidx, const float* __restrict__ xflt,
    const float* __restrict__ embA, const float* __restrict__ embS,
    const bf16* __restrict__ B1, bf16* __restrict__ C, int R, int M) {
    __shared__ bf16 As[128 * LDST];
    __shared__ bf16 Bs[128 * LDST];
    const int tid = threadIdx.x;
    const int lane = tid & 63;
    const int wave = tid >> 6;
    const int wm = (wave & 1) * 64, wn = (wave >> 1) * 64;
    const int bm0 = blockIdx.y * 128, bn0 = blockIdx.x * 128;
    const int l15 = lane & 15;
    const int q8 = (lane >> 4) * 8;
    const int srow = tid >> 2;
    const int scol = (tid & 3) * 8;

    f32x4v acc[4][4];
#pragma unroll
    for (int i = 0; i < 4; ++i)
#pragma unroll
        for (int j = 0; j < 4; ++j) acc[i][j] = (f32x4v)(0.0f);

    for (int k0 = 0; k0 < 128; k0 += BK) {
#pragma unroll
        for (int rnd = 0; rnd < 2; ++rnd) {
            int row = srow + rnd * 64;
            int ga = bm0 + row; ga = (ga < R) ? ga : (R - 1);
            int ia = xidx[2 * ga], is_ = xidx[2 * ga + 1];
            bf16 tmp[8];
#pragma unroll
            for (int t = 0; t < 8; ++t)
                tmp[t] = f2b(x0_val(k0 + scol + t, ia, is_, ga, embA, embS, xflt));
            *(int4*)&As[row * LDST + scol] = *(const int4*)tmp;
            int4 vb = *(const int4*)(B1 + (size_t)(bn0 + row) * 128 + k0 + scol);
            *(int4*)&Bs[row * LDST + scol] = vb;
        }
        __syncthreads();
        bf16x8v af[4], bfv[4];
#pragma unroll
        for (int i = 0; i < 4; ++i) {
            af[i]  = *(const bf16x8v*)&As[(wm + i * 16 + l15) * LDST + q8];
            bfv[i] = *(const bf16x8v*)&Bs[(wn + i * 16 + l15) * LDST + q8];
        }
#pragma unroll
        for (int i = 0; i < 4; ++i)
#pragma unroll
            for (int j = 0; j < 4; ++j)
                acc[i][j] = __builtin_amdgcn_mfma_f32_16x16x32_bf16(
                    af[i], bfv[j], acc[i][j], 0, 0, 0);
        __syncthreads();
    }
#pragma unroll
    for (int i = 0; i < 4; ++i) {
        const int row0 = bm0 + wm + i * 16 + (lane >> 4) * 4;
#pragma unroll
        for (int j = 0; j < 4; ++j) {
            const int col = bn0 + wn + j * 16 + l15;
#pragma unroll
            for (int r = 0; r < 4; ++r) {
                const int gr = row0 + r;
                if (gr < R) C[(size_t)gr * M + col] = f2b(acc[i][j][r]);
            }
        }
    }
}

// ---------------------------------------------------------------- GAT pieces

__global__ __launch_bounds__(256) void att_kernel(
    const bf16* __restrict__ xh, const float* __restrict__ as_,
    const float* __restrict__ ad_, float* __restrict__ asrc, float* __restrict__ adst) {
    int w = (blockIdx.x * blockDim.x + threadIdx.x) >> 6;
    int lane = threadIdx.x & 63;
    if (w >= N_NODES) return;
    const bf16* row = xh + (size_t)w * 256;
    float x0 = b2f(row[lane]), x1 = b2f(row[64 + lane]);
    float x2 = b2f(row[128 + lane]), x3 = b2f(row[192 + lane]);
    float s0 = x0 * as_[lane] + x1 * as_[64 + lane];
    float s1 = x2 * as_[128 + lane] + x3 * as_[192 + lane];
    float d0 = x0 * ad_[lane] + x1 * ad_[64 + lane];
    float d1 = x2 * ad_[128 + lane] + x3 * ad_[192 + lane];
    for (int o = 1; o < 64; o <<= 1) {
        s0 += __shfl_xor(s0, o); s1 += __shfl_xor(s1, o);
        d0 += __shfl_xor(d0, o); d1 += __shfl_xor(d1, o);
    }
    if (lane == 0) {
        asrc[2 * w] = s0; asrc[2 * w + 1] = s1;
        adst[2 * w] = d0; adst[2 * w + 1] = d1;
    }
}

__device__ __forceinline__ float lrelu02(float x) { return x > 0.f ? x : 0.2f * x; }

__global__ __launch_bounds__(256) void agg_kernel(
    const bf16* __restrict__ xh, const float* __restrict__ asrc,
    const float* __restrict__ adst, const int* __restrict__ offs,
    const int* __restrict__ eid, const int* __restrict__ srcarr,
    const bf16* __restrict__ xprev_l, const bf16* __restrict__ xprev_r,
    const int* __restrict__ xidx, const float* __restrict__ xflt,
    const float* __restrict__ embAl, const float* __restrict__ embSl,
    const float* __restrict__ embAr, const float* __restrict__ embSr,
    const float* __restrict__ bias, bf16* __restrict__ outx) {
    int n = (blockIdx.x * blockDim.x + threadIdx.x) >> 6;
    int lane = threadIdx.x & 63;
    if (n >= N_NODES) return;
    int start = offs[n], end = offs[n + 1];
    float ad0 = adst[2 * n], ad1 = adst[2 * n + 1];

    float m0 = -1e30f, m1 = -1e30f;
    for (int j = start + lane; j < end; j += 64) {
        int id = eid[j];
        int s = (id < N_EDGES) ? srcarr[id] : (id - N_EDGES);
        m0 = fmaxf(m0, lrelu02(asrc[2 * s] + ad0));
        m1 = fmaxf(m1, lrelu02(asrc[2 * s + 1] + ad1));
    }
    for (int o = 1; o < 64; o <<= 1) {
        m0 = fmaxf(m0, __shfl_xor(m0, o));
        m1 = fmaxf(m1, __shfl_xor(m1, o));
    }
    float d0 = 0.f, d1 = 0.f;
    for (int j = start + lane; j < end; j += 64) {
        int id = eid[j];
        int s = (id < N_EDGES) ? srcarr[id] : (id - N_EDGES);
        d0 += __expf(lrelu02(asrc[2 * s] + ad0) - m0);
        d1 += __expf(lrelu02(asrc[2 * s + 1] + ad1) - m1);
    }
    for (int o = 1; o < 64; o <<= 1) {
        d0 += __shfl_xor(d0, o);
        d1 += __shfl_xor(d1, o);
    }
    float inv0 = 1.f / (d0 + 1e-16f), inv1 = 1.f / (d1 + 1e-16f);

    float ac[4] = {0.f, 0.f, 0.f, 0.f};
    bool hd1 = lane >= 32;
    for (int j = start; j < end; ++j) {
        int id = eid[j];
        int s = (id < N_EDGES) ? srcarr[id] : (id - N_EDGES);
        float al;
        if (hd1) al = __expf(lrelu02(asrc[2 * s + 1] + ad1) - m1) * inv1;
        else     al = __expf(lrelu02(asrc[2 * s] + ad0) - m0) * inv0;
        float4 v = ld4(xh + (size_t)s * 256 + lane * 4);
        ac[0] += v.x * al; ac[1] += v.y * al; ac[2] += v.z * al; ac[3] += v.w * al;
    }
    float ot[4];
#pragma unroll
    for (int t = 0; t < 4; ++t) ot[t] = __shfl_xor(ac[t], 32);
    if (lane < 32) {
        int c0 = lane * 4;
        size_t base = (size_t)n * HID + c0;
        float xl[4], xr[4];
        if (xidx) {
            int ia = xidx[2 * n], is_ = xidx[2 * n + 1];
#pragma unroll
            for (int t = 0; t < 4; ++t) {
                xl[t] = x0_val(c0 + t, ia, is_, n, embAl, embSl, xflt);
                xr[t] = x0_val(c0 + t, ia, is_, n, embAr, embSr, xflt);
            }
        } else {
#pragma unroll
            for (int t = 0; t < 4; ++t) {
                xl[t] = b2f(xprev_l[base + t]);
                xr[t] = b2f(xprev_r[base + t]);
            }
        }
#pragma unroll
        for (int t = 0; t < 4; ++t) {
            float r = 0.5f * (xl[t] + xr[t]) +
                      fmaxf(0.f, 0.5f * (ac[t] + ot[t]) + bias[c0 + t]);
            outx[base + t] = f2b(r);
        }
    }
}

// ---------------------------------------------------------------- LSTM / JK

__global__ __launch_bounds__(256) void gate_kernel(
    const float* __restrict__ G, bf16* __restrict__ h, float* __restrict__ c,
    const float* __restrict__ attw, float* __restrict__ score, int accum) {
    int w = (blockIdx.x * blockDim.x + threadIdx.x) >> 6;
    int lane = threadIdx.x & 63;
    if (w >= CH) return;
    const float* g = G + (size_t)w * G4;
    float dot = 0.f;
#pragma unroll
    for (int j = 0; j < 3; ++j) {
        int u = lane + j * 64;
        float ig = g[u], fg = g[192 + u], gg = g[384 + u], og = g[576 + u];
        float co = c[(size_t)w * H2 + u];
        float si = 1.f / (1.f + __expf(-ig));
        float sf = 1.f / (1.f + __expf(-fg));
        float so = 1.f / (1.f + __expf(-og));
        float cn = sf * co + si * tanhf(gg);
        float hn = so * tanhf(cn);
        c[(size_t)w * H2 + u] = cn;
        h[(size_t)w * H2 + u] = f2b(hn);
        dot += hn * attw[u];
    }
    for (int o = 1; o < 64; o <<= 1) dot += __shfl_xor(dot, o);
    if (lane == 0) {
        if (accum) score[w] += dot; else score[w] = dot;
    }
}

__global__ __launch_bounds__(256) void jkfin_kernel(
    const float* __restrict__ scores, const bf16* __restrict__ xs0,
    const bf16* __restrict__ xs1, const bf16* __restrict__ xs2,
    bf16* __restrict__ jk, int c0) {
    int w = (blockIdx.x * blockDim.x + threadIdx.x) >> 6;
    int lane = threadIdx.x & 63;
    if (w >= CH) return;
    float s0 = scores[w], s1 = scores[CH + w], s2 = scores[2 * CH + w];
    float m = fmaxf(s0, fmaxf(s1, s2));
    float a0 = __expf(s0 - m), a1 = __expf(s1 - m), a2 = __expf(s2 - m);
    float inv = 1.f / (a0 + a1 + a2);
    a0 *= inv; a1 *= inv; a2 *= inv;
    size_t gn = (size_t)(c0 + w) * HID + lane * 2;
#pragma unroll
    for (int t = 0; t < 2; ++t) {
        float v0 = b2f(xs0[gn + t]);
        float v1 = b2f(xs1[gn + t]);
        float v2 = b2f(xs2[gn + t]);
        jk[gn + t] = f2b(v0 * a0 + v1 * a1 + v2 * a2);
    }
}

// ---------------------------------------------------------------- final combine

__global__ __launch_bounds__(256) void final_kernel(
    const float* __restrict__ o0, const float* __restrict__ o1,
    const float* __restrict__ o2, const float* __restrict__ o3,
    const float* __restrict__ lw, float* __restrict__ out, int nloc, long long c3off) {
    int w = (blockIdx.x * blockDim.x + threadIdx.x) >> 6;
    int lane = threadIdx.x & 63;
    if (w >= nloc) return;
    size_t base = (size_t)w * HID;
    float w0 = lw[lane], w1 = lw[64 + lane];
    const float* op[4] = {o0, o1, o2, o3};
    float v[4][2];
    float s[4];
#pragma unroll
    for (int i = 0; i < 4; ++i) {
        v[i][0] = op[i][base + lane];
        v[i][1] = op[i][base + 64 + lane];
        float t = v[i][0] * w0 + v[i][1] * w1;
        for (int o = 1; o < 64; o <<= 1) t += __shfl_xor(t, o);
        s[i] = t;
    }
    float m = fmaxf(fmaxf(s[0], s[1]), fmaxf(s[2], s[3]));
    float e0 = __expf(s[0] - m), e1 = __expf(s[1] - m);
    float e2 = __expf(s[2] - m), e3 = __expf(s[3] - m);
    float inv = 1.f / (e0 + e1 + e2 + e3);
    float r0 = (v[0][0] * e0 + v[1][0] * e1 + v[2][0] * e2 + v[3][0] * e3) * inv;
    float r1 = (v[0][1] * e0 + v[1][1] * e1 + v[2][1] * e2 + v[3][1] * e3) * inv;
    size_t obase = (size_t)(c3off + w) * HID;
    out[obase + lane] = r0;
    out[obase + 64 + lane] = r1;
}

// ---------------------------------------------------------------- entry

static long long align1k(long long x) { return (x + 1023) & ~1023LL; }

extern "C" void kernel_launch(void* const* d_in, const int* in_sizes, int n_in,
                              void* d_out, int out_size, void* d_ws, size_t ws_size,
                              hipStream_t stream) {
    (void)in_sizes; (void)n_in; (void)out_size;
    const int*   x_idx   = (const int*)  d_in[0];
    const float* x_flt   = (const float*)d_in[1];
    const int*   ei_l    = (const int*)  d_in[2];
    const int*   ei_r    = (const int*)  d_in[3];
    const float* emb_aa  = (const float*)d_in[4];
    const float* emb_ss  = (const float*)d_in[5];
    const float* conv_W  = (const float*)d_in[6];
    const float* att_s   = (const float*)d_in[7];
    const float* att_d   = (const float*)d_in[8];
    const float* conv_b  = (const float*)d_in[9];
    const float* Wih     = (const float*)d_in[10];
    const float* Whh     = (const float*)d_in[11];
    const float* bih     = (const float*)d_in[12];
    const float* bhh     = (const float*)d_in[13];
    const float* jkw     = (const float*)d_in[14];
    const float* dummy_W = (const float*)d_in[16];
    const float* dummy_b = (const float*)d_in[17];
    const float* fin_W   = (const float*)d_in[18];
    const float* fin_b   = (const float*)d_in[19];
    const float* last_W  = (const float*)d_in[20];
    float* out = (float*)d_out;

    const long long S = (long long)N_NODES * HID;
    char* ws = (char*)d_ws;
    long long off = 0;

    // hist: 6 bf16 slabs (xs_l[0..2], xs_r[0..2]); stage 3 reuses as fp32 scratch
    bf16* hist = (bf16*)(ws + off);
    off += align1k(6 * S * 2);
    // R1: stage0/1 {CSR ints, asrc, adst, convWt}  |  stage2 {Gbuf, hbuf, cbuf}
    char* R1 = ws + off;
    {
        long long io4 = 2LL * (N_NODES + (N_NODES + 1) + N_NODES + EL_TOT) * 4;
        long long st01 = ((io4 + 15) & ~15LL) + 2LL * N_NODES * 4 * 2 + 6LL * 256 * 128 * 2;
        long long st2  = (long long)CH * G4 * 4 + (long long)CH * H2 * 6;
        off += align1k(st01 > st2 ? st01 : st2);
    }
    // R2: stage1 xh (N x 256 bf16) | stage2/3 jk_l,jk_r (2 x S bf16)
    char* R2 = ws + off;
    off += align1k(2 * S * 2);
    float* scores = (float*)(ws + off); off += align1k(3LL * CH * 4);
    float* bsum   = (float*)(ws + off); off += align1k(4LL * G4 * 4);
    bf16* Wih_b   = (bf16*)(ws + off); off += align1k(4LL * G4 * HID * 2);
    bf16* Whh_b   = (bf16*)(ws + off); off += align1k(4LL * G4 * H2 * 2);
    bf16* dummyWt = (bf16*)(ws + off); off += align1k(2LL * 128 * 128 * 2);
    bf16* finWt   = (bf16*)(ws + off); off += align1k(4LL * 128 * 128 * 2);

    if ((long long)ws_size < off) {   // diagnosable: 200000 + ws MiB
        float val = 200000.0f + (float)(ws_size >> 20);
        sentinel_kernel<<<(N_NODES * HID + 255) / 256, 256, 0, stream>>>(
            out, N_NODES * HID, val);
        return;
    }

    // R1 stage0/1 views
    int* ibase = (int*)R1;
    int *deg[2], *offs[2], *pos[2], *eid[2];
    long long io = 0;
    for (int b = 0; b < 2; ++b) {
        deg[b]  = ibase + io; io += N_NODES;
        offs[b] = ibase + io; io += N_NODES + 1;
        pos[b]  = ibase + io; io += N_NODES;
        eid[b]  = ibase + io; io += EL_TOT;
    }
    long long io4a = ((io * 4 + 15) & ~15LL);
    float* asrc = (float*)(R1 + io4a);
    float* adst = asrc + 2LL * N_NODES;
    bf16* convWt = (bf16*)(R1 + io4a + 2LL * N_NODES * 4 * 2);
    // R1 stage2 views
    float* Gbuf = (float*)R1;
    bf16*  hbuf = (bf16*)(Gbuf + (long long)CH * G4);
    float* cbuf = (float*)(hbuf + (long long)CH * H2);
    // R2 views
    bf16* xh  = (bf16*)R2;
    bf16* jkb = (bf16*)R2;

    const float* embA[2] = {emb_aa, emb_aa + 26 * 123};
    const float* embS[2] = {emb_ss, emb_ss + 3 * 123};

    // ---- stage 0: weight conversion + CSR
    bsum_kernel<<<12, 256, 0, stream>>>(bih, bhh, bsum);
    trans_kernel<<<(6 * 128 * 256 + 255) / 256, 256, 0, stream>>>(
        conv_W, convWt, 6, 128, 256);
    cvt_kernel<<<(4 * G4 * HID + 255) / 256, 256, 0, stream>>>(
        Wih, Wih_b, 4LL * G4 * HID);
    cvt_kernel<<<(4 * G4 * H2 + 255) / 256, 256, 0, stream>>>(
        Whh, Whh_b, 4LL * G4 * H2);
    trans_kernel<<<(2 * 128 * 128 + 255) / 256, 256, 0, stream>>>(
        dummy_W, dummyWt, 2, 128, 128);
    trans_kernel<<<(4 * 128 * 128 + 255) / 256, 256, 0, stream>>>(
        fin_W, finWt, 4, 128, 128);
    for (int b = 0; b < 2; ++b) {
        const int* ei = b ? ei_r : ei_l;
        hipMemsetAsync(deg[b], 0, N_NODES * sizeof(int), stream);
        deg_kernel<<<(EL_TOT + 255) / 256, 256, 0, stream>>>(ei + N_EDGES, deg[b]);
        scan_kernel<<<1, 1024, 0, stream>>>(deg[b], offs[b], N_NODES);
        copy_int_kernel<<<(N_NODES + 255) / 256, 256, 0, stream>>>(offs[b], pos[b], N_NODES);
        fill_kernel<<<(EL_TOT + 255) / 256, 256, 0, stream>>>(ei + N_EDGES, pos[b], eid[b]);
    }

    // ---- stage 1: 3 GAT layers x 2 branches
    for (int i = 0; i < 3; ++i) {
        for (int b = 0; b < 2; ++b) {
            const int* ei = b ? ei_r : ei_l;
            const bf16* Wc = convWt + (size_t)(b * 3 + i) * 256 * 128;
            if (i == 0) {
                dim3 g(2, (N_NODES + 127) / 128);
                mfma_gemm_x0_kernel<<<g, 256, 0, stream>>>(
                    x_idx, x_flt, embA[b], embS[b], Wc, xh, N_NODES, 256);
            } else {
                mfma_gemm<bf16>(hist + (size_t)(b * 3 + i - 1) * S, Wc, 128,
                                nullptr, nullptr, 0, xh, nullptr, N_NODES, 256, stream);
            }
            att_kernel<<<25000, 256, 0, stream>>>(
                xh, att_s + (size_t)(b * 3 + i) * 2 * HID,
                att_d + (size_t)(b * 3 + i) * 2 * HID, asrc, adst);
            const bf16* xpl = (i == 0) ? nullptr : hist + (size_t)(i - 1) * S;
            const bf16* xpr = (i == 0) ? nullptr : hist + (size_t)(3 + i - 1) * S;
            agg_kernel<<<25000, 256, 0, stream>>>(
                xh, asrc, adst, offs[b], eid[b], ei, xpl, xpr,
                (i == 0) ? x_idx : nullptr, x_flt,
                embA[0], embS[0], embA[1], embS[1],
                conv_b + (size_t)(b * 3 + i) * HID, hist + (size_t)(b * 3 + i) * S);
        }
    }

    // ---- stage 2: bi-LSTM JK (fused ih+hh GEMM per step)
    for (int b = 0; b < 2; ++b) {
        for (int c0 = 0; c0 < N_NODES; c0 += CH) {
            for (int dir = 0; dir < 2; ++dir) {
                hipMemsetAsync(hbuf, 0, (size_t)CH * H2 * 6, stream);  // h(2B)+c(4B)
                const bf16* Wi = Wih_b + (size_t)(b * 2 + dir) * G4 * HID;
                const bf16* Wh = Whh_b + (size_t)(b * 2 + dir) * G4 * H2;
                const float* bs = bsum + (size_t)(b * 2 + dir) * G4;
                const float* aw = jkw + (size_t)b * 2 * H2 + (size_t)dir * H2;
                for (int st = 0; st < 3; ++st) {
                    int l = dir ? (2 - st) : st;
                    const bf16* A = hist + (size_t)(b * 3 + l) * S + (size_t)c0 * HID;
                    mfma_gemm<float>(A, Wi, 128, hbuf, Wh, H2, Gbuf, bs, CH, G4, stream);
                    gate_kernel<<<(CH + 3) / 4, 256, 0, stream>>>(
                        Gbuf, hbuf, cbuf, aw, scores + (size_t)l * CH, dir);
                }
            }
            jkfin_kernel<<<(CH + 3) / 4, 256, 0, stream>>>(
                scores, hist + (size_t)b * 3 * S, hist + (size_t)(b * 3 + 1) * S,
                hist + (size_t)(b * 3 + 2) * S, jkb + (size_t)b * S, c0);
        }
    }

    // ---- stage 3: sq, outs, final combine (scratch = freed hist region)
    float* f3 = (float*)hist;
    bf16* jkl = jkb; bf16* jkr = jkb + S;
    for (long long c3 = 0; c3 < N_NODES; c3 += CH3) {
        int Rr = (int)((N_NODES - c3) < CH3 ? (N_NODES - c3) : CH3);
        float* o0 = f3;
        float* o1 = f3 + 1LL * CH3 * HID;
        float* o2 = f3 + 2LL * CH3 * HID;
        float* o3 = f3 + 3LL * CH3 * HID;
        bf16* sql = (bf16*)(f3 + 4LL * CH3 * HID);
        bf16* sqr = sql + (long long)CH3 * HID;
        mfma_gemm<bf16>(jkl + c3 * HID, dummyWt, 128, nullptr, nullptr, 0,
                        sql, dummy_b, Rr, 128, stream);
        mfma_gemm<bf16>(jkr + c3 * HID, dummyWt + 16384, 128, nullptr, nullptr, 0,
                        sqr, dummy_b + 128, Rr, 128, stream);
        mfma_gemm<float>(jkl + c3 * HID, finWt, 128, nullptr, nullptr, 0,
                         o0, fin_b, Rr, 128, stream);
        mfma_gemm<float>(sql, finWt + 16384, 128, nullptr, nullptr, 0,
                         o1, fin_b + 128, Rr, 128, stream);
        mfma_gemm<float>(jkr + c3 * HID, finWt + 2 * 16384, 128, nullptr, nullptr, 0,
                         o2, fin_b + 256, Rr, 128, stream);
        mfma_gemm<float>(sqr, finWt + 3 * 16384, 128, nullptr, nullptr, 0,
                         o3, fin_b + 384, Rr, 128, stream);
        final_kernel<<<(Rr + 3) / 4, 256, 0, stream>>>(
            o0, o1, o2, o3, last_W, out, Rr, c3);
    }
}

// Round 5
// 5327.088 us; speedup vs baseline: 4.9324x; 1.2642x over previous
//
#include <hip/hip_runtime.h>
#include <cstddef>
#include <cstdint>

#define N_NODES 100000
#define N_EDGES 800000
#define EL_TOT  900000      // edges + self loops
#define HID 128
#define H2  192
#define G4  768             // 4*H2
#define CH  25000           // LSTM node chunk (divides N_NODES)
#define CH3 50000           // stage-3 chunk
#define BK  32
#define LDST 40             // LDS row stride in bf16 elems

typedef unsigned short bf16;
typedef __attribute__((ext_vector_type(8))) short bf16x8v;
typedef __attribute__((ext_vector_type(4))) float f32x4v;

// ---------------------------------------------------------------- dtype helpers

__device__ __forceinline__ float b2f(bf16 u) {
    return __uint_as_float(((unsigned)u) << 16);
}
__device__ __forceinline__ bf16 f2b(float f) {   // round-nearest-even
    unsigned u = __float_as_uint(f);
    u += 0x7FFFu + ((u >> 16) & 1u);
    return (bf16)(u >> 16);
}
__device__ __forceinline__ void stE(float* p, size_t i, float v) { p[i] = v; }
__device__ __forceinline__ void stE(bf16* p, size_t i, float v) { p[i] = f2b(v); }
__device__ __forceinline__ float4 ld4(const bf16* p) {
    ushort4 u = *(const ushort4*)p;
    return make_float4(b2f(u.x), b2f(u.y), b2f(u.z), b2f(u.w));
}
__device__ __forceinline__ float ftanh(float x) {
    float cx = fminf(fmaxf(x, -15.f), 15.f);
    float e = __expf(2.f * cx);
    return (e - 1.f) / (e + 1.f);
}

// x0 recompute: column c of node n for one branch
__device__ __forceinline__ float x0_val(int c, int ia, int is_, int n,
                                        const float* __restrict__ embA,
                                        const float* __restrict__ embS,
                                        const float* __restrict__ xflt) {
    return (c < 123) ? (embA[ia * 123 + c] + embS[is_ * 123 + c])
                     : xflt[n * 5 + (c - 123)];
}

// LSTM gate-column permutation: new col j -> orig gate row
__device__ __forceinline__ int lstm_perm(int j) {
    int w = j & 63, tt = j >> 6;
    return (w >> 4) * 192 + tt * 16 + (w & 15);   // gate*192 + unit
}

// ---------------------------------------------------------------- utilities

__global__ void sentinel_kernel(float* out, int n, float val) {
    int t = blockIdx.x * blockDim.x + threadIdx.x;
    if (t < n) out[t] = val;
}

__global__ void bsum_perm_kernel(const float* __restrict__ bih,
                                 const float* __restrict__ bhh,
                                 float* __restrict__ bsum) {
    int t = blockIdx.x * blockDim.x + threadIdx.x;
    if (t >= 4 * G4) return;
    int d = t / G4, j = t % G4;
    int orig = lstm_perm(j);
    bsum[t] = bih[d * G4 + orig] + bhh[d * G4 + orig];
}

// permute gate rows + convert to bf16: out[d][j][k] = in[d][perm(j)][k]
__global__ void lstm_w_perm_kernel(const float* __restrict__ in,
                                   bf16* __restrict__ out, int K) {
    long long t = (long long)blockIdx.x * blockDim.x + threadIdx.x;
    long long tot = 4LL * G4 * K;
    if (t >= tot) return;
    int k = (int)(t % K);
    int j = (int)((t / K) % G4);
    int d = (int)(t / ((long long)G4 * K));
    int orig = lstm_perm(j);
    out[t] = f2b(in[((size_t)d * G4 + orig) * K + k]);
}

// out[bt][m][k] = in[bt][k][m]  ((K,M) -> (M,K) bf16)
__global__ void trans_kernel(const float* __restrict__ in, bf16* __restrict__ out,
                             int batch, int K, int M) {
    long long t = (long long)blockIdx.x * blockDim.x + threadIdx.x;
    long long tot = (long long)batch * K * M;
    if (t >= tot) return;
    int per = K * M;
    int bt = (int)(t / per);
    int rem = (int)(t % per);
    int m = rem / K, k = rem % K;
    out[t] = f2b(in[(size_t)bt * per + (size_t)k * M + m]);
}

// ---------------------------------------------------------------- CSR build

__global__ void deg_kernel(const int* __restrict__ dst, int* __restrict__ deg) {
    int t = blockIdx.x * blockDim.x + threadIdx.x;
    if (t >= EL_TOT) return;
    int d = (t < N_EDGES) ? dst[t] : (t - N_EDGES);
    atomicAdd(&deg[d], 1);
}

__global__ void scan_kernel(const int* __restrict__ deg, int* __restrict__ offs, int n) {
    __shared__ int sdata[1024];
    __shared__ int carry;
    if (threadIdx.x == 0) carry = 0;
    __syncthreads();
    for (int base = 0; base < n; base += 1024) {
        int i = base + (int)threadIdx.x;
        int v = (i < n) ? deg[i] : 0;
        sdata[threadIdx.x] = v;
        __syncthreads();
        for (int off = 1; off < 1024; off <<= 1) {
            int t = (threadIdx.x >= (unsigned)off) ? sdata[threadIdx.x - off] : 0;
            __syncthreads();
            sdata[threadIdx.x] += t;
            __syncthreads();
        }
        if (i < n) offs[i + 1] = carry + sdata[threadIdx.x];
        __syncthreads();
        if (threadIdx.x == 1023) carry += sdata[1023];
        __syncthreads();
    }
    if (threadIdx.x == 0) offs[0] = 0;
}

__global__ void copy_int_kernel(const int* __restrict__ a, int* __restrict__ b, int n) {
    int t = blockIdx.x * blockDim.x + threadIdx.x;
    if (t < n) b[t] = a[t];
}

__global__ void fill_kernel(const int* __restrict__ dst, int* __restrict__ pos,
                            int* __restrict__ eid) {
    int t = blockIdx.x * blockDim.x + threadIdx.x;
    if (t >= EL_TOT) return;
    int d = (t < N_EDGES) ? dst[t] : (t - N_EDGES);
    int p = atomicAdd(&pos[d], 1);
    eid[p] = t;
}

// ---------------------------------------------------------------- MFMA GEMM
// C(RxM) = A1(RxK1) @ B1t(MxK1)^T [+ A2(RxK2) @ B2t(MxK2)^T] + bias[col]
template<typename TC>
__global__ __launch_bounds__(256) void mfma_gemm_kernel(
    const bf16* __restrict__ A1, const bf16* __restrict__ B1, int K1,
    const bf16* __restrict__ A2, const bf16* __restrict__ B2, int K2,
    TC* __restrict__ C, const float* __restrict__ bias, int R, int M) {
    __shared__ bf16 As[128 * LDST];
    __shared__ bf16 Bs[128 * LDST];
    const int tid = threadIdx.x;
    const int lane = tid & 63;
    const int wave = tid >> 6;
    const int wm = (wave & 1) * 64, wn = (wave >> 1) * 64;
    const int bm0 = blockIdx.y * 128, bn0 = blockIdx.x * 128;
    const int l15 = lane & 15;
    const int q8 = (lane >> 4) * 8;
    const int srow = tid >> 2;
    const int scol = (tid & 3) * 8;

    f32x4v acc[4][4];
#pragma unroll
    for (int i = 0; i < 4; ++i)
#pragma unroll
        for (int j = 0; j < 4; ++j) acc[i][j] = (f32x4v)(0.0f);

    auto panel = [&](const bf16* Ap, const bf16* Bp, int K) {
        for (int k0 = 0; k0 < K; k0 += BK) {
#pragma unroll
            for (int rnd = 0; rnd < 2; ++rnd) {
                int row = srow + rnd * 64;
                int ga = bm0 + row; ga = (ga < R) ? ga : (R - 1);
                int4 va = *(const int4*)(Ap + (size_t)ga * K + k0 + scol);
                *(int4*)&As[row * LDST + scol] = va;
                int4 vb = *(const int4*)(Bp + (size_t)(bn0 + row) * K + k0 + scol);
                *(int4*)&Bs[row * LDST + scol] = vb;
            }
            __syncthreads();
            bf16x8v af[4], bfv[4];
#pragma unroll
            for (int i = 0; i < 4; ++i) {
                af[i]  = *(const bf16x8v*)&As[(wm + i * 16 + l15) * LDST + q8];
                bfv[i] = *(const bf16x8v*)&Bs[(wn + i * 16 + l15) * LDST + q8];
            }
#pragma unroll
            for (int i = 0; i < 4; ++i)
#pragma unroll
                for (int j = 0; j < 4; ++j)
                    acc[i][j] = __builtin_amdgcn_mfma_f32_16x16x32_bf16(
                        af[i], bfv[j], acc[i][j], 0, 0, 0);
            __syncthreads();
        }
    };
    panel(A1, B1, K1);
    if (A2) panel(A2, B2, K2);

#pragma unroll
    for (int i = 0; i < 4; ++i) {
        const int row0 = bm0 + wm + i * 16 + (lane >> 4) * 4;
#pragma unroll
        for (int j = 0; j < 4; ++j) {
            const int col = bn0 + wn + j * 16 + l15;
            const float bv = bias ? bias[col] : 0.f;
#pragma unroll
            for (int r = 0; r < 4; ++r) {
                const int gr = row0 + r;
                if (gr < R) stE(C, (size_t)gr * M + col, acc[i][j][r] + bv);
            }
        }
    }
}

template<typename TC>
static void mfma_gemm(const bf16* A1, const bf16* B1, int K1,
                      const bf16* A2, const bf16* B2, int K2,
                      TC* C, const float* bias, int R, int M, hipStream_t s) {
    dim3 g(M / 128, (R + 127) / 128);
    mfma_gemm_kernel<TC><<<g, 256, 0, s>>>(A1, B1, K1, A2, B2, K2, C, bias, R, M);
}

// ---------------------------------------------------------------- fused LSTM GEMM
// Gates G = A1@Wih_perm^T [+ h@Whh_perm^T] + bias_perm, fully in-register.
// Permuted col j: tile64*64 + gate*16 + unitlocal -> lane's 4 j-frags are
// i,f,g,o of ONE unit. Epilogue does the LSTM cell + JK score partial.
__global__ __launch_bounds__(256) void lstm_gemm_kernel(
    const bf16* __restrict__ A1, const bf16* __restrict__ B1,
    const bf16* __restrict__ A2, const bf16* __restrict__ B2,
    const float* __restrict__ bias, float* __restrict__ c_state,
    bf16* __restrict__ h_out, const float* __restrict__ aw,
    float* __restrict__ score, int R) {
    __shared__ bf16 As[128 * LDST];
    __shared__ bf16 Bs[128 * LDST];
    const int tid = threadIdx.x;
    const int lane = tid & 63;
    const int wave = tid >> 6;
    const int wm = (wave & 1) * 64, wn = (wave >> 1) * 64;
    const int bm0 = blockIdx.y * 128, bn0 = blockIdx.x * 128;
    const int l15 = lane & 15;
    const int q = lane >> 4;
    const int q8 = q * 8;
    const int srow = tid >> 2;
    const int scol = (tid & 3) * 8;

    f32x4v acc[4][4];
#pragma unroll
    for (int i = 0; i < 4; ++i)
#pragma unroll
        for (int j = 0; j < 4; ++j) acc[i][j] = (f32x4v)(0.0f);

    auto panel = [&](const bf16* Ap, const bf16* Bp, int K) {
        for (int k0 = 0; k0 < K; k0 += BK) {
#pragma unroll
            for (int rnd = 0; rnd < 2; ++rnd) {
                int row = srow + rnd * 64;
                int ga = bm0 + row; ga = (ga < R) ? ga : (R - 1);
                int4 va = *(const int4*)(Ap + (size_t)ga * K + k0 + scol);
                *(int4*)&As[row * LDST + scol] = va;
                int4 vb = *(const int4*)(Bp + (size_t)(bn0 + row) * K + k0 + scol);
                *(int4*)&Bs[row * LDST + scol] = vb;
            }
            __syncthreads();
            bf16x8v af[4], bfv[4];
#pragma unroll
            for (int i = 0; i < 4; ++i) {
                af[i]  = *(const bf16x8v*)&As[(wm + i * 16 + l15) * LDST + q8];
                bfv[i] = *(const bf16x8v*)&Bs[(wn + i * 16 + l15) * LDST + q8];
            }
#pragma unroll
            for (int i = 0; i < 4; ++i)
#pragma unroll
                for (int j = 0; j < 4; ++j)
                    acc[i][j] = __builtin_amdgcn_mfma_f32_16x16x32_bf16(
                        af[i], bfv[j], acc[i][j], 0, 0, 0);
            __syncthreads();
        }
    };
    panel(A1, B1, 128);
    if (A2) panel(A2, B2, H2);

    // ---- fused LSTM cell epilogue
    const int u = ((bn0 + wn) >> 6) * 16 + l15;      // hidden unit 0..191
    const float awu = aw[u];
    float bv[4];
#pragma unroll
    for (int j = 0; j < 4; ++j) bv[j] = bias[bn0 + wn + j * 16 + l15];
    float psum[4][4];
#pragma unroll
    for (int i = 0; i < 4; ++i) {
        const int row0 = bm0 + wm + i * 16 + q * 4;
#pragma unroll
        for (int r = 0; r < 4; ++r) {
            const int gr = row0 + r;
            const bool ok = gr < R;
            float ig = acc[i][0][r] + bv[0];
            float fg = acc[i][1][r] + bv[1];
            float gg = acc[i][2][r] + bv[2];
            float og = acc[i][3][r] + bv[3];
            float si = 1.f / (1.f + __expf(-ig));
            float sf = 1.f / (1.f + __expf(-fg));
            float so = 1.f / (1.f + __expf(-og));
            float co = ok ? c_state[(size_t)gr * H2 + u] : 0.f;
            float cn = sf * co + si * ftanh(gg);
            float hn = so * ftanh(cn);
            if (ok) {
                c_state[(size_t)gr * H2 + u] = cn;
                h_out[(size_t)gr * H2 + u] = f2b(hn);
            }
            psum[i][r] = hn * awu;
        }
    }
#pragma unroll
    for (int m = 1; m < 16; m <<= 1)
#pragma unroll
        for (int i = 0; i < 4; ++i)
#pragma unroll
            for (int r = 0; r < 4; ++r)
                psum[i][r] += __shfl_xor(psum[i][r], m);
    if (l15 == 0) {
#pragma unroll
        for (int i = 0; i < 4; ++i)
#pragma unroll
            for (int r = 0; r < 4; ++r) {
                const int gr = bm0 + wm + i * 16 + q * 4 + r;
                if (gr < R) atomicAdd(&score[gr], psum[i][r]);
            }
    }
}

// Layer-0 conv GEMM: A built on the fly from embeddings (K=128 fixed)
__global__ __launch_bounds__(256) void mfma_gemm_x0_kernel(
    const int* __restrict__ xidx, const float* __restrict__ xflt,
    const float* __restrict__ embA, const float* __restrict__ embS,
    const bf16* __restrict__ B1, bf16* __restrict__ C, int R, int M) {
    __shared__ bf16 As[128 * LDST];
    __shared__ bf16 Bs[128 * LDST];
    const int tid = threadIdx.x;
    const int lane = tid & 63;
    const int wave = tid >> 6;
    const int wm = (wave & 1) * 64, wn = (wave >> 1) * 64;
    const int bm0 = blockIdx.y * 128, bn0 = blockIdx.x * 128;
    const int l15 = lane & 15;
    const int q8 = (lane >> 4) * 8;
    const int srow = tid >> 2;
    const int scol = (tid & 3) * 8;

    f32x4v acc[4][4];
#pragma unroll
    for (int i = 0; i < 4; ++i)
#pragma unroll
        for (int j = 0; j < 4; ++j) acc[i][j] = (f32x4v)(0.0f);

    for (int k0 = 0; k0 < 128; k0 += BK) {
#pragma unroll
        for (int rnd = 0; rnd < 2; ++rnd) {
            int row = srow + rnd * 64;
            int ga = bm0 + row; ga = (ga < R) ? ga : (R - 1);
            int ia = xidx[2 * ga], is_ = xidx[2 * ga + 1];
            bf16 tmp[8];
#pragma unroll
            for (int t = 0; t < 8; ++t)
                tmp[t] = f2b(x0_val(k0 + scol + t, ia, is_, ga, embA, embS, xflt));
            *(int4*)&As[row * LDST + scol] = *(const int4*)tmp;
            int4 vb = *(const int4*)(B1 + (size_t)(bn0 + row) * 128 + k0 + scol);
            *(int4*)&Bs[row * LDST + scol] = vb;
        }
        __syncthreads();
        bf16x8v af[4], bfv[4];
#pragma unroll
        for (int i = 0; i < 4; ++i) {
            af[i]  = *(const bf16x8v*)&As[(wm + i * 16 + l15) * LDST + q8];
            bfv[i] = *(const bf16x8v*)&Bs[(wn + i * 16 + l15) * LDST + q8];
        }
#pragma unroll
        for (int i = 0; i < 4; ++i)
#pragma unroll
            for (int j = 0; j < 4; ++j)
                acc[i][j] = __builtin_amdgcn_mfma_f32_16x16x32_bf16(
                    af[i], bfv[j], acc[i][j], 0, 0, 0);
        __syncthreads();
    }
#pragma unroll
    for (int i = 0; i < 4; ++i) {
        const int row0 = bm0 + wm + i * 16 + (lane >> 4) * 4;
#pragma unroll
        for (int j = 0; j < 4; ++j) {
            const int col = bn0 + wn + j * 16 + l15;
#pragma unroll
            for (int r = 0; r < 4; ++r) {
                const int gr = row0 + r;
                if (gr < R) C[(size_t)gr * M + col] = f2b(acc[i][j][r]);
            }
        }
    }
}

// ---------------------------------------------------------------- GAT pieces

__global__ __launch_bounds__(256) void att_kernel(
    const bf16* __restrict__ xh, const float* __restrict__ as_,
    const float* __restrict__ ad_, float* __restrict__ asrc, float* __restrict__ adst) {
    int w = (blockIdx.x * blockDim.x + threadIdx.x) >> 6;
    int lane = threadIdx.x & 63;
    if (w >= N_NODES) return;
    const bf16* row = xh + (size_t)w * 256;
    float x0 = b2f(row[lane]), x1 = b2f(row[64 + lane]);
    float x2 = b2f(row[128 + lane]), x3 = b2f(row[192 + lane]);
    float s0 = x0 * as_[lane] + x1 * as_[64 + lane];
    float s1 = x2 * as_[128 + lane] + x3 * as_[192 + lane];
    float d0 = x0 * ad_[lane] + x1 * ad_[64 + lane];
    float d1 = x2 * ad_[128 + lane] + x3 * ad_[192 + lane];
    for (int o = 1; o < 64; o <<= 1) {
        s0 += __shfl_xor(s0, o); s1 += __shfl_xor(s1, o);
        d0 += __shfl_xor(d0, o); d1 += __shfl_xor(d1, o);
    }
    if (lane == 0) {
        asrc[2 * w] = s0; asrc[2 * w + 1] = s1;
        adst[2 * w] = d0; adst[2 * w + 1] = d1;
    }
}

__device__ __forceinline__ float lrelu02(float x) { return x > 0.f ? x : 0.2f * x; }

__global__ __launch_bounds__(256) void agg_kernel(
    const bf16* __restrict__ xh, const float* __restrict__ asrc,
    const float* __restrict__ adst, const int* __restrict__ offs,
    const int* __restrict__ eid, const int* __restrict__ srcarr,
    const bf16* __restrict__ xprev_l, const bf16* __restrict__ xprev_r,
    const int* __restrict__ xidx, const float* __restrict__ xflt,
    const float* __restrict__ embAl, const float* __restrict__ embSl,
    const float* __restrict__ embAr, const float* __restrict__ embSr,
    const float* __restrict__ bias, bf16* __restrict__ outx) {
    int n = (blockIdx.x * blockDim.x + threadIdx.x) >> 6;
    int lane = threadIdx.x & 63;
    if (n >= N_NODES) return;
    int start = offs[n], end = offs[n + 1];
    float ad0 = adst[2 * n], ad1 = adst[2 * n + 1];

    float m0 = -1e30f, m1 = -1e30f;
    for (int j = start + lane; j < end; j += 64) {
        int id = eid[j];
        int s = (id < N_EDGES) ? srcarr[id] : (id - N_EDGES);
        m0 = fmaxf(m0, lrelu02(asrc[2 * s] + ad0));
        m1 = fmaxf(m1, lrelu02(asrc[2 * s + 1] + ad1));
    }
    for (int o = 1; o < 64; o <<= 1) {
        m0 = fmaxf(m0, __shfl_xor(m0, o));
        m1 = fmaxf(m1, __shfl_xor(m1, o));
    }
    float d0 = 0.f, d1 = 0.f;
    for (int j = start + lane; j < end; j += 64) {
        int id = eid[j];
        int s = (id < N_EDGES) ? srcarr[id] : (id - N_EDGES);
        d0 += __expf(lrelu02(asrc[2 * s] + ad0) - m0);
        d1 += __expf(lrelu02(asrc[2 * s + 1] + ad1) - m1);
    }
    for (int o = 1; o < 64; o <<= 1) {
        d0 += __shfl_xor(d0, o);
        d1 += __shfl_xor(d1, o);
    }
    float inv0 = 1.f / (d0 + 1e-16f), inv1 = 1.f / (d1 + 1e-16f);

    float ac[4] = {0.f, 0.f, 0.f, 0.f};
    bool hd1 = lane >= 32;
    for (int j = start; j < end; ++j) {
        int id = eid[j];
        int s = (id < N_EDGES) ? srcarr[id] : (id - N_EDGES);
        float al;
        if (hd1) al = __expf(lrelu02(asrc[2 * s + 1] + ad1) - m1) * inv1;
        else     al = __expf(lrelu02(asrc[2 * s] + ad0) - m0) * inv0;
        float4 v = ld4(xh + (size_t)s * 256 + lane * 4);
        ac[0] += v.x * al; ac[1] += v.y * al; ac[2] += v.z * al; ac[3] += v.w * al;
    }
    float ot[4];
#pragma unroll
    for (int t = 0; t < 4; ++t) ot[t] = __shfl_xor(ac[t], 32);
    if (lane < 32) {
        int c0 = lane * 4;
        size_t base = (size_t)n * HID + c0;
        float xl[4], xr[4];
        if (xidx) {
            int ia = xidx[2 * n], is_ = xidx[2 * n + 1];
#pragma unroll
            for (int t = 0; t < 4; ++t) {
                xl[t] = x0_val(c0 + t, ia, is_, n, embAl, embSl, xflt);
                xr[t] = x0_val(c0 + t, ia, is_, n, embAr, embSr, xflt);
            }
        } else {
#pragma unroll
            for (int t = 0; t < 4; ++t) {
                xl[t] = b2f(xprev_l[base + t]);
                xr[t] = b2f(xprev_r[base + t]);
            }
        }
#pragma unroll
        for (int t = 0; t < 4; ++t) {
            float r = 0.5f * (xl[t] + xr[t]) +
                      fmaxf(0.f, 0.5f * (ac[t] + ot[t]) + bias[c0 + t]);
            outx[base + t] = f2b(r);
        }
    }
}

// ---------------------------------------------------------------- JK / final

__global__ __launch_bounds__(256) void jkfin_kernel(
    const float* __restrict__ scores, const bf16* __restrict__ xs0,
    const bf16* __restrict__ xs1, const bf16* __restrict__ xs2,
    bf16* __restrict__ jk, int c0) {
    int w = (blockIdx.x * blockDim.x + threadIdx.x) >> 6;
    int lane = threadIdx.x & 63;
    if (w >= CH) return;
    float s0 = scores[w], s1 = scores[CH + w], s2 = scores[2 * CH + w];
    float m = fmaxf(s0, fmaxf(s1, s2));
    float a0 = __expf(s0 - m), a1 = __expf(s1 - m), a2 = __expf(s2 - m);
    float inv = 1.f / (a0 + a1 + a2);
    a0 *= inv; a1 *= inv; a2 *= inv;
    size_t gn = (size_t)(c0 + w) * HID + lane * 2;
#pragma unroll
    for (int t = 0; t < 2; ++t) {
        float v0 = b2f(xs0[gn + t]);
        float v1 = b2f(xs1[gn + t]);
        float v2 = b2f(xs2[gn + t]);
        jk[gn + t] = f2b(v0 * a0 + v1 * a1 + v2 * a2);
    }
}

__global__ __launch_bounds__(256) void final_kernel(
    const float* __restrict__ o0, const float* __restrict__ o1,
    const float* __restrict__ o2, const float* __restrict__ o3,
    const float* __restrict__ lw, float* __restrict__ out, int nloc, long long c3off) {
    int w = (blockIdx.x * blockDim.x + threadIdx.x) >> 6;
    int lane = threadIdx.x & 63;
    if (w >= nloc) return;
    size_t base = (size_t)w * HID;
    float w0 = lw[lane], w1 = lw[64 + lane];
    const float* op[4] = {o0, o1, o2, o3};
    float v[4][2];
    float s[4];
#pragma unroll
    for (int i = 0; i < 4; ++i) {
        v[i][0] = op[i][base + lane];
        v[i][1] = op[i][base + 64 + lane];
        float t = v[i][0] * w0 + v[i][1] * w1;
        for (int o = 1; o < 64; o <<= 1) t += __shfl_xor(t, o);
        s[i] = t;
    }
    float m = fmaxf(fmaxf(s[0], s[1]), fmaxf(s[2], s[3]));
    float e0 = __expf(s[0] - m), e1 = __expf(s[1] - m);
    float e2 = __expf(s[2] - m), e3 = __expf(s[3] - m);
    float inv = 1.f / (e0 + e1 + e2 + e3);
    float r0 = (v[0][0] * e0 + v[1][0] * e1 + v[2][0] * e2 + v[3][0] * e3) * inv;
    float r1 = (v[0][1] * e0 + v[1][1] * e1 + v[2][1] * e2 + v[3][1] * e3) * inv;
    size_t obase = (size_t)(c3off + w) * HID;
    out[obase + lane] = r0;
    out[obase + 64 + lane] = r1;
}

// ---------------------------------------------------------------- entry

static long long align1k(long long x) { return (x + 1023) & ~1023LL; }

extern "C" void kernel_launch(void* const* d_in, const int* in_sizes, int n_in,
                              void* d_out, int out_size, void* d_ws, size_t ws_size,
                              hipStream_t stream) {
    (void)in_sizes; (void)n_in; (void)out_size;
    const int*   x_idx   = (const int*)  d_in[0];
    const float* x_flt   = (const float*)d_in[1];
    const int*   ei_l    = (const int*)  d_in[2];
    const int*   ei_r    = (const int*)  d_in[3];
    const float* emb_aa  = (const float*)d_in[4];
    const float* emb_ss  = (const float*)d_in[5];
    const float* conv_W  = (const float*)d_in[6];
    const float* att_s   = (const float*)d_in[7];
    const float* att_d   = (const float*)d_in[8];
    const float* conv_b  = (const float*)d_in[9];
    const float* Wih     = (const float*)d_in[10];
    const float* Whh     = (const float*)d_in[11];
    const float* bih     = (const float*)d_in[12];
    const float* bhh     = (const float*)d_in[13];
    const float* jkw     = (const float*)d_in[14];
    const float* dummy_W = (const float*)d_in[16];
    const float* dummy_b = (const float*)d_in[17];
    const float* fin_W   = (const float*)d_in[18];
    const float* fin_b   = (const float*)d_in[19];
    const float* last_W  = (const float*)d_in[20];
    float* out = (float*)d_out;

    const long long S = (long long)N_NODES * HID;
    char* ws = (char*)d_ws;
    long long off = 0;

    // hist: 6 bf16 slabs; stage 3 reuses as fp32 scratch
    bf16* hist = (bf16*)(ws + off);
    off += align1k(6 * S * 2);
    // R1: stage0/1 {CSR ints, asrc, adst, convWt} | stage2 {hbuf, cbuf}
    char* R1 = ws + off;
    {
        long long io4 = 2LL * (N_NODES + (N_NODES + 1) + N_NODES + EL_TOT) * 4;
        long long st01 = ((io4 + 15) & ~15LL) + 2LL * N_NODES * 4 * 2 + 6LL * 256 * 128 * 2;
        long long st2  = (long long)CH * H2 * 2 + (long long)CH * H2 * 4;
        off += align1k(st01 > st2 ? st01 : st2);
    }
    // R2: stage1 xh (N x 256 bf16) | stage2/3 jk_l,jk_r (2 x S bf16)
    char* R2 = ws + off;
    off += align1k(2 * S * 2);
    float* scores = (float*)(ws + off); off += align1k(3LL * CH * 4);
    float* bsum   = (float*)(ws + off); off += align1k(4LL * G4 * 4);
    bf16* Wih_b   = (bf16*)(ws + off); off += align1k(4LL * G4 * HID * 2);
    bf16* Whh_b   = (bf16*)(ws + off); off += align1k(4LL * G4 * H2 * 2);
    bf16* dummyWt = (bf16*)(ws + off); off += align1k(2LL * 128 * 128 * 2);
    bf16* finWt   = (bf16*)(ws + off); off += align1k(4LL * 128 * 128 * 2);

    if ((long long)ws_size < off) {   // diagnosable: 200000 + ws MiB
        float val = 200000.0f + (float)(ws_size >> 20);
        sentinel_kernel<<<(N_NODES * HID + 255) / 256, 256, 0, stream>>>(
            out, N_NODES * HID, val);
        return;
    }

    // R1 stage0/1 views
    int* ibase = (int*)R1;
    int *deg[2], *offs[2], *pos[2], *eid[2];
    long long io = 0;
    for (int b = 0; b < 2; ++b) {
        deg[b]  = ibase + io; io += N_NODES;
        offs[b] = ibase + io; io += N_NODES + 1;
        pos[b]  = ibase + io; io += N_NODES;
        eid[b]  = ibase + io; io += EL_TOT;
    }
    long long io4a = ((io * 4 + 15) & ~15LL);
    float* asrc = (float*)(R1 + io4a);
    float* adst = asrc + 2LL * N_NODES;
    bf16* convWt = (bf16*)(R1 + io4a + 2LL * N_NODES * 4 * 2);
    // R1 stage2 views
    bf16*  hbuf = (bf16*)R1;
    float* cbuf = (float*)(R1 + (long long)CH * H2 * 2);
    // R2 views
    bf16* xh  = (bf16*)R2;
    bf16* jkb = (bf16*)R2;

    const float* embA[2] = {emb_aa, emb_aa + 26 * 123};
    const float* embS[2] = {emb_ss, emb_ss + 3 * 123};

    // ---- stage 0: weight conversion (LSTM weights gate-permuted) + CSR
    bsum_perm_kernel<<<12, 256, 0, stream>>>(bih, bhh, bsum);
    trans_kernel<<<(6 * 128 * 256 + 255) / 256, 256, 0, stream>>>(
        conv_W, convWt, 6, 128, 256);
    lstm_w_perm_kernel<<<(4 * G4 * HID + 255) / 256, 256, 0, stream>>>(
        Wih, Wih_b, HID);
    lstm_w_perm_kernel<<<(4 * G4 * H2 + 255) / 256, 256, 0, stream>>>(
        Whh, Whh_b, H2);
    trans_kernel<<<(2 * 128 * 128 + 255) / 256, 256, 0, stream>>>(
        dummy_W, dummyWt, 2, 128, 128);
    trans_kernel<<<(4 * 128 * 128 + 255) / 256, 256, 0, stream>>>(
        fin_W, finWt, 4, 128, 128);
    for (int b = 0; b < 2; ++b) {
        const int* ei = b ? ei_r : ei_l;
        hipMemsetAsync(deg[b], 0, N_NODES * sizeof(int), stream);
        deg_kernel<<<(EL_TOT + 255) / 256, 256, 0, stream>>>(ei + N_EDGES, deg[b]);
        scan_kernel<<<1, 1024, 0, stream>>>(deg[b], offs[b], N_NODES);
        copy_int_kernel<<<(N_NODES + 255) / 256, 256, 0, stream>>>(offs[b], pos[b], N_NODES);
        fill_kernel<<<(EL_TOT + 255) / 256, 256, 0, stream>>>(ei + N_EDGES, pos[b], eid[b]);
    }

    // ---- stage 1: 3 GAT layers x 2 branches
    for (int i = 0; i < 3; ++i) {
        for (int b = 0; b < 2; ++b) {
            const int* ei = b ? ei_r : ei_l;
            const bf16* Wc = convWt + (size_t)(b * 3 + i) * 256 * 128;
            if (i == 0) {
                dim3 g(2, (N_NODES + 127) / 128);
                mfma_gemm_x0_kernel<<<g, 256, 0, stream>>>(
                    x_idx, x_flt, embA[b], embS[b], Wc, xh, N_NODES, 256);
            } else {
                mfma_gemm<bf16>(hist + (size_t)(b * 3 + i - 1) * S, Wc, 128,
                                nullptr, nullptr, 0, xh, nullptr, N_NODES, 256, stream);
            }
            att_kernel<<<25000, 256, 0, stream>>>(
                xh, att_s + (size_t)(b * 3 + i) * 2 * HID,
                att_d + (size_t)(b * 3 + i) * 2 * HID, asrc, adst);
            const bf16* xpl = (i == 0) ? nullptr : hist + (size_t)(i - 1) * S;
            const bf16* xpr = (i == 0) ? nullptr : hist + (size_t)(3 + i - 1) * S;
            agg_kernel<<<25000, 256, 0, stream>>>(
                xh, asrc, adst, offs[b], eid[b], ei, xpl, xpr,
                (i == 0) ? x_idx : nullptr, x_flt,
                embA[0], embS[0], embA[1], embS[1],
                conv_b + (size_t)(b * 3 + i) * HID, hist + (size_t)(b * 3 + i) * S);
        }
    }

    // ---- stage 2: bi-LSTM JK with fully-fused cell epilogue
    for (int b = 0; b < 2; ++b) {
        for (int c0 = 0; c0 < N_NODES; c0 += CH) {
            hipMemsetAsync(scores, 0, (size_t)3 * CH * 4, stream);
            for (int dir = 0; dir < 2; ++dir) {
                hipMemsetAsync(cbuf, 0, (size_t)CH * H2 * 4, stream);
                const bf16* Wi = Wih_b + (size_t)(b * 2 + dir) * G4 * HID;
                const bf16* Wh = Whh_b + (size_t)(b * 2 + dir) * G4 * H2;
                const float* bs = bsum + (size_t)(b * 2 + dir) * G4;
                const float* aw = jkw + (size_t)b * 2 * H2 + (size_t)dir * H2;
                for (int st = 0; st < 3; ++st) {
                    int l = dir ? (2 - st) : st;
                    const bf16* A = hist + (size_t)(b * 3 + l) * S + (size_t)c0 * HID;
                    dim3 g(G4 / 128, (CH + 127) / 128);
                    lstm_gemm_kernel<<<g, 256, 0, stream>>>(
                        A, Wi, (st == 0) ? nullptr : hbuf, Wh, bs, cbuf, hbuf, aw,
                        scores + (size_t)l * CH, CH);
                }
            }
            jkfin_kernel<<<(CH + 3) / 4, 256, 0, stream>>>(
                scores, hist + (size_t)b * 3 * S, hist + (size_t)(b * 3 + 1) * S,
                hist + (size_t)(b * 3 + 2) * S, jkb + (size_t)b * S, c0);
        }
    }

    // ---- stage 3: sq, outs, final combine (scratch = freed hist region)
    float* f3 = (float*)hist;
    bf16* jkl = jkb; bf16* jkr = jkb + S;
    for (long long c3 = 0; c3 < N_NODES; c3 += CH3) {
        int Rr = (int)((N_NODES - c3) < CH3 ? (N_NODES - c3) : CH3);
        float* o0 = f3;
        float* o1 = f3 + 1LL * CH3 * HID;
        float* o2 = f3 + 2LL * CH3 * HID;
        float* o3 = f3 + 3LL * CH3 * HID;
        bf16* sql = (bf16*)(f3 + 4LL * CH3 * HID);
        bf16* sqr = sql + (long long)CH3 * HID;
        mfma_gemm<bf16>(jkl + c3 * HID, dummyWt, 128, nullptr, nullptr, 0,
                        sql, dummy_b, Rr, 128, stream);
        mfma_gemm<bf16>(jkr + c3 * HID, dummyWt + 16384, 128, nullptr, nullptr, 0,
                        sqr, dummy_b + 128, Rr, 128, stream);
        mfma_gemm<float>(jkl + c3 * HID, finWt, 128, nullptr, nullptr, 0,
                         o0, fin_b, Rr, 128, stream);
        mfma_gemm<float>(sql, finWt + 16384, 128, nullptr, nullptr, 0,
                         o1, fin_b + 128, Rr, 128, stream);
        mfma_gemm<float>(jkr + c3 * HID, finWt + 2 * 16384, 128, nullptr, nullptr, 0,
                         o2, fin_b + 256, Rr, 128, stream);
        mfma_gemm<float>(sqr, finWt + 3 * 16384, 128, nullptr, nullptr, 0,
                         o3, fin_b + 384, Rr, 128, stream);
        final_kernel<<<(Rr + 3) / 4, 256, 0, stream>>>(
            o0, o1, o2, o3, last_W, out, Rr, c3);
    }
}

// Round 6
// 3894.302 us; speedup vs baseline: 6.7471x; 1.3679x over previous
//
#include <hip/hip_runtime.h>
#include <cstddef>
#include <cstdint>

#define N_NODES 100000
#define N_EDGES 800000
#define EL_TOT  900000      // edges + self loops
#define HID 128
#define H2  192
#define G4  768             // 4*H2
#define CH3 50000           // stage-3 chunk
#define BK  32
#define LDST 40             // LDS row stride in bf16 elems

typedef unsigned short bf16;
typedef __attribute__((ext_vector_type(8))) short bf16x8v;
typedef __attribute__((ext_vector_type(4))) float f32x4v;

// ---------------------------------------------------------------- dtype helpers

__device__ __forceinline__ float b2f(bf16 u) {
    return __uint_as_float(((unsigned)u) << 16);
}
__device__ __forceinline__ bf16 f2b(float f) {   // round-nearest-even
    unsigned u = __float_as_uint(f);
    u += 0x7FFFu + ((u >> 16) & 1u);
    return (bf16)(u >> 16);
}
__device__ __forceinline__ void stE(float* p, size_t i, float v) { p[i] = v; }
__device__ __forceinline__ void stE(bf16* p, size_t i, float v) { p[i] = f2b(v); }
__device__ __forceinline__ float ftanh(float x) {
    float cx = fminf(fmaxf(x, -15.f), 15.f);
    float e = __expf(2.f * cx);
    return (e - 1.f) / (e + 1.f);
}

// x0 recompute: column c of node n for one branch
__device__ __forceinline__ float x0_val(int c, int ia, int is_, int n,
                                        const float* __restrict__ embA,
                                        const float* __restrict__ embS,
                                        const float* __restrict__ xflt) {
    return (c < 123) ? (embA[ia * 123 + c] + embS[is_ * 123 + c])
                     : xflt[n * 5 + (c - 123)];
}

// LSTM gate-column permutation: new col j -> orig gate row
__device__ __forceinline__ int lstm_perm(int j) {
    int w = j & 63, tt = j >> 6;
    return (w >> 4) * 192 + tt * 16 + (w & 15);   // gate*192 + unit
}

// ---------------------------------------------------------------- utilities

__global__ void sentinel_kernel(float* out, int n, float val) {
    int t = blockIdx.x * blockDim.x + threadIdx.x;
    if (t < n) out[t] = val;
}

__global__ void bsum_perm_kernel(const float* __restrict__ bih,
                                 const float* __restrict__ bhh,
                                 float* __restrict__ bsum) {
    int t = blockIdx.x * blockDim.x + threadIdx.x;
    if (t >= 4 * G4) return;
    int d = t / G4, j = t % G4;
    int orig = lstm_perm(j);
    bsum[t] = bih[d * G4 + orig] + bhh[d * G4 + orig];
}

// permute gate rows + convert to bf16: out[d][j][k] = in[d][perm(j)][k]
__global__ void lstm_w_perm_kernel(const float* __restrict__ in,
                                   bf16* __restrict__ out, int K) {
    long long t = (long long)blockIdx.x * blockDim.x + threadIdx.x;
    long long tot = 4LL * G4 * K;
    if (t >= tot) return;
    int k = (int)(t % K);
    int j = (int)((t / K) % G4);
    int d = (int)(t / ((long long)G4 * K));
    int orig = lstm_perm(j);
    out[t] = f2b(in[((size_t)d * G4 + orig) * K + k]);
}

// out[bt][m][k] = in[bt][k][m]  ((K,M) -> (M,K) bf16)
__global__ void trans_kernel(const float* __restrict__ in, bf16* __restrict__ out,
                             int batch, int K, int M) {
    long long t = (long long)blockIdx.x * blockDim.x + threadIdx.x;
    long long tot = (long long)batch * K * M;
    if (t >= tot) return;
    int per = K * M;
    int bt = (int)(t / per);
    int rem = (int)(t % per);
    int m = rem / K, k = rem % K;
    out[t] = f2b(in[(size_t)bt * per + (size_t)k * M + m]);
}

// ---------------------------------------------------------------- CSR build

__global__ void deg_kernel(const int* __restrict__ dst, int* __restrict__ deg) {
    int t = blockIdx.x * blockDim.x + threadIdx.x;
    if (t >= EL_TOT) return;
    int d = (t < N_EDGES) ? dst[t] : (t - N_EDGES);
    atomicAdd(&deg[d], 1);
}

__global__ void scan_kernel(const int* __restrict__ deg, int* __restrict__ offs, int n) {
    __shared__ int sdata[1024];
    __shared__ int carry;
    if (threadIdx.x == 0) carry = 0;
    __syncthreads();
    for (int base = 0; base < n; base += 1024) {
        int i = base + (int)threadIdx.x;
        int v = (i < n) ? deg[i] : 0;
        sdata[threadIdx.x] = v;
        __syncthreads();
        for (int off = 1; off < 1024; off <<= 1) {
            int t = (threadIdx.x >= (unsigned)off) ? sdata[threadIdx.x - off] : 0;
            __syncthreads();
            sdata[threadIdx.x] += t;
            __syncthreads();
        }
        if (i < n) offs[i + 1] = carry + sdata[threadIdx.x];
        __syncthreads();
        if (threadIdx.x == 1023) carry += sdata[1023];
        __syncthreads();
    }
    if (threadIdx.x == 0) offs[0] = 0;
}

__global__ void copy_int_kernel(const int* __restrict__ a, int* __restrict__ b, int n) {
    int t = blockIdx.x * blockDim.x + threadIdx.x;
    if (t < n) b[t] = a[t];
}

// store RESOLVED src (self-loop src = node id) at CSR position
__global__ void fill_kernel(const int* __restrict__ srcrow,
                            const int* __restrict__ dstrow,
                            int* __restrict__ pos, int* __restrict__ srcs) {
    int t = blockIdx.x * blockDim.x + threadIdx.x;
    if (t >= EL_TOT) return;
    int s, d;
    if (t < N_EDGES) { s = srcrow[t]; d = dstrow[t]; }
    else             { s = d = t - N_EDGES; }
    int p = atomicAdd(&pos[d], 1);
    srcs[p] = s;
}

// ---------------------------------------------------------------- MFMA GEMM
// C(RxM) = A1(RxK1) @ B1t(MxK1)^T [+ A2(RxK2) @ B2t(MxK2)^T] + bias[col]
template<typename TC>
__global__ __launch_bounds__(256) void mfma_gemm_kernel(
    const bf16* __restrict__ A1, const bf16* __restrict__ B1, int K1,
    const bf16* __restrict__ A2, const bf16* __restrict__ B2, int K2,
    TC* __restrict__ C, const float* __restrict__ bias, int R, int M) {
    __shared__ bf16 As[128 * LDST];
    __shared__ bf16 Bs[128 * LDST];
    const int tid = threadIdx.x;
    const int lane = tid & 63;
    const int wave = tid >> 6;
    const int wm = (wave & 1) * 64, wn = (wave >> 1) * 64;
    const int bm0 = blockIdx.y * 128, bn0 = blockIdx.x * 128;
    const int l15 = lane & 15;
    const int q8 = (lane >> 4) * 8;
    const int srow = tid >> 2;
    const int scol = (tid & 3) * 8;

    f32x4v acc[4][4];
#pragma unroll
    for (int i = 0; i < 4; ++i)
#pragma unroll
        for (int j = 0; j < 4; ++j) acc[i][j] = (f32x4v)(0.0f);

    auto panel = [&](const bf16* Ap, const bf16* Bp, int K) {
        for (int k0 = 0; k0 < K; k0 += BK) {
#pragma unroll
            for (int rnd = 0; rnd < 2; ++rnd) {
                int row = srow + rnd * 64;
                int ga = bm0 + row; ga = (ga < R) ? ga : (R - 1);
                int4 va = *(const int4*)(Ap + (size_t)ga * K + k0 + scol);
                *(int4*)&As[row * LDST + scol] = va;
                int4 vb = *(const int4*)(Bp + (size_t)(bn0 + row) * K + k0 + scol);
                *(int4*)&Bs[row * LDST + scol] = vb;
            }
            __syncthreads();
            bf16x8v af[4], bfv[4];
#pragma unroll
            for (int i = 0; i < 4; ++i) {
                af[i]  = *(const bf16x8v*)&As[(wm + i * 16 + l15) * LDST + q8];
                bfv[i] = *(const bf16x8v*)&Bs[(wn + i * 16 + l15) * LDST + q8];
            }
#pragma unroll
            for (int i = 0; i < 4; ++i)
#pragma unroll
                for (int j = 0; j < 4; ++j)
                    acc[i][j] = __builtin_amdgcn_mfma_f32_16x16x32_bf16(
                        af[i], bfv[j], acc[i][j], 0, 0, 0);
            __syncthreads();
        }
    };
    panel(A1, B1, K1);
    if (A2) panel(A2, B2, K2);

#pragma unroll
    for (int i = 0; i < 4; ++i) {
        const int row0 = bm0 + wm + i * 16 + (lane >> 4) * 4;
#pragma unroll
        for (int j = 0; j < 4; ++j) {
            const int col = bn0 + wn + j * 16 + l15;
            const float bv = bias ? bias[col] : 0.f;
#pragma unroll
            for (int r = 0; r < 4; ++r) {
                const int gr = row0 + r;
                if (gr < R) stE(C, (size_t)gr * M + col, acc[i][j][r] + bv);
            }
        }
    }
}

template<typename TC>
static void mfma_gemm(const bf16* A1, const bf16* B1, int K1,
                      const bf16* A2, const bf16* B2, int K2,
                      TC* C, const float* bias, int R, int M, hipStream_t s) {
    dim3 g(M / 128, (R + 127) / 128);
    mfma_gemm_kernel<TC><<<g, 256, 0, s>>>(A1, B1, K1, A2, B2, K2, C, bias, R, M);
}

// ---------------------------------------------------------------- fused LSTM GEMM
// Permuted col j: tile64*64 + gate*16 + unitlocal -> lane's 4 j-frags are
// i,f,g,o of ONE unit. Epilogue does the LSTM cell + JK score partial.
// A2==nullptr means step 0: h panel skipped AND c_prev treated as 0.
__global__ __launch_bounds__(256) void lstm_gemm_kernel(
    const bf16* __restrict__ A1, const bf16* __restrict__ B1,
    const bf16* __restrict__ A2, const bf16* __restrict__ B2,
    const float* __restrict__ bias, bf16* __restrict__ c_state,
    bf16* __restrict__ h_out, const float* __restrict__ aw,
    float* __restrict__ score, int R) {
    __shared__ bf16 As[128 * LDST];
    __shared__ bf16 Bs[128 * LDST];
    const int tid = threadIdx.x;
    const int lane = tid & 63;
    const int wave = tid >> 6;
    const int wm = (wave & 1) * 64, wn = (wave >> 1) * 64;
    const int bm0 = blockIdx.y * 128, bn0 = blockIdx.x * 128;
    const int l15 = lane & 15;
    const int q = lane >> 4;
    const int q8 = q * 8;
    const int srow = tid >> 2;
    const int scol = (tid & 3) * 8;

    f32x4v acc[4][4];
#pragma unroll
    for (int i = 0; i < 4; ++i)
#pragma unroll
        for (int j = 0; j < 4; ++j) acc[i][j] = (f32x4v)(0.0f);

    auto panel = [&](const bf16* Ap, const bf16* Bp, int K) {
        for (int k0 = 0; k0 < K; k0 += BK) {
#pragma unroll
            for (int rnd = 0; rnd < 2; ++rnd) {
                int row = srow + rnd * 64;
                int ga = bm0 + row; ga = (ga < R) ? ga : (R - 1);
                int4 va = *(const int4*)(Ap + (size_t)ga * K + k0 + scol);
                *(int4*)&As[row * LDST + scol] = va;
                int4 vb = *(const int4*)(Bp + (size_t)(bn0 + row) * K + k0 + scol);
                *(int4*)&Bs[row * LDST + scol] = vb;
            }
            __syncthreads();
            bf16x8v af[4], bfv[4];
#pragma unroll
            for (int i = 0; i < 4; ++i) {
                af[i]  = *(const bf16x8v*)&As[(wm + i * 16 + l15) * LDST + q8];
                bfv[i] = *(const bf16x8v*)&Bs[(wn + i * 16 + l15) * LDST + q8];
            }
#pragma unroll
            for (int i = 0; i < 4; ++i)
#pragma unroll
                for (int j = 0; j < 4; ++j)
                    acc[i][j] = __builtin_amdgcn_mfma_f32_16x16x32_bf16(
                        af[i], bfv[j], acc[i][j], 0, 0, 0);
            __syncthreads();
        }
    };
    panel(A1, B1, 128);
    if (A2) panel(A2, B2, H2);

    // ---- fused LSTM cell epilogue
    const int u = ((bn0 + wn) >> 6) * 16 + l15;      // hidden unit 0..191
    const float awu = aw[u];
    float bv[4];
#pragma unroll
    for (int j = 0; j < 4; ++j) bv[j] = bias[bn0 + wn + j * 16 + l15];
    float psum[4][4];
#pragma unroll
    for (int i = 0; i < 4; ++i) {
        const int row0 = bm0 + wm + i * 16 + q * 4;
#pragma unroll
        for (int r = 0; r < 4; ++r) {
            const int gr = row0 + r;
            const bool ok = gr < R;
            float ig = acc[i][0][r] + bv[0];
            float fg = acc[i][1][r] + bv[1];
            float gg = acc[i][2][r] + bv[2];
            float og = acc[i][3][r] + bv[3];
            float si = 1.f / (1.f + __expf(-ig));
            float sf = 1.f / (1.f + __expf(-fg));
            float so = 1.f / (1.f + __expf(-og));
            float co = (ok && A2) ? b2f(c_state[(size_t)gr * H2 + u]) : 0.f;
            float cn = sf * co + si * ftanh(gg);
            float hn = so * ftanh(cn);
            if (ok) {
                c_state[(size_t)gr * H2 + u] = f2b(cn);
                h_out[(size_t)gr * H2 + u] = f2b(hn);
            }
            psum[i][r] = hn * awu;
        }
    }
#pragma unroll
    for (int m = 1; m < 16; m <<= 1)
#pragma unroll
        for (int i = 0; i < 4; ++i)
#pragma unroll
            for (int r = 0; r < 4; ++r)
                psum[i][r] += __shfl_xor(psum[i][r], m);
    if (l15 == 0) {
#pragma unroll
        for (int i = 0; i < 4; ++i)
#pragma unroll
            for (int r = 0; r < 4; ++r) {
                const int gr = bm0 + wm + i * 16 + q * 4 + r;
                if (gr < R) atomicAdd(&score[gr], psum[i][r]);
            }
    }
}

// Layer-0 conv GEMM: A built on the fly from embeddings (K=128 fixed)
__global__ __launch_bounds__(256) void mfma_gemm_x0_kernel(
    const int* __restrict__ xidx, const float* __restrict__ xflt,
    const float* __restrict__ embA, const float* __restrict__ embS,
    const bf16* __restrict__ B1, bf16* __restrict__ C, int R, int M) {
    __shared__ bf16 As[128 * LDST];
    __shared__ bf16 Bs[128 * LDST];
    const int tid = threadIdx.x;
    const int lane = tid & 63;
    const int wave = tid >> 6;
    const int wm = (wave & 1) * 64, wn = (wave >> 1) * 64;
    const int bm0 = blockIdx.y * 128, bn0 = blockIdx.x * 128;
    const int l15 = lane & 15;
    const int q8 = (lane >> 4) * 8;
    const int srow = tid >> 2;
    const int scol = (tid & 3) * 8;

    f32x4v acc[4][4];
#pragma unroll
    for (int i = 0; i < 4; ++i)
#pragma unroll
        for (int j = 0; j < 4; ++j) acc[i][j] = (f32x4v)(0.0f);

    for (int k0 = 0; k0 < 128; k0 += BK) {
#pragma unroll
        for (int rnd = 0; rnd < 2; ++rnd) {
            int row = srow + rnd * 64;
            int ga = bm0 + row; ga = (ga < R) ? ga : (R - 1);
            int ia = xidx[2 * ga], is_ = xidx[2 * ga + 1];
            bf16 tmp[8];
#pragma unroll
            for (int t = 0; t < 8; ++t)
                tmp[t] = f2b(x0_val(k0 + scol + t, ia, is_, ga, embA, embS, xflt));
            *(int4*)&As[row * LDST + scol] = *(const int4*)tmp;
            int4 vb = *(const int4*)(B1 + (size_t)(bn0 + row) * 128 + k0 + scol);
            *(int4*)&Bs[row * LDST + scol] = vb;
        }
        __syncthreads();
        bf16x8v af[4], bfv[4];
#pragma unroll
        for (int i = 0; i < 4; ++i) {
            af[i]  = *(const bf16x8v*)&As[(wm + i * 16 + l15) * LDST + q8];
            bfv[i] = *(const bf16x8v*)&Bs[(wn + i * 16 + l15) * LDST + q8];
        }
#pragma unroll
        for (int i = 0; i < 4; ++i)
#pragma unroll
            for (int j = 0; j < 4; ++j)
                acc[i][j] = __builtin_amdgcn_mfma_f32_16x16x32_bf16(
                    af[i], bfv[j], acc[i][j], 0, 0, 0);
        __syncthreads();
    }
#pragma unroll
    for (int i = 0; i < 4; ++i) {
        const int row0 = bm0 + wm + i * 16 + (lane >> 4) * 4;
#pragma unroll
        for (int j = 0; j < 4; ++j) {
            const int col = bn0 + wn + j * 16 + l15;
#pragma unroll
            for (int r = 0; r < 4; ++r) {
                const int gr = row0 + r;
                if (gr < R) C[(size_t)gr * M + col] = f2b(acc[i][j][r]);
            }
        }
    }
}

// ---------------------------------------------------------------- GAT pieces

__global__ __launch_bounds__(256) void att_kernel(
    const bf16* __restrict__ xh, const float* __restrict__ as_,
    const float* __restrict__ ad_, float* __restrict__ asrc, float* __restrict__ adst) {
    int w = (blockIdx.x * blockDim.x + threadIdx.x) >> 6;
    int lane = threadIdx.x & 63;
    if (w >= N_NODES) return;
    const bf16* row = xh + (size_t)w * 256;
    float x0 = b2f(row[lane]), x1 = b2f(row[64 + lane]);
    float x2 = b2f(row[128 + lane]), x3 = b2f(row[192 + lane]);
    float s0 = x0 * as_[lane] + x1 * as_[64 + lane];
    float s1 = x2 * as_[128 + lane] + x3 * as_[192 + lane];
    float d0 = x0 * ad_[lane] + x1 * ad_[64 + lane];
    float d1 = x2 * ad_[128 + lane] + x3 * ad_[192 + lane];
    for (int o = 1; o < 64; o <<= 1) {
        s0 += __shfl_xor(s0, o); s1 += __shfl_xor(s1, o);
        d0 += __shfl_xor(d0, o); d1 += __shfl_xor(d1, o);
    }
    if (lane == 0) {
        asrc[2 * w] = s0; asrc[2 * w + 1] = s1;
        adst[2 * w] = d0; adst[2 * w + 1] = d1;
    }
}

__device__ __forceinline__ float lrelu02(float x) { return x > 0.f ? x : 0.2f * x; }

// one wave per dst node: online-softmax pass + 2-edge/iter gather
__global__ __launch_bounds__(256) void agg_kernel(
    const bf16* __restrict__ xh, const float* __restrict__ asrc,
    const float* __restrict__ adst, const int* __restrict__ offs,
    const int* __restrict__ srcs,
    const bf16* __restrict__ xprev_l, const bf16* __restrict__ xprev_r,
    const int* __restrict__ xidx, const float* __restrict__ xflt,
    const float* __restrict__ embAl, const float* __restrict__ embSl,
    const float* __restrict__ embAr, const float* __restrict__ embSr,
    const float* __restrict__ bias, bf16* __restrict__ outx) {
    int n = (blockIdx.x * blockDim.x + threadIdx.x) >> 6;
    int lane = threadIdx.x & 63;
    if (n >= N_NODES) return;
    const int start = offs[n], end = offs[n + 1];
    const float ad0 = adst[2 * n], ad1 = adst[2 * n + 1];

    // pass 1: online softmax (m, d) per head, lane-parallel
    float m0 = -1e30f, d0 = 0.f, m1 = -1e30f, d1 = 0.f;
    for (int j = start + lane; j < end; j += 64) {
        int s = srcs[j];
        float2 a2 = *(const float2*)(asrc + 2 * s);
        float a0 = lrelu02(a2.x + ad0);
        float a1 = lrelu02(a2.y + ad1);
        float nm0 = fmaxf(m0, a0);
        d0 = d0 * __expf(m0 - nm0) + __expf(a0 - nm0); m0 = nm0;
        float nm1 = fmaxf(m1, a1);
        d1 = d1 * __expf(m1 - nm1) + __expf(a1 - nm1); m1 = nm1;
    }
    for (int o = 1; o < 64; o <<= 1) {
        float om = __shfl_xor(m0, o), od = __shfl_xor(d0, o);
        float nm = fmaxf(m0, om);
        d0 = d0 * __expf(m0 - nm) + od * __expf(om - nm); m0 = nm;
        om = __shfl_xor(m1, o); od = __shfl_xor(d1, o);
        nm = fmaxf(m1, om);
        d1 = d1 * __expf(m1 - nm) + od * __expf(om - nm); m1 = nm;
    }
    const float inv0 = 1.f / (d0 + 1e-16f), inv1 = 1.f / (d1 + 1e-16f);

    // pass 2: gather, 2 edges per iteration (half-wave per edge, 16 B/lane)
    const int eh = lane >> 5;           // which edge of the pair
    const int l32 = lane & 31;
    const int head = l32 >> 4;          // head within edge
    const int l15 = l32 & 15;
    const int col = head * 128 + l15 * 8;
    const float mh = head ? m1 : m0;
    const float invh = head ? inv1 : inv0;
    const float adh = head ? ad1 : ad0;

    float acc[8] = {0.f, 0.f, 0.f, 0.f, 0.f, 0.f, 0.f, 0.f};
#pragma unroll 2
    for (int j = start; j < end; j += 2) {
        int e = j + eh;
        if (e < end) {
            int s = srcs[e];
            float a = asrc[2 * s + head] + adh;
            float al = __expf(lrelu02(a) - mh) * invh;
            int4 v = *(const int4*)(xh + (size_t)s * 256 + col);
            const int* w = (const int*)&v;
#pragma unroll
            for (int t = 0; t < 4; ++t) {
                float lo = __uint_as_float(((unsigned)w[t]) << 16);
                float hi = __uint_as_float(((unsigned)w[t]) & 0xffff0000u);
                acc[2 * t]     += lo * al;
                acc[2 * t + 1] += hi * al;
            }
        }
    }
#pragma unroll
    for (int t = 0; t < 8; ++t) acc[t] += __shfl_xor(acc[t], 32);  // edge parity
#pragma unroll
    for (int t = 0; t < 8; ++t)
        acc[t] = 0.5f * (acc[t] + __shfl_xor(acc[t], 16));         // head mean

    if (lane < 16) {
        const int c0 = lane * 8;
        const size_t base = (size_t)n * HID + c0;
        float xm[8];
        if (xidx) {
            int ia = xidx[2 * n], is_ = xidx[2 * n + 1];
#pragma unroll
            for (int t = 0; t < 8; ++t)
                xm[t] = 0.5f * (x0_val(c0 + t, ia, is_, n, embAl, embSl, xflt) +
                                x0_val(c0 + t, ia, is_, n, embAr, embSr, xflt));
        } else {
            int4 vl = *(const int4*)(xprev_l + base);
            int4 vr = *(const int4*)(xprev_r + base);
            const int* wl = (const int*)&vl;
            const int* wr = (const int*)&vr;
#pragma unroll
            for (int t = 0; t < 4; ++t) {
                xm[2 * t] = 0.5f * (__uint_as_float(((unsigned)wl[t]) << 16) +
                                    __uint_as_float(((unsigned)wr[t]) << 16));
                xm[2 * t + 1] = 0.5f * (__uint_as_float(((unsigned)wl[t]) & 0xffff0000u) +
                                        __uint_as_float(((unsigned)wr[t]) & 0xffff0000u));
            }
        }
        bf16 res[8];
#pragma unroll
        for (int t = 0; t < 8; ++t)
            res[t] = f2b(xm[t] + fmaxf(0.f, acc[t] + bias[c0 + t]));
        *(int4*)(outx + base) = *(const int4*)res;
    }
}

// ---------------------------------------------------------------- JK / final

__global__ __launch_bounds__(256) void jkfin_kernel(
    const float* __restrict__ sb, const bf16* __restrict__ xs0,
    const bf16* __restrict__ xs1, const bf16* __restrict__ xs2,
    bf16* __restrict__ jk) {
    int w = (blockIdx.x * blockDim.x + threadIdx.x) >> 6;
    int lane = threadIdx.x & 63;
    if (w >= N_NODES) return;
    float s0 = sb[w], s1 = sb[N_NODES + w], s2 = sb[2 * N_NODES + w];
    float m = fmaxf(s0, fmaxf(s1, s2));
    float a0 = __expf(s0 - m), a1 = __expf(s1 - m), a2 = __expf(s2 - m);
    float inv = 1.f / (a0 + a1 + a2);
    a0 *= inv; a1 *= inv; a2 *= inv;
    size_t gn = (size_t)w * HID + lane * 2;
#pragma unroll
    for (int t = 0; t < 2; ++t) {
        float v0 = b2f(xs0[gn + t]);
        float v1 = b2f(xs1[gn + t]);
        float v2 = b2f(xs2[gn + t]);
        jk[gn + t] = f2b(v0 * a0 + v1 * a1 + v2 * a2);
    }
}

__global__ __launch_bounds__(256) void final_kernel(
    const float* __restrict__ o0, const float* __restrict__ o1,
    const float* __restrict__ o2, const float* __restrict__ o3,
    const float* __restrict__ lw, float* __restrict__ out, int nloc, long long c3off) {
    int w = (blockIdx.x * blockDim.x + threadIdx.x) >> 6;
    int lane = threadIdx.x & 63;
    if (w >= nloc) return;
    size_t base = (size_t)w * HID;
    float w0 = lw[lane], w1 = lw[64 + lane];
    const float* op[4] = {o0, o1, o2, o3};
    float v[4][2];
    float s[4];
#pragma unroll
    for (int i = 0; i < 4; ++i) {
        v[i][0] = op[i][base + lane];
        v[i][1] = op[i][base + 64 + lane];
        float t = v[i][0] * w0 + v[i][1] * w1;
        for (int o = 1; o < 64; o <<= 1) t += __shfl_xor(t, o);
        s[i] = t;
    }
    float m = fmaxf(fmaxf(s[0], s[1]), fmaxf(s[2], s[3]));
    float e0 = __expf(s[0] - m), e1 = __expf(s[1] - m);
    float e2 = __expf(s[2] - m), e3 = __expf(s[3] - m);
    float inv = 1.f / (e0 + e1 + e2 + e3);
    float r0 = (v[0][0] * e0 + v[1][0] * e1 + v[2][0] * e2 + v[3][0] * e3) * inv;
    float r1 = (v[0][1] * e0 + v[1][1] * e1 + v[2][1] * e2 + v[3][1] * e3) * inv;
    size_t obase = (size_t)(c3off + w) * HID;
    out[obase + lane] = r0;
    out[obase + 64 + lane] = r1;
}

// ---------------------------------------------------------------- entry

static long long align1k(long long x) { return (x + 1023) & ~1023LL; }

extern "C" void kernel_launch(void* const* d_in, const int* in_sizes, int n_in,
                              void* d_out, int out_size, void* d_ws, size_t ws_size,
                              hipStream_t stream) {
    (void)in_sizes; (void)n_in; (void)out_size;
    const int*   x_idx   = (const int*)  d_in[0];
    const float* x_flt   = (const float*)d_in[1];
    const int*   ei_l    = (const int*)  d_in[2];
    const int*   ei_r    = (const int*)  d_in[3];
    const float* emb_aa  = (const float*)d_in[4];
    const float* emb_ss  = (const float*)d_in[5];
    const float* conv_W  = (const float*)d_in[6];
    const float* att_s   = (const float*)d_in[7];
    const float* att_d   = (const float*)d_in[8];
    const float* conv_b  = (const float*)d_in[9];
    const float* Wih     = (const float*)d_in[10];
    const float* Whh     = (const float*)d_in[11];
    const float* bih     = (const float*)d_in[12];
    const float* bhh     = (const float*)d_in[13];
    const float* jkw     = (const float*)d_in[14];
    const float* dummy_W = (const float*)d_in[16];
    const float* dummy_b = (const float*)d_in[17];
    const float* fin_W   = (const float*)d_in[18];
    const float* fin_b   = (const float*)d_in[19];
    const float* last_W  = (const float*)d_in[20];
    float* out = (float*)d_out;

    const long long S = (long long)N_NODES * HID;
    char* ws = (char*)d_ws;
    long long off = 0;

    // hist: 6 bf16 slabs; stage 3 reuses as fp32 scratch
    bf16* hist = (bf16*)(ws + off);
    off += align1k(6 * S * 2);
    // R1: stage0/1 {CSR ints, asrc, adst, convWt} | stage2 {c-state bf16, N x 192}
    char* R1 = ws + off;
    {
        long long io4 = 2LL * (N_NODES + (N_NODES + 1) + N_NODES + EL_TOT) * 4;
        long long st01 = ((io4 + 15) & ~15LL) + 4LL * N_NODES * 4 + 6LL * 256 * 128 * 2;
        long long st2  = (long long)N_NODES * H2 * 2;
        off += align1k(st01 > st2 ? st01 : st2);
    }
    // R2: stage1 xh (N x 256 bf16) | stage2 h (N x 192 bf16) | stage2-end/3 jk
    char* R2 = ws + off;
    off += align1k(2 * S * 2);
    float* scores = (float*)(ws + off); off += align1k(6LL * N_NODES * 4);
    float* bsum   = (float*)(ws + off); off += align1k(4LL * G4 * 4);
    bf16* Wih_b   = (bf16*)(ws + off); off += align1k(4LL * G4 * HID * 2);
    bf16* Whh_b   = (bf16*)(ws + off); off += align1k(4LL * G4 * H2 * 2);
    bf16* dummyWt = (bf16*)(ws + off); off += align1k(2LL * 128 * 128 * 2);
    bf16* finWt   = (bf16*)(ws + off); off += align1k(4LL * 128 * 128 * 2);

    if ((long long)ws_size < off) {   // diagnosable: 200000 + ws MiB
        float val = 200000.0f + (float)(ws_size >> 20);
        sentinel_kernel<<<(N_NODES * HID + 255) / 256, 256, 0, stream>>>(
            out, N_NODES * HID, val);
        return;
    }

    // R1 stage0/1 views
    int* ibase = (int*)R1;
    int *deg[2], *offs[2], *pos[2], *srcs[2];
    long long io = 0;
    for (int b = 0; b < 2; ++b) {
        deg[b]  = ibase + io; io += N_NODES;
        offs[b] = ibase + io; io += N_NODES + 1;
        pos[b]  = ibase + io; io += N_NODES;
        srcs[b] = ibase + io; io += EL_TOT;
    }
    long long io4a = ((io * 4 + 15) & ~15LL);
    float* asrc = (float*)(R1 + io4a);
    float* adst = asrc + 2LL * N_NODES;
    bf16* convWt = (bf16*)(R1 + io4a + 4LL * N_NODES * 4);
    // stage2 views
    bf16* cbuf = (bf16*)R1;
    bf16* hbuf = (bf16*)R2;
    // R2 views
    bf16* xh  = (bf16*)R2;
    bf16* jkb = (bf16*)R2;

    const float* embA[2] = {emb_aa, emb_aa + 26 * 123};
    const float* embS[2] = {emb_ss, emb_ss + 3 * 123};

    // ---- stage 0: weight conversion (LSTM weights gate-permuted) + CSR
    bsum_perm_kernel<<<12, 256, 0, stream>>>(bih, bhh, bsum);
    trans_kernel<<<(6 * 128 * 256 + 255) / 256, 256, 0, stream>>>(
        conv_W, convWt, 6, 128, 256);
    lstm_w_perm_kernel<<<(4 * G4 * HID + 255) / 256, 256, 0, stream>>>(
        Wih, Wih_b, HID);
    lstm_w_perm_kernel<<<(4 * G4 * H2 + 255) / 256, 256, 0, stream>>>(
        Whh, Whh_b, H2);
    trans_kernel<<<(2 * 128 * 128 + 255) / 256, 256, 0, stream>>>(
        dummy_W, dummyWt, 2, 128, 128);
    trans_kernel<<<(4 * 128 * 128 + 255) / 256, 256, 0, stream>>>(
        fin_W, finWt, 4, 128, 128);
    for (int b = 0; b < 2; ++b) {
        const int* ei = b ? ei_r : ei_l;
        hipMemsetAsync(deg[b], 0, N_NODES * sizeof(int), stream);
        deg_kernel<<<(EL_TOT + 255) / 256, 256, 0, stream>>>(ei + N_EDGES, deg[b]);
        scan_kernel<<<1, 1024, 0, stream>>>(deg[b], offs[b], N_NODES);
        copy_int_kernel<<<(N_NODES + 255) / 256, 256, 0, stream>>>(offs[b], pos[b], N_NODES);
        fill_kernel<<<(EL_TOT + 255) / 256, 256, 0, stream>>>(
            ei, ei + N_EDGES, pos[b], srcs[b]);
    }

    // ---- stage 1: 3 GAT layers x 2 branches
    for (int i = 0; i < 3; ++i) {
        for (int b = 0; b < 2; ++b) {
            const bf16* Wc = convWt + (size_t)(b * 3 + i) * 256 * 128;
            if (i == 0) {
                dim3 g(2, (N_NODES + 127) / 128);
                mfma_gemm_x0_kernel<<<g, 256, 0, stream>>>(
                    x_idx, x_flt, embA[b], embS[b], Wc, xh, N_NODES, 256);
            } else {
                mfma_gemm<bf16>(hist + (size_t)(b * 3 + i - 1) * S, Wc, 128,
                                nullptr, nullptr, 0, xh, nullptr, N_NODES, 256, stream);
            }
            att_kernel<<<25000, 256, 0, stream>>>(
                xh, att_s + (size_t)(b * 3 + i) * 2 * HID,
                att_d + (size_t)(b * 3 + i) * 2 * HID, asrc, adst);
            const bf16* xpl = (i == 0) ? nullptr : hist + (size_t)(i - 1) * S;
            const bf16* xpr = (i == 0) ? nullptr : hist + (size_t)(3 + i - 1) * S;
            agg_kernel<<<25000, 256, 0, stream>>>(
                xh, asrc, adst, offs[b], srcs[b], xpl, xpr,
                (i == 0) ? x_idx : nullptr, x_flt,
                embA[0], embS[0], embA[1], embS[1],
                conv_b + (size_t)(b * 3 + i) * HID, hist + (size_t)(b * 3 + i) * S);
        }
    }

    // ---- stage 2: bi-LSTM JK, full-N, fused cell epilogue
    hipMemsetAsync(scores, 0, (size_t)6 * N_NODES * 4, stream);
    for (int b = 0; b < 2; ++b) {
        for (int dir = 0; dir < 2; ++dir) {
            const bf16* Wi = Wih_b + (size_t)(b * 2 + dir) * G4 * HID;
            const bf16* Wh = Whh_b + (size_t)(b * 2 + dir) * G4 * H2;
            const float* bs = bsum + (size_t)(b * 2 + dir) * G4;
            const float* aw = jkw + (size_t)b * 2 * H2 + (size_t)dir * H2;
            for (int st = 0; st < 3; ++st) {
                int l = dir ? (2 - st) : st;
                const bf16* A = hist + (size_t)(b * 3 + l) * S;
                dim3 g(G4 / 128, (N_NODES + 127) / 128);
                lstm_gemm_kernel<<<g, 256, 0, stream>>>(
                    A, Wi, (st == 0) ? nullptr : hbuf, Wh, bs, cbuf, hbuf, aw,
                    scores + (size_t)(b * 3 + l) * N_NODES, N_NODES);
            }
        }
    }
    for (int b = 0; b < 2; ++b)
        jkfin_kernel<<<25000, 256, 0, stream>>>(
            scores + (size_t)b * 3 * N_NODES,
            hist + (size_t)b * 3 * S, hist + (size_t)(b * 3 + 1) * S,
            hist + (size_t)(b * 3 + 2) * S, jkb + (size_t)b * S);

    // ---- stage 3: sq, outs, final combine (scratch = freed hist region)
    float* f3 = (float*)hist;
    bf16* jkl = jkb; bf16* jkr = jkb + S;
    for (long long c3 = 0; c3 < N_NODES; c3 += CH3) {
        int Rr = (int)((N_NODES - c3) < CH3 ? (N_NODES - c3) : CH3);
        float* o0 = f3;
        float* o1 = f3 + 1LL * CH3 * HID;
        float* o2 = f3 + 2LL * CH3 * HID;
        float* o3 = f3 + 3LL * CH3 * HID;
        bf16* sql = (bf16*)(f3 + 4LL * CH3 * HID);
        bf16* sqr = sql + (long long)CH3 * HID;
        mfma_gemm<bf16>(jkl + c3 * HID, dummyWt, 128, nullptr, nullptr, 0,
                        sql, dummy_b, Rr, 128, stream);
        mfma_gemm<bf16>(jkr + c3 * HID, dummyWt + 16384, 128, nullptr, nullptr, 0,
                        sqr, dummy_b + 128, Rr, 128, stream);
        mfma_gemm<float>(jkl + c3 * HID, finWt, 128, nullptr, nullptr, 0,
                         o0, fin_b, Rr, 128, stream);
        mfma_gemm<float>(sql, finWt + 16384, 128, nullptr, nullptr, 0,
                         o1, fin_b + 128, Rr, 128, stream);
        mfma_gemm<float>(jkr + c3 * HID, finWt + 2 * 16384, 128, nullptr, nullptr, 0,
                         o2, fin_b + 256, Rr, 128, stream);
        mfma_gemm<float>(sqr, finWt + 3 * 16384, 128, nullptr, nullptr, 0,
                         o3, fin_b + 384, Rr, 128, stream);
        final_kernel<<<(Rr + 3) / 4, 256, 0, stream>>>(
            o0, o1, o2, o3, last_W, out, Rr, c3);
    }
}

// Round 7
// 3824.877 us; speedup vs baseline: 6.8696x; 1.0182x over previous
//
#include <hip/hip_runtime.h>
#include <cstddef>
#include <cstdint>

#define N_NODES 100000
#define N_EDGES 800000
#define EL_TOT  900000      // edges + self loops
#define HID 128
#define H2  192
#define G4  768             // 4*H2
#define CH3 50000           // stage-3 chunk
#define BK  32
#define LDST 40             // LDS row stride in bf16 elems (multiple of 8 for b128 align)

typedef unsigned short bf16;
typedef __attribute__((ext_vector_type(8))) short bf16x8v;
typedef __attribute__((ext_vector_type(4))) float f32x4v;

// ---------------------------------------------------------------- dtype helpers

__device__ __forceinline__ float b2f(bf16 u) {
    return __uint_as_float(((unsigned)u) << 16);
}
__device__ __forceinline__ bf16 f2b(float f) {   // round-nearest-even
    unsigned u = __float_as_uint(f);
    u += 0x7FFFu + ((u >> 16) & 1u);
    return (bf16)(u >> 16);
}
__device__ __forceinline__ void stE(float* p, size_t i, float v) { p[i] = v; }
__device__ __forceinline__ void stE(bf16* p, size_t i, float v) { p[i] = f2b(v); }
__device__ __forceinline__ float ftanh(float x) {
    float cx = fminf(fmaxf(x, -15.f), 15.f);
    float e = __expf(2.f * cx);
    return (e - 1.f) / (e + 1.f);
}

// x0 recompute: column c of node n for one branch
__device__ __forceinline__ float x0_val(int c, int ia, int is_, int n,
                                        const float* __restrict__ embA,
                                        const float* __restrict__ embS,
                                        const float* __restrict__ xflt) {
    return (c < 123) ? (embA[ia * 123 + c] + embS[is_ * 123 + c])
                     : xflt[n * 5 + (c - 123)];
}

// LSTM gate-column permutation: new col j -> orig gate row
__device__ __forceinline__ int lstm_perm(int j) {
    int w = j & 63, tt = j >> 6;
    return (w >> 4) * 192 + tt * 16 + (w & 15);   // gate*192 + unit
}

// XCD-aware swizzle: the ntile column tiles of one row panel are consecutive
// blocks on the SAME XCD (id%8 heuristic) -> A-panel re-reads hit that L2.
__device__ __forceinline__ bool swz_tile(int R, int ntile, int& bm0, int& bn0) {
    const int id = blockIdx.x;
    const int xcd = id & 7;
    const int s = id >> 3;
    const int nt = s % ntile;
    const int yp = (s / ntile) * 8 + xcd;
    if (yp * 128 >= R) return false;
    bm0 = yp * 128; bn0 = nt * 128;
    return true;
}
static inline int swz_grid(int R, int ntile) {
    int panels = (R + 127) / 128;
    return 8 * ntile * ((panels + 7) / 8);
}

// ---------------------------------------------------------------- utilities

__global__ void sentinel_kernel(float* out, int n, float val) {
    int t = blockIdx.x * blockDim.x + threadIdx.x;
    if (t < n) out[t] = val;
}

__global__ void bsum_perm_kernel(const float* __restrict__ bih,
                                 const float* __restrict__ bhh,
                                 float* __restrict__ bsum) {
    int t = blockIdx.x * blockDim.x + threadIdx.x;
    if (t >= 4 * G4) return;
    int d = t / G4, j = t % G4;
    int orig = lstm_perm(j);
    bsum[t] = bih[d * G4 + orig] + bhh[d * G4 + orig];
}

// permute gate rows + convert to bf16: out[d][j][k] = in[d][perm(j)][k]
__global__ void lstm_w_perm_kernel(const float* __restrict__ in,
                                   bf16* __restrict__ out, int K) {
    long long t = (long long)blockIdx.x * blockDim.x + threadIdx.x;
    long long tot = 4LL * G4 * K;
    if (t >= tot) return;
    int k = (int)(t % K);
    int j = (int)((t / K) % G4);
    int d = (int)(t / ((long long)G4 * K));
    int orig = lstm_perm(j);
    out[t] = f2b(in[((size_t)d * G4 + orig) * K + k]);
}

// out[bt][m][k] = in[bt][k][m]  ((K,M) -> (M,K) bf16)
__global__ void trans_kernel(const float* __restrict__ in, bf16* __restrict__ out,
                             int batch, int K, int M) {
    long long t = (long long)blockIdx.x * blockDim.x + threadIdx.x;
    long long tot = (long long)batch * K * M;
    if (t >= tot) return;
    int per = K * M;
    int bt = (int)(t / per);
    int rem = (int)(t % per);
    int m = rem / K, k = rem % K;
    out[t] = f2b(in[(size_t)bt * per + (size_t)k * M + m]);
}

// ---------------------------------------------------------------- CSR build

__global__ void deg_kernel(const int* __restrict__ dst, int* __restrict__ deg) {
    int t = blockIdx.x * blockDim.x + threadIdx.x;
    if (t >= EL_TOT) return;
    int d = (t < N_EDGES) ? dst[t] : (t - N_EDGES);
    atomicAdd(&deg[d], 1);
}

__global__ void scan_kernel(const int* __restrict__ deg, int* __restrict__ offs, int n) {
    __shared__ int sdata[1024];
    __shared__ int carry;
    if (threadIdx.x == 0) carry = 0;
    __syncthreads();
    for (int base = 0; base < n; base += 1024) {
        int i = base + (int)threadIdx.x;
        int v = (i < n) ? deg[i] : 0;
        sdata[threadIdx.x] = v;
        __syncthreads();
        for (int off = 1; off < 1024; off <<= 1) {
            int t = (threadIdx.x >= (unsigned)off) ? sdata[threadIdx.x - off] : 0;
            __syncthreads();
            sdata[threadIdx.x] += t;
            __syncthreads();
        }
        if (i < n) offs[i + 1] = carry + sdata[threadIdx.x];
        __syncthreads();
        if (threadIdx.x == 1023) carry += sdata[1023];
        __syncthreads();
    }
    if (threadIdx.x == 0) offs[0] = 0;
}

__global__ void copy_int_kernel(const int* __restrict__ a, int* __restrict__ b, int n) {
    int t = blockIdx.x * blockDim.x + threadIdx.x;
    if (t < n) b[t] = a[t];
}

// store RESOLVED src (self-loop src = node id) at CSR position
__global__ void fill_kernel(const int* __restrict__ srcrow,
                            const int* __restrict__ dstrow,
                            int* __restrict__ pos, int* __restrict__ srcs) {
    int t = blockIdx.x * blockDim.x + threadIdx.x;
    if (t >= EL_TOT) return;
    int s, d;
    if (t < N_EDGES) { s = srcrow[t]; d = dstrow[t]; }
    else             { s = d = t - N_EDGES; }
    int p = atomicAdd(&pos[d], 1);
    srcs[p] = s;
}

// ---------------------------------------------------------------- MFMA GEMM
// C(RxM) = A1(RxK1) @ B1t(MxK1)^T [+ A2(RxK2) @ B2t(MxK2)^T] + bias[col]
template<typename TC>
__global__ __launch_bounds__(256) void mfma_gemm_kernel(
    const bf16* __restrict__ A1, const bf16* __restrict__ B1, int K1,
    const bf16* __restrict__ A2, const bf16* __restrict__ B2, int K2,
    TC* __restrict__ C, const float* __restrict__ bias, int R, int M) {
    __shared__ bf16 As[128 * LDST];
    __shared__ bf16 Bs[128 * LDST];
    int bm0, bn0;
    if (!swz_tile(R, M >> 7, bm0, bn0)) return;
    const int tid = threadIdx.x;
    const int lane = tid & 63;
    const int wave = tid >> 6;
    const int wm = (wave & 1) * 64, wn = (wave >> 1) * 64;
    const int l15 = lane & 15;
    const int q8 = (lane >> 4) * 8;
    const int srow = tid >> 2;
    const int scol = (tid & 3) * 8;

    f32x4v acc[4][4];
#pragma unroll
    for (int i = 0; i < 4; ++i)
#pragma unroll
        for (int j = 0; j < 4; ++j) acc[i][j] = (f32x4v)(0.0f);

    auto panel = [&](const bf16* Ap, const bf16* Bp, int K) {
        for (int k0 = 0; k0 < K; k0 += BK) {
#pragma unroll
            for (int rnd = 0; rnd < 2; ++rnd) {
                int row = srow + rnd * 64;
                int ga = bm0 + row; ga = (ga < R) ? ga : (R - 1);
                int4 va = *(const int4*)(Ap + (size_t)ga * K + k0 + scol);
                *(int4*)&As[row * LDST + scol] = va;
                int4 vb = *(const int4*)(Bp + (size_t)(bn0 + row) * K + k0 + scol);
                *(int4*)&Bs[row * LDST + scol] = vb;
            }
            __syncthreads();
            bf16x8v af[4], bfv[4];
#pragma unroll
            for (int i = 0; i < 4; ++i) {
                af[i]  = *(const bf16x8v*)&As[(wm + i * 16 + l15) * LDST + q8];
                bfv[i] = *(const bf16x8v*)&Bs[(wn + i * 16 + l15) * LDST + q8];
            }
#pragma unroll
            for (int i = 0; i < 4; ++i)
#pragma unroll
                for (int j = 0; j < 4; ++j)
                    acc[i][j] = __builtin_amdgcn_mfma_f32_16x16x32_bf16(
                        af[i], bfv[j], acc[i][j], 0, 0, 0);
            __syncthreads();
        }
    };
    panel(A1, B1, K1);
    if (A2) panel(A2, B2, K2);

#pragma unroll
    for (int i = 0; i < 4; ++i) {
        const int row0 = bm0 + wm + i * 16 + (lane >> 4) * 4;
#pragma unroll
        for (int j = 0; j < 4; ++j) {
            const int col = bn0 + wn + j * 16 + l15;
            const float bv = bias ? bias[col] : 0.f;
#pragma unroll
            for (int r = 0; r < 4; ++r) {
                const int gr = row0 + r;
                if (gr < R) stE(C, (size_t)gr * M + col, acc[i][j][r] + bv);
            }
        }
    }
}

template<typename TC>
static void mfma_gemm(const bf16* A1, const bf16* B1, int K1,
                      const bf16* A2, const bf16* B2, int K2,
                      TC* C, const float* bias, int R, int M, hipStream_t s) {
    mfma_gemm_kernel<TC><<<swz_grid(R, M / 128), 256, 0, s>>>(
        A1, B1, K1, A2, B2, K2, C, bias, R, M);
}

// ---------------------------------------------------------------- fused LSTM GEMM
// Permuted col j: tile64*64 + gate*16 + unitlocal -> lane's 4 j-frags are
// i,f,g,o of ONE unit. Epilogue does the LSTM cell + JK score partial.
// A2==nullptr means step 0: h panel skipped AND c_prev treated as 0.
__global__ __launch_bounds__(256) void lstm_gemm_kernel(
    const bf16* __restrict__ A1, const bf16* __restrict__ B1,
    const bf16* __restrict__ A2, const bf16* __restrict__ B2,
    const float* __restrict__ bias, bf16* __restrict__ c_state,
    bf16* __restrict__ h_out, const float* __restrict__ aw,
    float* __restrict__ score, int R) {
    __shared__ bf16 As[128 * LDST];
    __shared__ bf16 Bs[128 * LDST];
    int bm0, bn0;
    if (!swz_tile(R, G4 >> 7, bm0, bn0)) return;
    const int tid = threadIdx.x;
    const int lane = tid & 63;
    const int wave = tid >> 6;
    const int wm = (wave & 1) * 64, wn = (wave >> 1) * 64;
    const int l15 = lane & 15;
    const int q = lane >> 4;
    const int q8 = q * 8;
    const int srow = tid >> 2;
    const int scol = (tid & 3) * 8;

    f32x4v acc[4][4];
#pragma unroll
    for (int i = 0; i < 4; ++i)
#pragma unroll
        for (int j = 0; j < 4; ++j) acc[i][j] = (f32x4v)(0.0f);

    auto panel = [&](const bf16* Ap, const bf16* Bp, int K) {
        for (int k0 = 0; k0 < K; k0 += BK) {
#pragma unroll
            for (int rnd = 0; rnd < 2; ++rnd) {
                int row = srow + rnd * 64;
                int ga = bm0 + row; ga = (ga < R) ? ga : (R - 1);
                int4 va = *(const int4*)(Ap + (size_t)ga * K + k0 + scol);
                *(int4*)&As[row * LDST + scol] = va;
                int4 vb = *(const int4*)(Bp + (size_t)(bn0 + row) * K + k0 + scol);
                *(int4*)&Bs[row * LDST + scol] = vb;
            }
            __syncthreads();
            bf16x8v af[4], bfv[4];
#pragma unroll
            for (int i = 0; i < 4; ++i) {
                af[i]  = *(const bf16x8v*)&As[(wm + i * 16 + l15) * LDST + q8];
                bfv[i] = *(const bf16x8v*)&Bs[(wn + i * 16 + l15) * LDST + q8];
            }
#pragma unroll
            for (int i = 0; i < 4; ++i)
#pragma unroll
                for (int j = 0; j < 4; ++j)
                    acc[i][j] = __builtin_amdgcn_mfma_f32_16x16x32_bf16(
                        af[i], bfv[j], acc[i][j], 0, 0, 0);
            __syncthreads();
        }
    };
    panel(A1, B1, 128);
    if (A2) panel(A2, B2, H2);

    // ---- fused LSTM cell epilogue
    const int u = ((bn0 + wn) >> 6) * 16 + l15;      // hidden unit 0..191
    const float awu = aw[u];
    float bv[4];
#pragma unroll
    for (int j = 0; j < 4; ++j) bv[j] = bias[bn0 + wn + j * 16 + l15];
    float psum[4][4];
#pragma unroll
    for (int i = 0; i < 4; ++i) {
        const int row0 = bm0 + wm + i * 16 + q * 4;
#pragma unroll
        for (int r = 0; r < 4; ++r) {
            const int gr = row0 + r;
            const bool ok = gr < R;
            float ig = acc[i][0][r] + bv[0];
            float fg = acc[i][1][r] + bv[1];
            float gg = acc[i][2][r] + bv[2];
            float og = acc[i][3][r] + bv[3];
            float si = 1.f / (1.f + __expf(-ig));
            float sf = 1.f / (1.f + __expf(-fg));
            float so = 1.f / (1.f + __expf(-og));
            float co = (ok && A2) ? b2f(c_state[(size_t)gr * H2 + u]) : 0.f;
            float cn = sf * co + si * ftanh(gg);
            float hn = so * ftanh(cn);
            if (ok) {
                c_state[(size_t)gr * H2 + u] = f2b(cn);
                h_out[(size_t)gr * H2 + u] = f2b(hn);
            }
            psum[i][r] = hn * awu;
        }
    }
#pragma unroll
    for (int m = 1; m < 16; m <<= 1)
#pragma unroll
        for (int i = 0; i < 4; ++i)
#pragma unroll
            for (int r = 0; r < 4; ++r)
                psum[i][r] += __shfl_xor(psum[i][r], m);
    if (l15 == 0) {
#pragma unroll
        for (int i = 0; i < 4; ++i)
#pragma unroll
            for (int r = 0; r < 4; ++r) {
                const int gr = bm0 + wm + i * 16 + q * 4 + r;
                if (gr < R) atomicAdd(&score[gr], psum[i][r]);
            }
    }
}

// Layer-0 conv GEMM: A built on the fly from embeddings (K=128 fixed)
__global__ __launch_bounds__(256) void mfma_gemm_x0_kernel(
    const int* __restrict__ xidx, const float* __restrict__ xflt,
    const float* __restrict__ embA, const float* __restrict__ embS,
    const bf16* __restrict__ B1, bf16* __restrict__ C, int R, int M) {
    __shared__ bf16 As[128 * LDST];
    __shared__ bf16 Bs[128 * LDST];
    int bm0, bn0;
    if (!swz_tile(R, M >> 7, bm0, bn0)) return;
    const int tid = threadIdx.x;
    const int lane = tid & 63;
    const int wave = tid >> 6;
    const int wm = (wave & 1) * 64, wn = (wave >> 1) * 64;
    const int l15 = lane & 15;
    const int q8 = (lane >> 4) * 8;
    const int srow = tid >> 2;
    const int scol = (tid & 3) * 8;

    f32x4v acc[4][4];
#pragma unroll
    for (int i = 0; i < 4; ++i)
#pragma unroll
        for (int j = 0; j < 4; ++j) acc[i][j] = (f32x4v)(0.0f);

    for (int k0 = 0; k0 < 128; k0 += BK) {
#pragma unroll
        for (int rnd = 0; rnd < 2; ++rnd) {
            int row = srow + rnd * 64;
            int ga = bm0 + row; ga = (ga < R) ? ga : (R - 1);
            int ia = xidx[2 * ga], is_ = xidx[2 * ga + 1];
            bf16 tmp[8];
#pragma unroll
            for (int t = 0; t < 8; ++t)
                tmp[t] = f2b(x0_val(k0 + scol + t, ia, is_, ga, embA, embS, xflt));
            *(int4*)&As[row * LDST + scol] = *(const int4*)tmp;
            int4 vb = *(const int4*)(B1 + (size_t)(bn0 + row) * 128 + k0 + scol);
            *(int4*)&Bs[row * LDST + scol] = vb;
        }
        __syncthreads();
        bf16x8v af[4], bfv[4];
#pragma unroll
        for (int i = 0; i < 4; ++i) {
            af[i]  = *(const bf16x8v*)&As[(wm + i * 16 + l15) * LDST + q8];
            bfv[i] = *(const bf16x8v*)&Bs[(wn + i * 16 + l15) * LDST + q8];
        }
#pragma unroll
        for (int i = 0; i < 4; ++i)
#pragma unroll
            for (int j = 0; j < 4; ++j)
                acc[i][j] = __builtin_amdgcn_mfma_f32_16x16x32_bf16(
                    af[i], bfv[j], acc[i][j], 0, 0, 0);
        __syncthreads();
    }
#pragma unroll
    for (int i = 0; i < 4; ++i) {
        const int row0 = bm0 + wm + i * 16 + (lane >> 4) * 4;
#pragma unroll
        for (int j = 0; j < 4; ++j) {
            const int col = bn0 + wn + j * 16 + l15;
#pragma unroll
            for (int r = 0; r < 4; ++r) {
                const int gr = row0 + r;
                if (gr < R) C[(size_t)gr * M + col] = f2b(acc[i][j][r]);
            }
        }
    }
}

// ---------------------------------------------------------------- GAT pieces

__global__ __launch_bounds__(256) void att_kernel(
    const bf16* __restrict__ xh, const float* __restrict__ as_,
    const float* __restrict__ ad_, float* __restrict__ asrc, float* __restrict__ adst) {
    int w = (blockIdx.x * blockDim.x + threadIdx.x) >> 6;
    int lane = threadIdx.x & 63;
    if (w >= N_NODES) return;
    const bf16* row = xh + (size_t)w * 256;
    float x0 = b2f(row[lane]), x1 = b2f(row[64 + lane]);
    float x2 = b2f(row[128 + lane]), x3 = b2f(row[192 + lane]);
    float s0 = x0 * as_[lane] + x1 * as_[64 + lane];
    float s1 = x2 * as_[128 + lane] + x3 * as_[192 + lane];
    float d0 = x0 * ad_[lane] + x1 * ad_[64 + lane];
    float d1 = x2 * ad_[128 + lane] + x3 * ad_[192 + lane];
    for (int o = 1; o < 64; o <<= 1) {
        s0 += __shfl_xor(s0, o); s1 += __shfl_xor(s1, o);
        d0 += __shfl_xor(d0, o); d1 += __shfl_xor(d1, o);
    }
    if (lane == 0) {
        asrc[2 * w] = s0; asrc[2 * w + 1] = s1;
        adst[2 * w] = d0; adst[2 * w + 1] = d1;
    }
}

__device__ __forceinline__ float lrelu02(float x) { return x > 0.f ? x : 0.2f * x; }

// one wave per dst node: online-softmax pass + 2-edge/iter gather
__global__ __launch_bounds__(256) void agg_kernel(
    const bf16* __restrict__ xh, const float* __restrict__ asrc,
    const float* __restrict__ adst, const int* __restrict__ offs,
    const int* __restrict__ srcs,
    const bf16* __restrict__ xprev_l, const bf16* __restrict__ xprev_r,
    const int* __restrict__ xidx, const float* __restrict__ xflt,
    const float* __restrict__ embAl, const float* __restrict__ embSl,
    const float* __restrict__ embAr, const float* __restrict__ embSr,
    const float* __restrict__ bias, bf16* __restrict__ outx) {
    int n = (blockIdx.x * blockDim.x + threadIdx.x) >> 6;
    int lane = threadIdx.x & 63;
    if (n >= N_NODES) return;
    const int start = offs[n], end = offs[n + 1];
    const float ad0 = adst[2 * n], ad1 = adst[2 * n + 1];

    // pass 1: online softmax (m, d) per head, lane-parallel
    float m0 = -1e30f, d0 = 0.f, m1 = -1e30f, d1 = 0.f;
    for (int j = start + lane; j < end; j += 64) {
        int s = srcs[j];
        float2 a2 = *(const float2*)(asrc + 2 * s);
        float a0 = lrelu02(a2.x + ad0);
        float a1 = lrelu02(a2.y + ad1);
        float nm0 = fmaxf(m0, a0);
        d0 = d0 * __expf(m0 - nm0) + __expf(a0 - nm0); m0 = nm0;
        float nm1 = fmaxf(m1, a1);
        d1 = d1 * __expf(m1 - nm1) + __expf(a1 - nm1); m1 = nm1;
    }
    for (int o = 1; o < 64; o <<= 1) {
        float om = __shfl_xor(m0, o), od = __shfl_xor(d0, o);
        float nm = fmaxf(m0, om);
        d0 = d0 * __expf(m0 - nm) + od * __expf(om - nm); m0 = nm;
        om = __shfl_xor(m1, o); od = __shfl_xor(d1, o);
        nm = fmaxf(m1, om);
        d1 = d1 * __expf(m1 - nm) + od * __expf(om - nm); m1 = nm;
    }
    const float inv0 = 1.f / (d0 + 1e-16f), inv1 = 1.f / (d1 + 1e-16f);

    // pass 2: gather, 2 edges per iteration (half-wave per edge, 16 B/lane)
    const int eh = lane >> 5;           // which edge of the pair
    const int l32 = lane & 31;
    const int head = l32 >> 4;          // head within edge
    const int l15 = l32 & 15;
    const int col = head * 128 + l15 * 8;
    const float mh = head ? m1 : m0;
    const float invh = head ? inv1 : inv0;
    const float adh = head ? ad1 : ad0;

    float acc[8] = {0.f, 0.f, 0.f, 0.f, 0.f, 0.f, 0.f, 0.f};
#pragma unroll 2
    for (int j = start; j < end; j += 2) {
        int e = j + eh;
        if (e < end) {
            int s = srcs[e];
            float a = asrc[2 * s + head] + adh;
            float al = __expf(lrelu02(a) - mh) * invh;
            int4 v = *(const int4*)(xh + (size_t)s * 256 + col);
            const int* w = (const int*)&v;
#pragma unroll
            for (int t = 0; t < 4; ++t) {
                float lo = __uint_as_float(((unsigned)w[t]) << 16);
                float hi = __uint_as_float(((unsigned)w[t]) & 0xffff0000u);
                acc[2 * t]     += lo * al;
                acc[2 * t + 1] += hi * al;
            }
        }
    }
#pragma unroll
    for (int t = 0; t < 8; ++t) acc[t] += __shfl_xor(acc[t], 32);  // edge parity
#pragma unroll
    for (int t = 0; t < 8; ++t)
        acc[t] = 0.5f * (acc[t] + __shfl_xor(acc[t], 16));         // head mean

    if (lane < 16) {
        const int c0 = lane * 8;
        const size_t base = (size_t)n * HID + c0;
        float xm[8];
        if (xidx) {
            int ia = xidx[2 * n], is_ = xidx[2 * n + 1];
#pragma unroll
            for (int t = 0; t < 8; ++t)
                xm[t] = 0.5f * (x0_val(c0 + t, ia, is_, n, embAl, embSl, xflt) +
                                x0_val(c0 + t, ia, is_, n, embAr, embSr, xflt));
        } else {
            int4 vl = *(const int4*)(xprev_l + base);
            int4 vr = *(const int4*)(xprev_r + base);
            const int* wl = (const int*)&vl;
            const int* wr = (const int*)&vr;
#pragma unroll
            for (int t = 0; t < 4; ++t) {
                xm[2 * t] = 0.5f * (__uint_as_float(((unsigned)wl[t]) << 16) +
                                    __uint_as_float(((unsigned)wr[t]) << 16));
                xm[2 * t + 1] = 0.5f * (__uint_as_float(((unsigned)wl[t]) & 0xffff0000u) +
                                        __uint_as_float(((unsigned)wr[t]) & 0xffff0000u));
            }
        }
        bf16 res[8];
#pragma unroll
        for (int t = 0; t < 8; ++t)
            res[t] = f2b(xm[t] + fmaxf(0.f, acc[t] + bias[c0 + t]));
        *(int4*)(outx + base) = *(const int4*)res;
    }
}

// ---------------------------------------------------------------- JK / final

__global__ __launch_bounds__(256) void jkfin_kernel(
    const float* __restrict__ sb, const bf16* __restrict__ xs0,
    const bf16* __restrict__ xs1, const bf16* __restrict__ xs2,
    bf16* __restrict__ jk) {
    int w = (blockIdx.x * blockDim.x + threadIdx.x) >> 6;
    int lane = threadIdx.x & 63;
    if (w >= N_NODES) return;
    float s0 = sb[w], s1 = sb[N_NODES + w], s2 = sb[2 * N_NODES + w];
    float m = fmaxf(s0, fmaxf(s1, s2));
    float a0 = __expf(s0 - m), a1 = __expf(s1 - m), a2 = __expf(s2 - m);
    float inv = 1.f / (a0 + a1 + a2);
    a0 *= inv; a1 *= inv; a2 *= inv;
    size_t gn = (size_t)w * HID + lane * 2;
#pragma unroll
    for (int t = 0; t < 2; ++t) {
        float v0 = b2f(xs0[gn + t]);
        float v1 = b2f(xs1[gn + t]);
        float v2 = b2f(xs2[gn + t]);
        jk[gn + t] = f2b(v0 * a0 + v1 * a1 + v2 * a2);
    }
}

__global__ __launch_bounds__(256) void final_kernel(
    const float* __restrict__ o0, const float* __restrict__ o1,
    const float* __restrict__ o2, const float* __restrict__ o3,
    const float* __restrict__ lw, float* __restrict__ out, int nloc, long long c3off) {
    int w = (blockIdx.x * blockDim.x + threadIdx.x) >> 6;
    int lane = threadIdx.x & 63;
    if (w >= nloc) return;
    size_t base = (size_t)w * HID;
    float w0 = lw[lane], w1 = lw[64 + lane];
    const float* op[4] = {o0, o1, o2, o3};
    float v[4][2];
    float s[4];
#pragma unroll
    for (int i = 0; i < 4; ++i) {
        v[i][0] = op[i][base + lane];
        v[i][1] = op[i][base + 64 + lane];
        float t = v[i][0] * w0 + v[i][1] * w1;
        for (int o = 1; o < 64; o <<= 1) t += __shfl_xor(t, o);
        s[i] = t;
    }
    float m = fmaxf(fmaxf(s[0], s[1]), fmaxf(s[2], s[3]));
    float e0 = __expf(s[0] - m), e1 = __expf(s[1] - m);
    float e2 = __expf(s[2] - m), e3 = __expf(s[3] - m);
    float inv = 1.f / (e0 + e1 + e2 + e3);
    float r0 = (v[0][0] * e0 + v[1][0] * e1 + v[2][0] * e2 + v[3][0] * e3) * inv;
    float r1 = (v[0][1] * e0 + v[1][1] * e1 + v[2][1] * e2 + v[3][1] * e3) * inv;
    size_t obase = (size_t)(c3off + w) * HID;
    out[obase + lane] = r0;
    out[obase + 64 + lane] = r1;
}

// ---------------------------------------------------------------- entry

static long long align1k(long long x) { return (x + 1023) & ~1023LL; }

extern "C" void kernel_launch(void* const* d_in, const int* in_sizes, int n_in,
                              void* d_out, int out_size, void* d_ws, size_t ws_size,
                              hipStream_t stream) {
    (void)in_sizes; (void)n_in; (void)out_size;
    const int*   x_idx   = (const int*)  d_in[0];
    const float* x_flt   = (const float*)d_in[1];
    const int*   ei_l    = (const int*)  d_in[2];
    const int*   ei_r    = (const int*)  d_in[3];
    const float* emb_aa  = (const float*)d_in[4];
    const float* emb_ss  = (const float*)d_in[5];
    const float* conv_W  = (const float*)d_in[6];
    const float* att_s   = (const float*)d_in[7];
    const float* att_d   = (const float*)d_in[8];
    const float* conv_b  = (const float*)d_in[9];
    const float* Wih     = (const float*)d_in[10];
    const float* Whh     = (const float*)d_in[11];
    const float* bih     = (const float*)d_in[12];
    const float* bhh     = (const float*)d_in[13];
    const float* jkw     = (const float*)d_in[14];
    const float* dummy_W = (const float*)d_in[16];
    const float* dummy_b = (const float*)d_in[17];
    const float* fin_W   = (const float*)d_in[18];
    const float* fin_b   = (const float*)d_in[19];
    const float* last_W  = (const float*)d_in[20];
    float* out = (float*)d_out;

    const long long S = (long long)N_NODES * HID;
    char* ws = (char*)d_ws;
    long long off = 0;

    // hist: 6 bf16 slabs; stage 3 reuses as fp32 scratch
    bf16* hist = (bf16*)(ws + off);
    off += align1k(6 * S * 2);
    // R1: stage0/1 {CSR ints, asrc, adst, convWt} | stage2 {c-state bf16, N x 192}
    char* R1 = ws + off;
    {
        long long io4 = 2LL * (N_NODES + (N_NODES + 1) + N_NODES + EL_TOT) * 4;
        long long st01 = ((io4 + 15) & ~15LL) + 4LL * N_NODES * 4 + 6LL * 256 * 128 * 2;
        long long st2  = (long long)N_NODES * H2 * 2;
        off += align1k(st01 > st2 ? st01 : st2);
    }
    // R2: stage1 xh (N x 256 bf16) | stage2 h (N x 192 bf16) | stage2-end/3 jk
    char* R2 = ws + off;
    off += align1k(2 * S * 2);
    float* scores = (float*)(ws + off); off += align1k(6LL * N_NODES * 4);
    float* bsum   = (float*)(ws + off); off += align1k(4LL * G4 * 4);
    bf16* Wih_b   = (bf16*)(ws + off); off += align1k(4LL * G4 * HID * 2);
    bf16* Whh_b   = (bf16*)(ws + off); off += align1k(4LL * G4 * H2 * 2);
    bf16* dummyWt = (bf16*)(ws + off); off += align1k(2LL * 128 * 128 * 2);
    bf16* finWt   = (bf16*)(ws + off); off += align1k(4LL * 128 * 128 * 2);

    if ((long long)ws_size < off) {   // diagnosable: 200000 + ws MiB
        float val = 200000.0f + (float)(ws_size >> 20);
        sentinel_kernel<<<(N_NODES * HID + 255) / 256, 256, 0, stream>>>(
            out, N_NODES * HID, val);
        return;
    }

    // R1 stage0/1 views
    int* ibase = (int*)R1;
    int *deg[2], *offs[2], *pos[2], *srcs[2];
    long long io = 0;
    for (int b = 0; b < 2; ++b) {
        deg[b]  = ibase + io; io += N_NODES;
        offs[b] = ibase + io; io += N_NODES + 1;
        pos[b]  = ibase + io; io += N_NODES;
        srcs[b] = ibase + io; io += EL_TOT;
    }
    long long io4a = ((io * 4 + 15) & ~15LL);
    float* asrc = (float*)(R1 + io4a);
    float* adst = asrc + 2LL * N_NODES;
    bf16* convWt = (bf16*)(R1 + io4a + 4LL * N_NODES * 4);
    // stage2 views
    bf16* cbuf = (bf16*)R1;
    bf16* hbuf = (bf16*)R2;
    // R2 views
    bf16* xh  = (bf16*)R2;
    bf16* jkb = (bf16*)R2;

    const float* embA[2] = {emb_aa, emb_aa + 26 * 123};
    const float* embS[2] = {emb_ss, emb_ss + 3 * 123};

    // ---- stage 0: weight conversion (LSTM weights gate-permuted) + CSR
    bsum_perm_kernel<<<12, 256, 0, stream>>>(bih, bhh, bsum);
    trans_kernel<<<(6 * 128 * 256 + 255) / 256, 256, 0, stream>>>(
        conv_W, convWt, 6, 128, 256);
    lstm_w_perm_kernel<<<(4 * G4 * HID + 255) / 256, 256, 0, stream>>>(
        Wih, Wih_b, HID);
    lstm_w_perm_kernel<<<(4 * G4 * H2 + 255) / 256, 256, 0, stream>>>(
        Whh, Whh_b, H2);
    trans_kernel<<<(2 * 128 * 128 + 255) / 256, 256, 0, stream>>>(
        dummy_W, dummyWt, 2, 128, 128);
    trans_kernel<<<(4 * 128 * 128 + 255) / 256, 256, 0, stream>>>(
        fin_W, finWt, 4, 128, 128);
    for (int b = 0; b < 2; ++b) {
        const int* ei = b ? ei_r : ei_l;
        hipMemsetAsync(deg[b], 0, N_NODES * sizeof(int), stream);
        deg_kernel<<<(EL_TOT + 255) / 256, 256, 0, stream>>>(ei + N_EDGES, deg[b]);
        scan_kernel<<<1, 1024, 0, stream>>>(deg[b], offs[b], N_NODES);
        copy_int_kernel<<<(N_NODES + 255) / 256, 256, 0, stream>>>(offs[b], pos[b], N_NODES);
        fill_kernel<<<(EL_TOT + 255) / 256, 256, 0, stream>>>(
            ei, ei + N_EDGES, pos[b], srcs[b]);
    }

    // ---- stage 1: 3 GAT layers x 2 branches
    for (int i = 0; i < 3; ++i) {
        for (int b = 0; b < 2; ++b) {
            const bf16* Wc = convWt + (size_t)(b * 3 + i) * 256 * 128;
            if (i == 0) {
                mfma_gemm_x0_kernel<<<swz_grid(N_NODES, 2), 256, 0, stream>>>(
                    x_idx, x_flt, embA[b], embS[b], Wc, xh, N_NODES, 256);
            } else {
                mfma_gemm<bf16>(hist + (size_t)(b * 3 + i - 1) * S, Wc, 128,
                                nullptr, nullptr, 0, xh, nullptr, N_NODES, 256, stream);
            }
            att_kernel<<<25000, 256, 0, stream>>>(
                xh, att_s + (size_t)(b * 3 + i) * 2 * HID,
                att_d + (size_t)(b * 3 + i) * 2 * HID, asrc, adst);
            const bf16* xpl = (i == 0) ? nullptr : hist + (size_t)(i - 1) * S;
            const bf16* xpr = (i == 0) ? nullptr : hist + (size_t)(3 + i - 1) * S;
            agg_kernel<<<25000, 256, 0, stream>>>(
                xh, asrc, adst, offs[b], srcs[b], xpl, xpr,
                (i == 0) ? x_idx : nullptr, x_flt,
                embA[0], embS[0], embA[1], embS[1],
                conv_b + (size_t)(b * 3 + i) * HID, hist + (size_t)(b * 3 + i) * S);
        }
    }

    // ---- stage 2: bi-LSTM JK, full-N, fused cell epilogue
    hipMemsetAsync(scores, 0, (size_t)6 * N_NODES * 4, stream);
    for (int b = 0; b < 2; ++b) {
        for (int dir = 0; dir < 2; ++dir) {
            const bf16* Wi = Wih_b + (size_t)(b * 2 + dir) * G4 * HID;
            const bf16* Wh = Whh_b + (size_t)(b * 2 + dir) * G4 * H2;
            const float* bs = bsum + (size_t)(b * 2 + dir) * G4;
            const float* aw = jkw + (size_t)b * 2 * H2 + (size_t)dir * H2;
            for (int st = 0; st < 3; ++st) {
                int l = dir ? (2 - st) : st;
                const bf16* A = hist + (size_t)(b * 3 + l) * S;
                lstm_gemm_kernel<<<swz_grid(N_NODES, 6), 256, 0, stream>>>(
                    A, Wi, (st == 0) ? nullptr : hbuf, Wh, bs, cbuf, hbuf, aw,
                    scores + (size_t)(b * 3 + l) * N_NODES, N_NODES);
            }
        }
    }
    for (int b = 0; b < 2; ++b)
        jkfin_kernel<<<25000, 256, 0, stream>>>(
            scores + (size_t)b * 3 * N_NODES,
            hist + (size_t)b * 3 * S, hist + (size_t)(b * 3 + 1) * S,
            hist + (size_t)(b * 3 + 2) * S, jkb + (size_t)b * S);

    // ---- stage 3: sq, outs, final combine (scratch = freed hist region)
    float* f3 = (float*)hist;
    bf16* jkl = jkb; bf16* jkr = jkb + S;
    for (long long c3 = 0; c3 < N_NODES; c3 += CH3) {
        int Rr = (int)((N_NODES - c3) < CH3 ? (N_NODES - c3) : CH3);
        float* o0 = f3;
        float* o1 = f3 + 1LL * CH3 * HID;
        float* o2 = f3 + 2LL * CH3 * HID;
        float* o3 = f3 + 3LL * CH3 * HID;
        bf16* sql = (bf16*)(f3 + 4LL * CH3 * HID);
        bf16* sqr = sql + (long long)CH3 * HID;
        mfma_gemm<bf16>(jkl + c3 * HID, dummyWt, 128, nullptr, nullptr, 0,
                        sql, dummy_b, Rr, 128, stream);
        mfma_gemm<bf16>(jkr + c3 * HID, dummyWt + 16384, 128, nullptr, nullptr, 0,
                        sqr, dummy_b + 128, Rr, 128, stream);
        mfma_gemm<float>(jkl + c3 * HID, finWt, 128, nullptr, nullptr, 0,
                         o0, fin_b, Rr, 128, stream);
        mfma_gemm<float>(sql, finWt + 16384, 128, nullptr, nullptr, 0,
                         o1, fin_b + 128, Rr, 128, stream);
        mfma_gemm<float>(jkr + c3 * HID, finWt + 2 * 16384, 128, nullptr, nullptr, 0,
                         o2, fin_b + 256, Rr, 128, stream);
        mfma_gemm<float>(sqr, finWt + 3 * 16384, 128, nullptr, nullptr, 0,
                         o3, fin_b + 384, Rr, 128, stream);
        final_kernel<<<(Rr + 3) / 4, 256, 0, stream>>>(
            o0, o1, o2, o3, last_W, out, Rr, c3);
    }
}

// Round 8
// 3752.399 us; speedup vs baseline: 7.0023x; 1.0193x over previous
//
#include <hip/hip_runtime.h>
#include <cstddef>
#include <cstdint>

#define N_NODES 100000
#define N_EDGES 800000
#define EL_TOT  900000      // edges + self loops
#define HID 128
#define H2  192
#define G4  768             // 4*H2
#define CH3 50000           // stage-3 chunk
#define BK  32
#define LDST 32             // UNPADDED: required by global_load_lds lane mapping

typedef unsigned short bf16;
typedef __attribute__((ext_vector_type(8))) short bf16x8v;
typedef __attribute__((ext_vector_type(4))) float f32x4v;

#define AS1 __attribute__((address_space(1)))
#define AS3 __attribute__((address_space(3)))

// async global->LDS, 16B per lane; lds base must be wave-uniform (lane i -> +i*16B)
__device__ __forceinline__ void async16(const bf16* g, bf16* l) {
    __builtin_amdgcn_global_load_lds((AS1 void*)g, (AS3 void*)l, 16, 0, 0);
}

// ---------------------------------------------------------------- dtype helpers

__device__ __forceinline__ float b2f(bf16 u) {
    return __uint_as_float(((unsigned)u) << 16);
}
__device__ __forceinline__ bf16 f2b(float f) {   // round-nearest-even
    unsigned u = __float_as_uint(f);
    u += 0x7FFFu + ((u >> 16) & 1u);
    return (bf16)(u >> 16);
}
__device__ __forceinline__ void stE(float* p, size_t i, float v) { p[i] = v; }
__device__ __forceinline__ void stE(bf16* p, size_t i, float v) { p[i] = f2b(v); }
__device__ __forceinline__ float ftanh(float x) {
    float cx = fminf(fmaxf(x, -15.f), 15.f);
    float e = __expf(2.f * cx);
    return (e - 1.f) / (e + 1.f);
}

// x0 recompute: column c of node n for one branch
__device__ __forceinline__ float x0_val(int c, int ia, int is_, int n,
                                        const float* __restrict__ embA,
                                        const float* __restrict__ embS,
                                        const float* __restrict__ xflt) {
    return (c < 123) ? (embA[ia * 123 + c] + embS[is_ * 123 + c])
                     : xflt[n * 5 + (c - 123)];
}

// LSTM gate-column permutation: new col j -> orig gate row
__device__ __forceinline__ int lstm_perm(int j) {
    int w = j & 63, tt = j >> 6;
    return (w >> 4) * 192 + tt * 16 + (w & 15);   // gate*192 + unit
}

// XCD-aware swizzle: the ntile column tiles of one row panel are consecutive
// blocks on the SAME XCD (id%8 heuristic) -> A-panel re-reads hit that L2.
__device__ __forceinline__ bool swz_tile(int R, int ntile, int& bm0, int& bn0) {
    const int id = blockIdx.x;
    const int xcd = id & 7;
    const int s = id >> 3;
    const int nt = s % ntile;
    const int yp = (s / ntile) * 8 + xcd;
    if (yp * 128 >= R) return false;
    bm0 = yp * 128; bn0 = nt * 128;
    return true;
}
static inline int swz_grid(int R, int ntile) {
    int panels = (R + 127) / 128;
    return 8 * ntile * ((panels + 7) / 8);
}

// ---------------------------------------------------------------- utilities

__global__ void sentinel_kernel(float* out, int n, float val) {
    int t = blockIdx.x * blockDim.x + threadIdx.x;
    if (t < n) out[t] = val;
}

__global__ void bsum_perm_kernel(const float* __restrict__ bih,
                                 const float* __restrict__ bhh,
                                 float* __restrict__ bsum) {
    int t = blockIdx.x * blockDim.x + threadIdx.x;
    if (t >= 4 * G4) return;
    int d = t / G4, j = t % G4;
    int orig = lstm_perm(j);
    bsum[t] = bih[d * G4 + orig] + bhh[d * G4 + orig];
}

// permute gate rows + convert to bf16: out[d][j][k] = in[d][perm(j)][k]
__global__ void lstm_w_perm_kernel(const float* __restrict__ in,
                                   bf16* __restrict__ out, int K) {
    long long t = (long long)blockIdx.x * blockDim.x + threadIdx.x;
    long long tot = 4LL * G4 * K;
    if (t >= tot) return;
    int k = (int)(t % K);
    int j = (int)((t / K) % G4);
    int d = (int)(t / ((long long)G4 * K));
    int orig = lstm_perm(j);
    out[t] = f2b(in[((size_t)d * G4 + orig) * K + k]);
}

// out[bt][m][k] = in[bt][k][m]  ((K,M) -> (M,K) bf16)
__global__ void trans_kernel(const float* __restrict__ in, bf16* __restrict__ out,
                             int batch, int K, int M) {
    long long t = (long long)blockIdx.x * blockDim.x + threadIdx.x;
    long long tot = (long long)batch * K * M;
    if (t >= tot) return;
    int per = K * M;
    int bt = (int)(t / per);
    int rem = (int)(t % per);
    int m = rem / K, k = rem % K;
    out[t] = f2b(in[(size_t)bt * per + (size_t)k * M + m]);
}

// ---------------------------------------------------------------- CSR build

__global__ void deg_kernel(const int* __restrict__ dst, int* __restrict__ deg) {
    int t = blockIdx.x * blockDim.x + threadIdx.x;
    if (t >= EL_TOT) return;
    int d = (t < N_EDGES) ? dst[t] : (t - N_EDGES);
    atomicAdd(&deg[d], 1);
}

__global__ void scan_kernel(const int* __restrict__ deg, int* __restrict__ offs, int n) {
    __shared__ int sdata[1024];
    __shared__ int carry;
    if (threadIdx.x == 0) carry = 0;
    __syncthreads();
    for (int base = 0; base < n; base += 1024) {
        int i = base + (int)threadIdx.x;
        int v = (i < n) ? deg[i] : 0;
        sdata[threadIdx.x] = v;
        __syncthreads();
        for (int off = 1; off < 1024; off <<= 1) {
            int t = (threadIdx.x >= (unsigned)off) ? sdata[threadIdx.x - off] : 0;
            __syncthreads();
            sdata[threadIdx.x] += t;
            __syncthreads();
        }
        if (i < n) offs[i + 1] = carry + sdata[threadIdx.x];
        __syncthreads();
        if (threadIdx.x == 1023) carry += sdata[1023];
        __syncthreads();
    }
    if (threadIdx.x == 0) offs[0] = 0;
}

__global__ void copy_int_kernel(const int* __restrict__ a, int* __restrict__ b, int n) {
    int t = blockIdx.x * blockDim.x + threadIdx.x;
    if (t < n) b[t] = a[t];
}

// store RESOLVED src (self-loop src = node id) at CSR position
__global__ void fill_kernel(const int* __restrict__ srcrow,
                            const int* __restrict__ dstrow,
                            int* __restrict__ pos, int* __restrict__ srcs) {
    int t = blockIdx.x * blockDim.x + threadIdx.x;
    if (t >= EL_TOT) return;
    int s, d;
    if (t < N_EDGES) { s = srcrow[t]; d = dstrow[t]; }
    else             { s = d = t - N_EDGES; }
    int p = atomicAdd(&pos[d], 1);
    srcs[p] = s;
}

// ---------------------------------------------------------------- MFMA GEMM
// C(RxM) = A1(RxK1) @ B1t(MxK1)^T [+ A2(RxK2) @ B2t(MxK2)^T] + bias[col]
// m97-style: global_load_lds(16B) staging into unpadded LDS tiles.
template<typename TC>
__global__ __launch_bounds__(256) void mfma_gemm_kernel(
    const bf16* __restrict__ A1, const bf16* __restrict__ B1, int K1,
    const bf16* __restrict__ A2, const bf16* __restrict__ B2, int K2,
    TC* __restrict__ C, const float* __restrict__ bias, int R, int M) {
    __shared__ bf16 As[128 * LDST];
    __shared__ bf16 Bs[128 * LDST];
    int bm0, bn0;
    if (!swz_tile(R, M >> 7, bm0, bn0)) return;
    const int tid = threadIdx.x;
    const int lane = tid & 63;
    const int wave = tid >> 6;
    const int wm = (wave & 1) * 64, wn = (wave >> 1) * 64;
    const int l15 = lane & 15;
    const int q8 = (lane >> 4) * 8;
    const int lr = lane >> 2;            // row-within-wave-panel
    const int lc = (lane & 3) * 8;       // col elems

    f32x4v acc[4][4];
#pragma unroll
    for (int i = 0; i < 4; ++i)
#pragma unroll
        for (int j = 0; j < 4; ++j) acc[i][j] = (f32x4v)(0.0f);

    auto panel = [&](const bf16* Ap, const bf16* Bp, int K) {
        for (int k0 = 0; k0 < K; k0 += BK) {
#pragma unroll
            for (int rnd = 0; rnd < 2; ++rnd) {
                const int rbase = wave * 16 + rnd * 64;
                int row = rbase + lr;
                int ga = bm0 + row; ga = (ga < R) ? ga : (R - 1);
                async16(Ap + (size_t)ga * K + k0 + lc, &As[rbase * LDST]);
                async16(Bp + (size_t)(bn0 + row) * K + k0 + lc, &Bs[rbase * LDST]);
            }
            __syncthreads();
            bf16x8v af[4], bfv[4];
#pragma unroll
            for (int i = 0; i < 4; ++i) {
                af[i]  = *(const bf16x8v*)&As[(wm + i * 16 + l15) * LDST + q8];
                bfv[i] = *(const bf16x8v*)&Bs[(wn + i * 16 + l15) * LDST + q8];
            }
#pragma unroll
            for (int i = 0; i < 4; ++i)
#pragma unroll
                for (int j = 0; j < 4; ++j)
                    acc[i][j] = __builtin_amdgcn_mfma_f32_16x16x32_bf16(
                        af[i], bfv[j], acc[i][j], 0, 0, 0);
            __syncthreads();
        }
    };
    panel(A1, B1, K1);
    if (A2) panel(A2, B2, K2);

#pragma unroll
    for (int i = 0; i < 4; ++i) {
        const int row0 = bm0 + wm + i * 16 + (lane >> 4) * 4;
#pragma unroll
        for (int j = 0; j < 4; ++j) {
            const int col = bn0 + wn + j * 16 + l15;
            const float bv = bias ? bias[col] : 0.f;
#pragma unroll
            for (int r = 0; r < 4; ++r) {
                const int gr = row0 + r;
                if (gr < R) stE(C, (size_t)gr * M + col, acc[i][j][r] + bv);
            }
        }
    }
}

template<typename TC>
static void mfma_gemm(const bf16* A1, const bf16* B1, int K1,
                      const bf16* A2, const bf16* B2, int K2,
                      TC* C, const float* bias, int R, int M, hipStream_t s) {
    mfma_gemm_kernel<TC><<<swz_grid(R, M / 128), 256, 0, s>>>(
        A1, B1, K1, A2, B2, K2, C, bias, R, M);
}

// ---------------------------------------------------------------- fused LSTM GEMM
// Permuted col j: tile64*64 + gate*16 + unitlocal -> lane's 4 j-frags are
// i,f,g,o of ONE unit. Epilogue does the LSTM cell + JK score partial.
// A2==nullptr means step 0: h panel skipped AND c_prev treated as 0.
__global__ __launch_bounds__(256) void lstm_gemm_kernel(
    const bf16* __restrict__ A1, const bf16* __restrict__ B1,
    const bf16* __restrict__ A2, const bf16* __restrict__ B2,
    const float* __restrict__ bias, bf16* __restrict__ c_state,
    bf16* __restrict__ h_out, const float* __restrict__ aw,
    float* __restrict__ score, int R) {
    __shared__ bf16 As[128 * LDST];
    __shared__ bf16 Bs[128 * LDST];
    int bm0, bn0;
    if (!swz_tile(R, G4 >> 7, bm0, bn0)) return;
    const int tid = threadIdx.x;
    const int lane = tid & 63;
    const int wave = tid >> 6;
    const int wm = (wave & 1) * 64, wn = (wave >> 1) * 64;
    const int l15 = lane & 15;
    const int q = lane >> 4;
    const int q8 = q * 8;
    const int lr = lane >> 2;
    const int lc = (lane & 3) * 8;

    f32x4v acc[4][4];
#pragma unroll
    for (int i = 0; i < 4; ++i)
#pragma unroll
        for (int j = 0; j < 4; ++j) acc[i][j] = (f32x4v)(0.0f);

    auto panel = [&](const bf16* Ap, const bf16* Bp, int K) {
        for (int k0 = 0; k0 < K; k0 += BK) {
#pragma unroll
            for (int rnd = 0; rnd < 2; ++rnd) {
                const int rbase = wave * 16 + rnd * 64;
                int row = rbase + lr;
                int ga = bm0 + row; ga = (ga < R) ? ga : (R - 1);
                async16(Ap + (size_t)ga * K + k0 + lc, &As[rbase * LDST]);
                async16(Bp + (size_t)(bn0 + row) * K + k0 + lc, &Bs[rbase * LDST]);
            }
            __syncthreads();
            bf16x8v af[4], bfv[4];
#pragma unroll
            for (int i = 0; i < 4; ++i) {
                af[i]  = *(const bf16x8v*)&As[(wm + i * 16 + l15) * LDST + q8];
                bfv[i] = *(const bf16x8v*)&Bs[(wn + i * 16 + l15) * LDST + q8];
            }
#pragma unroll
            for (int i = 0; i < 4; ++i)
#pragma unroll
                for (int j = 0; j < 4; ++j)
                    acc[i][j] = __builtin_amdgcn_mfma_f32_16x16x32_bf16(
                        af[i], bfv[j], acc[i][j], 0, 0, 0);
            __syncthreads();
        }
    };
    panel(A1, B1, 128);
    if (A2) panel(A2, B2, H2);

    // ---- fused LSTM cell epilogue
    const int u = ((bn0 + wn) >> 6) * 16 + l15;      // hidden unit 0..191
    const float awu = aw[u];
    float bv[4];
#pragma unroll
    for (int j = 0; j < 4; ++j) bv[j] = bias[bn0 + wn + j * 16 + l15];
    float psum[4][4];
#pragma unroll
    for (int i = 0; i < 4; ++i) {
        const int row0 = bm0 + wm + i * 16 + q * 4;
#pragma unroll
        for (int r = 0; r < 4; ++r) {
            const int gr = row0 + r;
            const bool ok = gr < R;
            float ig = acc[i][0][r] + bv[0];
            float fg = acc[i][1][r] + bv[1];
            float gg = acc[i][2][r] + bv[2];
            float og = acc[i][3][r] + bv[3];
            float si = 1.f / (1.f + __expf(-ig));
            float sf = 1.f / (1.f + __expf(-fg));
            float so = 1.f / (1.f + __expf(-og));
            float co = (ok && A2) ? b2f(c_state[(size_t)gr * H2 + u]) : 0.f;
            float cn = sf * co + si * ftanh(gg);
            float hn = so * ftanh(cn);
            if (ok) {
                c_state[(size_t)gr * H2 + u] = f2b(cn);
                h_out[(size_t)gr * H2 + u] = f2b(hn);
            }
            psum[i][r] = hn * awu;
        }
    }
#pragma unroll
    for (int m = 1; m < 16; m <<= 1)
#pragma unroll
        for (int i = 0; i < 4; ++i)
#pragma unroll
            for (int r = 0; r < 4; ++r)
                psum[i][r] += __shfl_xor(psum[i][r], m);
    if (l15 == 0) {
#pragma unroll
        for (int i = 0; i < 4; ++i)
#pragma unroll
            for (int r = 0; r < 4; ++r) {
                const int gr = bm0 + wm + i * 16 + q * 4 + r;
                if (gr < R) atomicAdd(&score[gr], psum[i][r]);
            }
    }
}

// Layer-0 conv GEMM: A built on the fly from embeddings (K=128 fixed);
// A staged via ds_write (computed), B via async global_load_lds.
__global__ __launch_bounds__(256) void mfma_gemm_x0_kernel(
    const int* __restrict__ xidx, const float* __restrict__ xflt,
    const float* __restrict__ embA, const float* __restrict__ embS,
    const bf16* __restrict__ B1, bf16* __restrict__ C, int R, int M) {
    __shared__ bf16 As[128 * LDST];
    __shared__ bf16 Bs[128 * LDST];
    int bm0, bn0;
    if (!swz_tile(R, M >> 7, bm0, bn0)) return;
    const int tid = threadIdx.x;
    const int lane = tid & 63;
    const int wave = tid >> 6;
    const int wm = (wave & 1) * 64, wn = (wave >> 1) * 64;
    const int l15 = lane & 15;
    const int q8 = (lane >> 4) * 8;
    const int srow = tid >> 2;
    const int scol = (tid & 3) * 8;
    const int lr = lane >> 2;
    const int lc = (lane & 3) * 8;

    f32x4v acc[4][4];
#pragma unroll
    for (int i = 0; i < 4; ++i)
#pragma unroll
        for (int j = 0; j < 4; ++j) acc[i][j] = (f32x4v)(0.0f);

    for (int k0 = 0; k0 < 128; k0 += BK) {
#pragma unroll
        for (int rnd = 0; rnd < 2; ++rnd) {
            {   // A: computed on the fly -> ds_write
                int row = srow + rnd * 64;
                int ga = bm0 + row; ga = (ga < R) ? ga : (R - 1);
                int ia = xidx[2 * ga], is_ = xidx[2 * ga + 1];
                bf16 tmp[8];
#pragma unroll
                for (int t = 0; t < 8; ++t)
                    tmp[t] = f2b(x0_val(k0 + scol + t, ia, is_, ga, embA, embS, xflt));
                *(int4*)&As[row * LDST + scol] = *(const int4*)tmp;
            }
            {   // B: async
                const int rbase = wave * 16 + rnd * 64;
                int row = rbase + lr;
                async16(B1 + (size_t)(bn0 + row) * 128 + k0 + lc, &Bs[rbase * LDST]);
            }
        }
        __syncthreads();
        bf16x8v af[4], bfv[4];
#pragma unroll
        for (int i = 0; i < 4; ++i) {
            af[i]  = *(const bf16x8v*)&As[(wm + i * 16 + l15) * LDST + q8];
            bfv[i] = *(const bf16x8v*)&Bs[(wn + i * 16 + l15) * LDST + q8];
        }
#pragma unroll
        for (int i = 0; i < 4; ++i)
#pragma unroll
            for (int j = 0; j < 4; ++j)
                acc[i][j] = __builtin_amdgcn_mfma_f32_16x16x32_bf16(
                    af[i], bfv[j], acc[i][j], 0, 0, 0);
        __syncthreads();
    }
#pragma unroll
    for (int i = 0; i < 4; ++i) {
        const int row0 = bm0 + wm + i * 16 + (lane >> 4) * 4;
#pragma unroll
        for (int j = 0; j < 4; ++j) {
            const int col = bn0 + wn + j * 16 + l15;
#pragma unroll
            for (int r = 0; r < 4; ++r) {
                const int gr = row0 + r;
                if (gr < R) C[(size_t)gr * M + col] = f2b(acc[i][j][r]);
            }
        }
    }
}

// ---------------------------------------------------------------- GAT pieces

__global__ __launch_bounds__(256) void att_kernel(
    const bf16* __restrict__ xh, const float* __restrict__ as_,
    const float* __restrict__ ad_, float* __restrict__ asrc, float* __restrict__ adst) {
    int w = (blockIdx.x * blockDim.x + threadIdx.x) >> 6;
    int lane = threadIdx.x & 63;
    if (w >= N_NODES) return;
    const bf16* row = xh + (size_t)w * 256;
    float x0 = b2f(row[lane]), x1 = b2f(row[64 + lane]);
    float x2 = b2f(row[128 + lane]), x3 = b2f(row[192 + lane]);
    float s0 = x0 * as_[lane] + x1 * as_[64 + lane];
    float s1 = x2 * as_[128 + lane] + x3 * as_[192 + lane];
    float d0 = x0 * ad_[lane] + x1 * ad_[64 + lane];
    float d1 = x2 * ad_[128 + lane] + x3 * ad_[192 + lane];
    for (int o = 1; o < 64; o <<= 1) {
        s0 += __shfl_xor(s0, o); s1 += __shfl_xor(s1, o);
        d0 += __shfl_xor(d0, o); d1 += __shfl_xor(d1, o);
    }
    if (lane == 0) {
        asrc[2 * w] = s0; asrc[2 * w + 1] = s1;
        adst[2 * w] = d0; adst[2 * w + 1] = d1;
    }
}

__device__ __forceinline__ float lrelu02(float x) { return x > 0.f ? x : 0.2f * x; }

// one wave per dst node: online-softmax pass + 2-edge/iter gather
__global__ __launch_bounds__(256) void agg_kernel(
    const bf16* __restrict__ xh, const float* __restrict__ asrc,
    const float* __restrict__ adst, const int* __restrict__ offs,
    const int* __restrict__ srcs,
    const bf16* __restrict__ xprev_l, const bf16* __restrict__ xprev_r,
    const int* __restrict__ xidx, const float* __restrict__ xflt,
    const float* __restrict__ embAl, const float* __restrict__ embSl,
    const float* __restrict__ embAr, const float* __restrict__ embSr,
    const float* __restrict__ bias, bf16* __restrict__ outx) {
    int n = (blockIdx.x * blockDim.x + threadIdx.x) >> 6;
    int lane = threadIdx.x & 63;
    if (n >= N_NODES) return;
    const int start = offs[n], end = offs[n + 1];
    const float ad0 = adst[2 * n], ad1 = adst[2 * n + 1];

    // pass 1: online softmax (m, d) per head, lane-parallel
    float m0 = -1e30f, d0 = 0.f, m1 = -1e30f, d1 = 0.f;
    for (int j = start + lane; j < end; j += 64) {
        int s = srcs[j];
        float2 a2 = *(const float2*)(asrc + 2 * s);
        float a0 = lrelu02(a2.x + ad0);
        float a1 = lrelu02(a2.y + ad1);
        float nm0 = fmaxf(m0, a0);
        d0 = d0 * __expf(m0 - nm0) + __expf(a0 - nm0); m0 = nm0;
        float nm1 = fmaxf(m1, a1);
        d1 = d1 * __expf(m1 - nm1) + __expf(a1 - nm1); m1 = nm1;
    }
    for (int o = 1; o < 64; o <<= 1) {
        float om = __shfl_xor(m0, o), od = __shfl_xor(d0, o);
        float nm = fmaxf(m0, om);
        d0 = d0 * __expf(m0 - nm) + od * __expf(om - nm); m0 = nm;
        om = __shfl_xor(m1, o); od = __shfl_xor(d1, o);
        nm = fmaxf(m1, om);
        d1 = d1 * __expf(m1 - nm) + od * __expf(om - nm); m1 = nm;
    }
    const float inv0 = 1.f / (d0 + 1e-16f), inv1 = 1.f / (d1 + 1e-16f);

    // pass 2: gather, 2 edges per iteration (half-wave per edge, 16 B/lane)
    const int eh = lane >> 5;           // which edge of the pair
    const int l32 = lane & 31;
    const int head = l32 >> 4;          // head within edge
    const int l15 = l32 & 15;
    const int col = head * 128 + l15 * 8;
    const float mh = head ? m1 : m0;
    const float invh = head ? inv1 : inv0;
    const float adh = head ? ad1 : ad0;

    float acc[8] = {0.f, 0.f, 0.f, 0.f, 0.f, 0.f, 0.f, 0.f};
#pragma unroll 2
    for (int j = start; j < end; j += 2) {
        int e = j + eh;
        if (e < end) {
            int s = srcs[e];
            float a = asrc[2 * s + head] + adh;
            float al = __expf(lrelu02(a) - mh) * invh;
            int4 v = *(const int4*)(xh + (size_t)s * 256 + col);
            const int* w = (const int*)&v;
#pragma unroll
            for (int t = 0; t < 4; ++t) {
                float lo = __uint_as_float(((unsigned)w[t]) << 16);
                float hi = __uint_as_float(((unsigned)w[t]) & 0xffff0000u);
                acc[2 * t]     += lo * al;
                acc[2 * t + 1] += hi * al;
            }
        }
    }
#pragma unroll
    for (int t = 0; t < 8; ++t) acc[t] += __shfl_xor(acc[t], 32);  // edge parity
#pragma unroll
    for (int t = 0; t < 8; ++t)
        acc[t] = 0.5f * (acc[t] + __shfl_xor(acc[t], 16));         // head mean

    if (lane < 16) {
        const int c0 = lane * 8;
        const size_t base = (size_t)n * HID + c0;
        float xm[8];
        if (xidx) {
            int ia = xidx[2 * n], is_ = xidx[2 * n + 1];
#pragma unroll
            for (int t = 0; t < 8; ++t)
                xm[t] = 0.5f * (x0_val(c0 + t, ia, is_, n, embAl, embSl, xflt) +
                                x0_val(c0 + t, ia, is_, n, embAr, embSr, xflt));
        } else {
            int4 vl = *(const int4*)(xprev_l + base);
            int4 vr = *(const int4*)(xprev_r + base);
            const int* wl = (const int*)&vl;
            const int* wr = (const int*)&vr;
#pragma unroll
            for (int t = 0; t < 4; ++t) {
                xm[2 * t] = 0.5f * (__uint_as_float(((unsigned)wl[t]) << 16) +
                                    __uint_as_float(((unsigned)wr[t]) << 16));
                xm[2 * t + 1] = 0.5f * (__uint_as_float(((unsigned)wl[t]) & 0xffff0000u) +
                                        __uint_as_float(((unsigned)wr[t]) & 0xffff0000u));
            }
        }
        bf16 res[8];
#pragma unroll
        for (int t = 0; t < 8; ++t)
            res[t] = f2b(xm[t] + fmaxf(0.f, acc[t] + bias[c0 + t]));
        *(int4*)(outx + base) = *(const int4*)res;
    }
}

// ---------------------------------------------------------------- JK / final

__global__ __launch_bounds__(256) void jkfin_kernel(
    const float* __restrict__ sb, const bf16* __restrict__ xs0,
    const bf16* __restrict__ xs1, const bf16* __restrict__ xs2,
    bf16* __restrict__ jk) {
    int w = (blockIdx.x * blockDim.x + threadIdx.x) >> 6;
    int lane = threadIdx.x & 63;
    if (w >= N_NODES) return;
    float s0 = sb[w], s1 = sb[N_NODES + w], s2 = sb[2 * N_NODES + w];
    float m = fmaxf(s0, fmaxf(s1, s2));
    float a0 = __expf(s0 - m), a1 = __expf(s1 - m), a2 = __expf(s2 - m);
    float inv = 1.f / (a0 + a1 + a2);
    a0 *= inv; a1 *= inv; a2 *= inv;
    size_t gn = (size_t)w * HID + lane * 2;
#pragma unroll
    for (int t = 0; t < 2; ++t) {
        float v0 = b2f(xs0[gn + t]);
        float v1 = b2f(xs1[gn + t]);
        float v2 = b2f(xs2[gn + t]);
        jk[gn + t] = f2b(v0 * a0 + v1 * a1 + v2 * a2);
    }
}

__global__ __launch_bounds__(256) void final_kernel(
    const float* __restrict__ o0, const float* __restrict__ o1,
    const float* __restrict__ o2, const float* __restrict__ o3,
    const float* __restrict__ lw, float* __restrict__ out, int nloc, long long c3off) {
    int w = (blockIdx.x * blockDim.x + threadIdx.x) >> 6;
    int lane = threadIdx.x & 63;
    if (w >= nloc) return;
    size_t base = (size_t)w * HID;
    float w0 = lw[lane], w1 = lw[64 + lane];
    const float* op[4] = {o0, o1, o2, o3};
    float v[4][2];
    float s[4];
#pragma unroll
    for (int i = 0; i < 4; ++i) {
        v[i][0] = op[i][base + lane];
        v[i][1] = op[i][base + 64 + lane];
        float t = v[i][0] * w0 + v[i][1] * w1;
        for (int o = 1; o < 64; o <<= 1) t += __shfl_xor(t, o);
        s[i] = t;
    }
    float m = fmaxf(fmaxf(s[0], s[1]), fmaxf(s[2], s[3]));
    float e0 = __expf(s[0] - m), e1 = __expf(s[1] - m);
    float e2 = __expf(s[2] - m), e3 = __expf(s[3] - m);
    float inv = 1.f / (e0 + e1 + e2 + e3);
    float r0 = (v[0][0] * e0 + v[1][0] * e1 + v[2][0] * e2 + v[3][0] * e3) * inv;
    float r1 = (v[0][1] * e0 + v[1][1] * e1 + v[2][1] * e2 + v[3][1] * e3) * inv;
    size_t obase = (size_t)(c3off + w) * HID;
    out[obase + lane] = r0;
    out[obase + 64 + lane] = r1;
}

// ---------------------------------------------------------------- entry

static long long align1k(long long x) { return (x + 1023) & ~1023LL; }

extern "C" void kernel_launch(void* const* d_in, const int* in_sizes, int n_in,
                              void* d_out, int out_size, void* d_ws, size_t ws_size,
                              hipStream_t stream) {
    (void)in_sizes; (void)n_in; (void)out_size;
    const int*   x_idx   = (const int*)  d_in[0];
    const float* x_flt   = (const float*)d_in[1];
    const int*   ei_l    = (const int*)  d_in[2];
    const int*   ei_r    = (const int*)  d_in[3];
    const float* emb_aa  = (const float*)d_in[4];
    const float* emb_ss  = (const float*)d_in[5];
    const float* conv_W  = (const float*)d_in[6];
    const float* att_s   = (const float*)d_in[7];
    const float* att_d   = (const float*)d_in[8];
    const float* conv_b  = (const float*)d_in[9];
    const float* Wih     = (const float*)d_in[10];
    const float* Whh     = (const float*)d_in[11];
    const float* bih     = (const float*)d_in[12];
    const float* bhh     = (const float*)d_in[13];
    const float* jkw     = (const float*)d_in[14];
    const float* dummy_W = (const float*)d_in[16];
    const float* dummy_b = (const float*)d_in[17];
    const float* fin_W   = (const float*)d_in[18];
    const float* fin_b   = (const float*)d_in[19];
    const float* last_W  = (const float*)d_in[20];
    float* out = (float*)d_out;

    const long long S = (long long)N_NODES * HID;
    char* ws = (char*)d_ws;
    long long off = 0;

    // hist: 6 bf16 slabs; stage 3 reuses as fp32 scratch
    bf16* hist = (bf16*)(ws + off);
    off += align1k(6 * S * 2);
    // R1: stage0/1 {CSR ints, asrc, adst, convWt} | stage2 {c-state bf16, N x 192}
    char* R1 = ws + off;
    {
        long long io4 = 2LL * (N_NODES + (N_NODES + 1) + N_NODES + EL_TOT) * 4;
        long long st01 = ((io4 + 15) & ~15LL) + 4LL * N_NODES * 4 + 6LL * 256 * 128 * 2;
        long long st2  = (long long)N_NODES * H2 * 2;
        off += align1k(st01 > st2 ? st01 : st2);
    }
    // R2: stage1 xh (N x 256 bf16) | stage2 h (N x 192 bf16) | stage2-end/3 jk
    char* R2 = ws + off;
    off += align1k(2 * S * 2);
    float* scores = (float*)(ws + off); off += align1k(6LL * N_NODES * 4);
    float* bsum   = (float*)(ws + off); off += align1k(4LL * G4 * 4);
    bf16* Wih_b   = (bf16*)(ws + off); off += align1k(4LL * G4 * HID * 2);
    bf16* Whh_b   = (bf16*)(ws + off); off += align1k(4LL * G4 * H2 * 2);
    bf16* dummyWt = (bf16*)(ws + off); off += align1k(2LL * 128 * 128 * 2);
    bf16* finWt   = (bf16*)(ws + off); off += align1k(4LL * 128 * 128 * 2);

    if ((long long)ws_size < off) {   // diagnosable: 200000 + ws MiB
        float val = 200000.0f + (float)(ws_size >> 20);
        sentinel_kernel<<<(N_NODES * HID + 255) / 256, 256, 0, stream>>>(
            out, N_NODES * HID, val);
        return;
    }

    // R1 stage0/1 views
    int* ibase = (int*)R1;
    int *deg[2], *offs[2], *pos[2], *srcs[2];
    long long io = 0;
    for (int b = 0; b < 2; ++b) {
        deg[b]  = ibase + io; io += N_NODES;
        offs[b] = ibase + io; io += N_NODES + 1;
        pos[b]  = ibase + io; io += N_NODES;
        srcs[b] = ibase + io; io += EL_TOT;
    }
    long long io4a = ((io * 4 + 15) & ~15LL);
    float* asrc = (float*)(R1 + io4a);
    float* adst = asrc + 2LL * N_NODES;
    bf16* convWt = (bf16*)(R1 + io4a + 4LL * N_NODES * 4);
    // stage2 views
    bf16* cbuf = (bf16*)R1;
    bf16* hbuf = (bf16*)R2;
    // R2 views
    bf16* xh  = (bf16*)R2;
    bf16* jkb = (bf16*)R2;

    const float* embA[2] = {emb_aa, emb_aa + 26 * 123};
    const float* embS[2] = {emb_ss, emb_ss + 3 * 123};

    // ---- stage 0: weight conversion (LSTM weights gate-permuted) + CSR
    bsum_perm_kernel<<<12, 256, 0, stream>>>(bih, bhh, bsum);
    trans_kernel<<<(6 * 128 * 256 + 255) / 256, 256, 0, stream>>>(
        conv_W, convWt, 6, 128, 256);
    lstm_w_perm_kernel<<<(4 * G4 * HID + 255) / 256, 256, 0, stream>>>(
        Wih, Wih_b, HID);
    lstm_w_perm_kernel<<<(4 * G4 * H2 + 255) / 256, 256, 0, stream>>>(
        Whh, Whh_b, H2);
    trans_kernel<<<(2 * 128 * 128 + 255) / 256, 256, 0, stream>>>(
        dummy_W, dummyWt, 2, 128, 128);
    trans_kernel<<<(4 * 128 * 128 + 255) / 256, 256, 0, stream>>>(
        fin_W, finWt, 4, 128, 128);
    for (int b = 0; b < 2; ++b) {
        const int* ei = b ? ei_r : ei_l;
        hipMemsetAsync(deg[b], 0, N_NODES * sizeof(int), stream);
        deg_kernel<<<(EL_TOT + 255) / 256, 256, 0, stream>>>(ei + N_EDGES, deg[b]);
        scan_kernel<<<1, 1024, 0, stream>>>(deg[b], offs[b], N_NODES);
        copy_int_kernel<<<(N_NODES + 255) / 256, 256, 0, stream>>>(offs[b], pos[b], N_NODES);
        fill_kernel<<<(EL_TOT + 255) / 256, 256, 0, stream>>>(
            ei, ei + N_EDGES, pos[b], srcs[b]);
    }

    // ---- stage 1: 3 GAT layers x 2 branches
    for (int i = 0; i < 3; ++i) {
        for (int b = 0; b < 2; ++b) {
            const bf16* Wc = convWt + (size_t)(b * 3 + i) * 256 * 128;
            if (i == 0) {
                mfma_gemm_x0_kernel<<<swz_grid(N_NODES, 2), 256, 0, stream>>>(
                    x_idx, x_flt, embA[b], embS[b], Wc, xh, N_NODES, 256);
            } else {
                mfma_gemm<bf16>(hist + (size_t)(b * 3 + i - 1) * S, Wc, 128,
                                nullptr, nullptr, 0, xh, nullptr, N_NODES, 256, stream);
            }
            att_kernel<<<25000, 256, 0, stream>>>(
                xh, att_s + (size_t)(b * 3 + i) * 2 * HID,
                att_d + (size_t)(b * 3 + i) * 2 * HID, asrc, adst);
            const bf16* xpl = (i == 0) ? nullptr : hist + (size_t)(i - 1) * S;
            const bf16* xpr = (i == 0) ? nullptr : hist + (size_t)(3 + i - 1) * S;
            agg_kernel<<<25000, 256, 0, stream>>>(
                xh, asrc, adst, offs[b], srcs[b], xpl, xpr,
                (i == 0) ? x_idx : nullptr, x_flt,
                embA[0], embS[0], embA[1], embS[1],
                conv_b + (size_t)(b * 3 + i) * HID, hist + (size_t)(b * 3 + i) * S);
        }
    }

    // ---- stage 2: bi-LSTM JK, full-N, fused cell epilogue
    hipMemsetAsync(scores, 0, (size_t)6 * N_NODES * 4, stream);
    for (int b = 0; b < 2; ++b) {
        for (int dir = 0; dir < 2; ++dir) {
            const bf16* Wi = Wih_b + (size_t)(b * 2 + dir) * G4 * HID;
            const bf16* Wh = Whh_b + (size_t)(b * 2 + dir) * G4 * H2;
            const float* bs = bsum + (size_t)(b * 2 + dir) * G4;
            const float* aw = jkw + (size_t)b * 2 * H2 + (size_t)dir * H2;
            for (int st = 0; st < 3; ++st) {
                int l = dir ? (2 - st) : st;
                const bf16* A = hist + (size_t)(b * 3 + l) * S;
                lstm_gemm_kernel<<<swz_grid(N_NODES, 6), 256, 0, stream>>>(
                    A, Wi, (st == 0) ? nullptr : hbuf, Wh, bs, cbuf, hbuf, aw,
                    scores + (size_t)(b * 3 + l) * N_NODES, N_NODES);
            }
        }
    }
    for (int b = 0; b < 2; ++b)
        jkfin_kernel<<<25000, 256, 0, stream>>>(
            scores + (size_t)b * 3 * N_NODES,
            hist + (size_t)b * 3 * S, hist + (size_t)(b * 3 + 1) * S,
            hist + (size_t)(b * 3 + 2) * S, jkb + (size_t)b * S);

    // ---- stage 3: sq, outs, final combine (scratch = freed hist region)
    float* f3 = (float*)hist;
    bf16* jkl = jkb; bf16* jkr = jkb + S;
    for (long long c3 = 0; c3 < N_NODES; c3 += CH3) {
        int Rr = (int)((N_NODES - c3) < CH3 ? (N_NODES - c3) : CH3);
        float* o0 = f3;
        float* o1 = f3 + 1LL * CH3 * HID;
        float* o2 = f3 + 2LL * CH3 * HID;
        float* o3 = f3 + 3LL * CH3 * HID;
        bf16* sql = (bf16*)(f3 + 4LL * CH3 * HID);
        bf16* sqr = sql + (long long)CH3 * HID;
        mfma_gemm<bf16>(jkl + c3 * HID, dummyWt, 128, nullptr, nullptr, 0,
                        sql, dummy_b, Rr, 128, stream);
        mfma_gemm<bf16>(jkr + c3 * HID, dummyWt + 16384, 128, nullptr, nullptr, 0,
                        sqr, dummy_b + 128, Rr, 128, stream);
        mfma_gemm<float>(jkl + c3 * HID, finWt, 128, nullptr, nullptr, 0,
                         o0, fin_b, Rr, 128, stream);
        mfma_gemm<float>(sql, finWt + 16384, 128, nullptr, nullptr, 0,
                         o1, fin_b + 128, Rr, 128, stream);
        mfma_gemm<float>(jkr + c3 * HID, finWt + 2 * 16384, 128, nullptr, nullptr, 0,
                         o2, fin_b + 256, Rr, 128, stream);
        mfma_gemm<float>(sqr, finWt + 3 * 16384, 128, nullptr, nullptr, 0,
                         o3, fin_b + 384, Rr, 128, stream);
        final_kernel<<<(Rr + 3) / 4, 256, 0, stream>>>(
            o0, o1, o2, o3, last_W, out, Rr, c3);
    }
}